// Round 13
// baseline (392.640 us; speedup 1.0000x reference)
//
#include <hip/hip_runtime.h>
#include <math.h>

#define GSZ 256

typedef unsigned short u16;
typedef short bf16x8 __attribute__((ext_vector_type(8)));
typedef u16 u16x8 __attribute__((ext_vector_type(8)));
typedef float f32x4 __attribute__((ext_vector_type(4)));
#define MFMA16 __builtin_amdgcn_mfma_f32_16x16x32_bf16

// hF fragment layout: unit(n,c) = hF + (((n>>5)*NCC + (c>>4))*64 + ((n>>3)&3)*16 + (c&15))*8,
// elem n&7.  NCC = 128 for h (2048 cols), 8 for EqkF (128 cols).

__device__ __forceinline__ float bf2f(u16 u){
  union { unsigned int i; float f; } x; x.i = ((unsigned int)u) << 16; return x.f;
}
__device__ __forceinline__ u16 f2bf(float f){
  union { float ff; unsigned int i; } x; x.ff = f;
  unsigned int r = x.i + 0x7fffu + ((x.i >> 16) & 1u);
  return (u16)(r >> 16);
}
__device__ __forceinline__ float sigm(float x){ return 1.0f/(1.0f+__expf(-x)); }
__device__ __forceinline__ float siluf(float x){ return x/(1.0f+__expf(-x)); }

__device__ __forceinline__ void gload16(const void* g, void* l){
  __builtin_amdgcn_global_load_lds(
      (const __attribute__((address_space(1))) void*)g,
      (__attribute__((address_space(3))) void*)l, 16, 0, 0);
}

__device__ __forceinline__ float2 blockReduce2(float s, float ss){
  __shared__ float red[8];
  #pragma unroll
  for (int off=32; off>0; off>>=1){
    s  += __shfl_down(s, off, 64);
    ss += __shfl_down(ss, off, 64);
  }
  int lane = threadIdx.x & 63, wid = threadIdx.x >> 6;
  if (lane==0){ red[wid]=s; red[4+wid]=ss; }
  __syncthreads();
  float2 r;
  r.x = red[0]+red[1]+red[2]+red[3];
  r.y = red[4]+red[5]+red[6]+red[7];
  return r;
}

// ---------------- small prep kernels ----------------

__global__ __launch_bounds__(256) void shift_ln_kernel(
    const float* __restrict__ x, u16* __restrict__ out, int N)
{
  int n = blockIdx.x;
  int t = threadIdx.x;
  float v0 = (n > 0) ? x[(long long)(n-1)*512 + t] : 0.0f;
  float v1 = x[(long long)n*512 + 256 + t];
  float2 r = blockReduce2(v0+v1, fmaf(v0,v0,v1*v1));
  float mu = r.x * (1.0f/512.0f);
  float var = r.y * (1.0f/512.0f) - mu*mu;
  float rs = rsqrtf(var + 1e-5f);
  long long base = (long long)n*512;
  out[base + t]       = f2bf((v0-mu)*rs);
  out[base + 256 + t] = f2bf((v1-mu)*rs);
}

__global__ __launch_bounds__(256) void fuse_wT_kernel(
    const float* __restrict__ g, const float* __restrict__ w,
    u16* __restrict__ wT, int K, int Nn)
{
  __shared__ float sL[32][33];
  int k0 = blockIdx.x*32, n0 = blockIdx.y*32;
  int t = threadIdx.x;
  int r = t >> 3, cq = t & 7;
  float4 v = *(const float4*)(w + (size_t)(k0+r)*Nn + n0 + cq*4);
  float gg = g[k0+r];
  sL[r][cq*4+0] = v.x*gg; sL[r][cq*4+1] = v.y*gg;
  sL[r][cq*4+2] = v.z*gg; sL[r][cq*4+3] = v.w*gg;
  __syncthreads();
  ushort4 o;
  o.x = f2bf(sL[cq*4+0][r]); o.y = f2bf(sL[cq*4+1][r]);
  o.z = f2bf(sL[cq*4+2][r]); o.w = f2bf(sL[cq*4+3][r]);
  *(ushort4*)(wT + (size_t)(n0+r)*K + k0 + cq*4) = o;
}

__global__ void copy_bias_kernel(const float* __restrict__ bias, float* __restrict__ bout, int Nn){
  int i = blockIdx.x*256 + threadIdx.x;
  if (i < Nn) bout[i] = bias[i];
}

__global__ __launch_bounds__(256) void fuse_b_acc(
    const float* __restrict__ bln, const float* __restrict__ w,
    float* __restrict__ bout, int K, int Nn)
{
  int n = blockIdx.x*256 + threadIdx.x;
  int k0 = blockIdx.y*64;
  if (n >= Nn) return;
  float acc = 0.f;
  #pragma unroll
  for (int k = 0; k < 64; ++k)
    acc = fmaf(bln[k0+k], w[(size_t)(k0+k)*Nn + n], acc);
  atomicAdd(&bout[n], acc);
}

__global__ void zero_kernel(float* __restrict__ p, long long total){
  long long i = (long long)blockIdx.x*256 + threadIdx.x;
  if (i < total) p[i] = 0.0f;
}

// per-row mean/rstd of T2 (N x 1024 bf16) -> mu[], rs[]
__global__ __launch_bounds__(256) void rowstat_kernel(
    const u16* __restrict__ buf, float* __restrict__ mu, float* __restrict__ rs)
{
  long long n = blockIdx.x;
  const ushort4* p = (const ushort4*)(buf + n*1024) + threadIdx.x;
  ushort4 q = *p;
  float a = bf2f(q.x), b = bf2f(q.y), c = bf2f(q.z), d = bf2f(q.w);
  float s = a+b+c+d;
  float ss = fmaf(a,a, fmaf(b,b, fmaf(c,c, d*d)));
  float2 r = blockReduce2(s, ss);
  if (threadIdx.x == 0) {
    float m = r.x * (1.0f/1024.0f);
    float var = r.y * (1.0f/1024.0f) - m*m;
    mu[n] = m;
    rs[n] = rsqrtf(var + 1e-5f);
  }
}

// ---------------- MFMA kernels (chunk-linear LDS + global_load_lds) --------------
// LDS chunk = 64 units x 16B; unit l of chunk = fragment of lane l.
// MFMA frags: A row=l&15 k=(l>>4)*8+j ; B col=l&15 ; D col=l&15 row=(l>>4)*4+i.

// C = silu(A @ WT^T + bias).  BM=128, BN=128, BK=32, depth-2 (3 buffers).
__global__ __launch_bounds__(256) void gemm_mfma_silu(
    const u16* __restrict__ A, int lda,
    const u16* __restrict__ BT, int ldbt, int wtc0,
    u16* __restrict__ C, int ldc,
    const float* __restrict__ bias, int K)
{
  __shared__ u16 lds[3*16*512];
  int t = threadIdx.x;
  int lane = t & 63, wid = t >> 6;
  int wm = wid >> 1, wn = wid & 1;
  int lrow = lane & 15, kcL = lane >> 4;
  int bm = blockIdx.y*128, bn = blockIdx.x*128;
  const u16* gA0 = A + (size_t)(bm + wid*16 + lrow)*lda + kcL*8;
  const u16* gA1 = A + (size_t)(bm + (wid+4)*16 + lrow)*lda + kcL*8;
  const u16* gB0 = BT + (size_t)(wtc0 + bn + wid*16 + lrow)*ldbt + kcL*8;
  const u16* gB1 = BT + (size_t)(wtc0 + bn + (wid+4)*16 + lrow)*ldbt + kcL*8;
  f32x4 acc[4][4] = {};
  int nt = K >> 5;
  auto issue = [&](int ti, u16* b){
    int k1 = ti << 5;
    gload16(gA0 + k1, b + (size_t)wid*512);
    gload16(gA1 + k1, b + (size_t)(wid+4)*512);
    gload16(gB0 + k1, b + (size_t)(8+wid)*512);
    gload16(gB1 + k1, b + (size_t)(12+wid)*512);
  };
  issue(0, lds);
  if (nt > 1) issue(1, lds + 8192);
  for (int ti = 0; ti < nt; ++ti) {
    if (ti + 2 < nt) {
      issue(ti + 2, lds + (size_t)((ti+2)%3)*8192);
      asm volatile("s_waitcnt vmcnt(8)" ::: "memory");
    } else if (ti + 1 < nt) {
      asm volatile("s_waitcnt vmcnt(4)" ::: "memory");
    } else {
      asm volatile("s_waitcnt vmcnt(0)" ::: "memory");
    }
    __builtin_amdgcn_s_barrier();
    asm volatile("" ::: "memory");
    const bf16x8* L = (const bf16x8*)(lds + (size_t)(ti%3)*8192);
    bf16x8 af[4], bfr[4];
    #pragma unroll
    for (int mr = 0; mr < 4; ++mr) af[mr] = L[(wm*4+mr)*64 + lane];
    #pragma unroll
    for (int nr = 0; nr < 4; ++nr) bfr[nr] = L[(8 + wn*4+nr)*64 + lane];
    #pragma unroll
    for (int mr = 0; mr < 4; ++mr)
      #pragma unroll
      for (int nr = 0; nr < 4; ++nr)
        acc[mr][nr] = MFMA16(af[mr], bfr[nr], acc[mr][nr], 0, 0, 0);
    asm volatile("" ::: "memory");
    __builtin_amdgcn_s_barrier();
  }
  #pragma unroll
  for (int mr = 0; mr < 4; ++mr)
    #pragma unroll
    for (int nr = 0; nr < 4; ++nr) {
      int col = bn + wn*64 + nr*16 + lrow;
      float bs = bias[wtc0 + col];
      #pragma unroll
      for (int i = 0; i < 4; ++i) {
        int row = bm + wm*64 + mr*16 + kcL*4 + i;
        C[(size_t)row*ldc + col] = f2bf(siluf(acc[mr][nr][i] + bs));
      }
    }
}

// out-GEMM with fused LayerNorm: C = silu(rs[r]*(acc - mu[r]*S[c]) + bias[c]).
// A = raw T2 (N x 1024). Depth-2 body identical to gemm_mfma_silu.
__global__ __launch_bounds__(256) void gemm_mfma_ln_silu(
    const u16* __restrict__ A, int lda,
    const u16* __restrict__ BT, int ldbt,
    u16* __restrict__ C, int ldc,
    const float* __restrict__ bias, const float* __restrict__ S,
    const float* __restrict__ mu, const float* __restrict__ rs, int K)
{
  __shared__ u16 lds[3*16*512];
  int t = threadIdx.x;
  int lane = t & 63, wid = t >> 6;
  int wm = wid >> 1, wn = wid & 1;
  int lrow = lane & 15, kcL = lane >> 4;
  int bm = blockIdx.y*128, bn = blockIdx.x*128;
  const u16* gA0 = A + (size_t)(bm + wid*16 + lrow)*lda + kcL*8;
  const u16* gA1 = A + (size_t)(bm + (wid+4)*16 + lrow)*lda + kcL*8;
  const u16* gB0 = BT + (size_t)(bn + wid*16 + lrow)*ldbt + kcL*8;
  const u16* gB1 = BT + (size_t)(bn + (wid+4)*16 + lrow)*ldbt + kcL*8;
  f32x4 acc[4][4] = {};
  int nt = K >> 5;
  auto issue = [&](int ti, u16* b){
    int k1 = ti << 5;
    gload16(gA0 + k1, b + (size_t)wid*512);
    gload16(gA1 + k1, b + (size_t)(wid+4)*512);
    gload16(gB0 + k1, b + (size_t)(8+wid)*512);
    gload16(gB1 + k1, b + (size_t)(12+wid)*512);
  };
  issue(0, lds);
  issue(1, lds + 8192);
  for (int ti = 0; ti < nt; ++ti) {
    if (ti + 2 < nt) {
      issue(ti + 2, lds + (size_t)((ti+2)%3)*8192);
      asm volatile("s_waitcnt vmcnt(8)" ::: "memory");
    } else if (ti + 1 < nt) {
      asm volatile("s_waitcnt vmcnt(4)" ::: "memory");
    } else {
      asm volatile("s_waitcnt vmcnt(0)" ::: "memory");
    }
    __builtin_amdgcn_s_barrier();
    asm volatile("" ::: "memory");
    const bf16x8* L = (const bf16x8*)(lds + (size_t)(ti%3)*8192);
    bf16x8 af[4], bfr[4];
    #pragma unroll
    for (int mr = 0; mr < 4; ++mr) af[mr] = L[(wm*4+mr)*64 + lane];
    #pragma unroll
    for (int nr = 0; nr < 4; ++nr) bfr[nr] = L[(8 + wn*4+nr)*64 + lane];
    #pragma unroll
    for (int mr = 0; mr < 4; ++mr)
      #pragma unroll
      for (int nr = 0; nr < 4; ++nr)
        acc[mr][nr] = MFMA16(af[mr], bfr[nr], acc[mr][nr], 0, 0, 0);
    asm volatile("" ::: "memory");
    __builtin_amdgcn_s_barrier();
  }
  #pragma unroll
  for (int mr = 0; mr < 4; ++mr)
    #pragma unroll
    for (int nr = 0; nr < 4; ++nr) {
      int col = bn + wn*64 + nr*16 + lrow;
      float bs = bias[col];
      float Sc = S[col];
      #pragma unroll
      for (int i = 0; i < 4; ++i) {
        int row = bm + wm*64 + mr*16 + kcL*4 + i;
        float m = mu[row], r = rs[row];
        C[(size_t)row*ldc + col] = f2bf(siluf(fmaf(r, acc[mr][nr][i] - m*Sc, bs)));
      }
    }
}

// attn = relu(Eq0 @ Ek2^T / GS)^2 per group — depth-2 GEMM. grid (2, 2, G)
__global__ __launch_bounds__(256) void score_mfma2(
    const u16* __restrict__ Eq0, const u16* __restrict__ Ek2,
    u16* __restrict__ attn)
{
  __shared__ u16 lds[3*16*512];
  int t = threadIdx.x;
  int lane = t & 63, wid = t >> 6;
  int wm = wid >> 1, wn = wid & 1;
  int lrow = lane & 15, kcL = lane >> 4;
  int g = blockIdx.z;
  int bm = blockIdx.y*128, bn = blockIdx.x*128;
  size_t rowbase = (size_t)g * GSZ;
  const u16* gA0 = Eq0 + (rowbase + bm + wid*16 + lrow)*128 + kcL*8;
  const u16* gA1 = Eq0 + (rowbase + bm + (wid+4)*16 + lrow)*128 + kcL*8;
  const u16* gB0 = Ek2 + (rowbase + bn + wid*16 + lrow)*128 + kcL*8;
  const u16* gB1 = Ek2 + (rowbase + bn + (wid+4)*16 + lrow)*128 + kcL*8;
  f32x4 acc[4][4] = {};
  auto issue = [&](int ti, u16* b){
    int k1 = ti << 5;
    gload16(gA0 + k1, b + (size_t)wid*512);
    gload16(gA1 + k1, b + (size_t)(wid+4)*512);
    gload16(gB0 + k1, b + (size_t)(8+wid)*512);
    gload16(gB1 + k1, b + (size_t)(12+wid)*512);
  };
  issue(0, lds);
  issue(1, lds + 8192);
  for (int ti = 0; ti < 4; ++ti) {
    if (ti + 2 < 4) {
      issue(ti + 2, lds + (size_t)((ti+2)%3)*8192);
      asm volatile("s_waitcnt vmcnt(8)" ::: "memory");
    } else if (ti + 1 < 4) {
      asm volatile("s_waitcnt vmcnt(4)" ::: "memory");
    } else {
      asm volatile("s_waitcnt vmcnt(0)" ::: "memory");
    }
    __builtin_amdgcn_s_barrier();
    asm volatile("" ::: "memory");
    const bf16x8* L = (const bf16x8*)(lds + (size_t)(ti%3)*8192);
    bf16x8 af[4], bfr[4];
    #pragma unroll
    for (int mr = 0; mr < 4; ++mr) af[mr] = L[(wm*4+mr)*64 + lane];
    #pragma unroll
    for (int nr = 0; nr < 4; ++nr) bfr[nr] = L[(8 + wn*4+nr)*64 + lane];
    #pragma unroll
    for (int mr = 0; mr < 4; ++mr)
      #pragma unroll
      for (int nr = 0; nr < 4; ++nr)
        acc[mr][nr] = MFMA16(af[mr], bfr[nr], acc[mr][nr], 0, 0, 0);
    asm volatile("" ::: "memory");
    __builtin_amdgcn_s_barrier();
  }
  #pragma unroll
  for (int mr = 0; mr < 4; ++mr)
    #pragma unroll
    for (int nr = 0; nr < 4; ++nr) {
      int col = bn + wn*64 + nr*16 + lrow;
      #pragma unroll
      for (int i = 0; i < 4; ++i) {
        int row = bm + wm*64 + mr*16 + kcL*4 + i;
        float s = fmaxf(acc[mr][nr][i] * (1.0f/GSZ), 0.0f);
        attn[(rowbase + row)*GSZ + col] = f2bf(s*s);
      }
    }
}

// Fraw[d][e] += sum_n EqkF(n,d) * hF(n,e) — pure gload dbuf GEMM. grid (32, 16)
__global__ __launch_bounds__(256) void linkv_mfma(
    const u16* __restrict__ EqkF, const u16* __restrict__ hF,
    float* __restrict__ Fraw, int N)
{
  __shared__ u16 lds[2*12*512];
  int t = threadIdx.x;
  int lane = t & 63, wid = t >> 6;
  int wm = wid >> 1, wn = wid & 1;
  int lrow = lane & 15, kcL = lane >> 4;
  int e0 = blockIdx.x * 64;
  int nkt = (N / gridDim.y) >> 5;
  size_t kt0 = (size_t)blockIdx.y * nkt;
  f32x4 acc[4][2] = {};
  auto issue = [&](int kt, u16* b) {
    size_t ktile = kt0 + kt;
    gload16(EqkF + ((ktile*8 + wid)*64 + lane)*8,           b + (size_t)wid*512);
    gload16(EqkF + ((ktile*8 + wid+4)*64 + lane)*8,         b + (size_t)(wid+4)*512);
    gload16(hF + ((ktile*128 + (e0>>4) + wid)*64 + lane)*8, b + (size_t)(8+wid)*512);
  };
  issue(0, lds);
  int cur = 0;
  for (int ti = 0; ti < nkt; ++ti) {
    if (ti + 1 < nkt) {
      issue(ti + 1, lds + (size_t)(cur^1)*6144);
      asm volatile("s_waitcnt vmcnt(3)" ::: "memory");
    } else {
      asm volatile("s_waitcnt vmcnt(0)" ::: "memory");
    }
    __builtin_amdgcn_s_barrier();
    asm volatile("" ::: "memory");
    const bf16x8* L = (const bf16x8*)(lds + (size_t)cur*6144);
    bf16x8 af[4], bfr[2];
    #pragma unroll
    for (int mr = 0; mr < 4; ++mr) af[mr] = L[(wm*4+mr)*64 + lane];
    #pragma unroll
    for (int nr = 0; nr < 2; ++nr) bfr[nr] = L[(8 + wn*2+nr)*64 + lane];
    #pragma unroll
    for (int mr = 0; mr < 4; ++mr)
      #pragma unroll
      for (int nr = 0; nr < 2; ++nr)
        acc[mr][nr] = MFMA16(af[mr], bfr[nr], acc[mr][nr], 0, 0, 0);
    asm volatile("" ::: "memory");
    __builtin_amdgcn_s_barrier();
    cur ^= 1;
  }
  #pragma unroll
  for (int mr = 0; mr < 4; ++mr)
    #pragma unroll
    for (int nr = 0; nr < 2; ++nr) {
      int e = e0 + wn*32 + nr*16 + lrow;
      #pragma unroll
      for (int i = 0; i < 4; ++i) {
        int d = wm*64 + mr*16 + kcL*4 + i;
        atomicAdd(&Fraw[(size_t)d*2048 + e], acc[mr][nr][i]);
      }
    }
}

// F = inv_n*(g3[d]*Fraw + b3[d]*hsum[e]); FTg[e][d] = g1[d]*F ; cvec[e] = sum_d b1[d]*F
__global__ __launch_bounds__(256) void fconv_kernel(
    const float* __restrict__ Fraw, const float* __restrict__ osg, const float* __restrict__ osb,
    const float* __restrict__ hsum, float inv_n,
    u16* __restrict__ FTg, float* __restrict__ cvec)
{
  __shared__ float g1s[128], b1s[128], g3s[128], b3s[128];
  int t = threadIdx.x;
  if (t < 128) { g1s[t] = osg[128+t]; b1s[t] = osb[128+t];
                 g3s[t] = osg[3*128+t]; b3s[t] = osb[3*128+t]; }
  __syncthreads();
  int e = blockIdx.x*256 + t;
  float hs = hsum[e];
  float c = 0.f;
  for (int d = 0; d < 128; ++d) {
    float f = inv_n * fmaf(g3s[d], Fraw[(size_t)d*2048 + e], b3s[d]*hs);
    c = fmaf(b1s[d], f, c);
    FTg[(size_t)e*128 + d] = f2bf(g1s[d] * f);
  }
  cvec[e] = c;
}

// fused quad+lin attention + gate. 2-buffer depth-1 (R10 proven-best). grid 2048.
__global__ __launch_bounds__(256) void quadlin_mfma(
    const u16* __restrict__ attn, const u16* __restrict__ hF,
    const u16* __restrict__ eqk, const u16* __restrict__ FTg,
    const float* __restrict__ cvec, u16* __restrict__ T2)
{
  __shared__ u16 lds[2*16*512];
  int bid = blockIdx.x;
  int wgid = (bid & 7)*256 + (bid >> 3);
  int g = wgid >> 5;
  int rem = wgid & 31;
  int bm = (rem >> 4) * 128;
  int cb = (rem & 15) * 64;
  int t = threadIdx.x;
  int lane = t & 63, wid = t >> 6;
  int wm = wid >> 1, wn = wid & 1;
  int lrow = lane & 15, kcL = lane >> 4;
  size_t rowbase = (size_t)g * GSZ;
  f32x4 accV[4][2] = {}, accU[4][2] = {};
  const u16* gA0q = attn + (rowbase + bm + wid*16 + lrow)*GSZ + kcL*8;
  const u16* gA1q = attn + (rowbase + bm + (wid+4)*16 + lrow)*GSZ + kcL*8;
  const u16* gA0l = eqk + (rowbase + bm + wid*16 + lrow)*128 + kcL*8;
  const u16* gA1l = eqk + (rowbase + bm + (wid+4)*16 + lrow)*128 + kcL*8;
  const u16* gBVl = FTg + (size_t)(cb + wid*16 + lrow)*128 + kcL*8;
  const u16* gBUl = FTg + (size_t)(1024 + cb + wid*16 + lrow)*128 + kcL*8;
  auto issue = [&](int ti, u16* b) {
    if (ti < 8) {
      int k0 = ti << 5;
      size_t ktile = (size_t)g*8 + ti;
      gload16(gA0q + k0, b + (size_t)wid*512);
      gload16(gA1q + k0, b + (size_t)(wid+4)*512);
      gload16(hF + ((ktile*128 + (cb>>4) + wid)*64 + lane)*8,      b + (size_t)(8+wid)*512);
      gload16(hF + ((ktile*128 + 64 + (cb>>4) + wid)*64 + lane)*8, b + (size_t)(12+wid)*512);
    } else {
      int k0 = (ti - 8) << 5;
      gload16(gA0l + k0, b + (size_t)wid*512);
      gload16(gA1l + k0, b + (size_t)(wid+4)*512);
      gload16(gBVl + k0, b + (size_t)(8+wid)*512);
      gload16(gBUl + k0, b + (size_t)(12+wid)*512);
    }
  };
  issue(0, lds);
  int cur = 0;
  for (int ti = 0; ti < 12; ++ti) {
    if (ti + 1 < 12) {
      issue(ti + 1, lds + (size_t)(cur^1)*8192);
      asm volatile("s_waitcnt vmcnt(4)" ::: "memory");
    } else {
      asm volatile("s_waitcnt vmcnt(0)" ::: "memory");
    }
    __builtin_amdgcn_s_barrier();
    asm volatile("" ::: "memory");
    const bf16x8* L = (const bf16x8*)(lds + (size_t)cur*8192);
    bf16x8 af[4], bv[2], bu[2];
    #pragma unroll
    for (int mr = 0; mr < 4; ++mr) af[mr] = L[(wm*4+mr)*64 + lane];
    #pragma unroll
    for (int nr = 0; nr < 2; ++nr) { bv[nr] = L[(8 + wn*2+nr)*64 + lane];
                                     bu[nr] = L[(12 + wn*2+nr)*64 + lane]; }
    #pragma unroll
    for (int mr = 0; mr < 4; ++mr)
      #pragma unroll
      for (int nr = 0; nr < 2; ++nr) {
        accV[mr][nr] = MFMA16(af[mr], bv[nr], accV[mr][nr], 0, 0, 0);
        accU[mr][nr] = MFMA16(af[mr], bu[nr], accU[mr][nr], 0, 0, 0);
      }
    asm volatile("" ::: "memory");
    __builtin_amdgcn_s_barrier();
    cur ^= 1;
  }
  #pragma unroll
  for (int mr = 0; mr < 4; ++mr)
    #pragma unroll
    for (int nr = 0; nr < 2; ++nr) {
      int c = cb + wn*32 + nr*16 + lrow;
      float cV = cvec[c], cU = cvec[1024 + c];
      int np = bm + wm*64 + mr*16 + kcL*4;
      size_t ktile = (size_t)g*8 + (np>>5);
      int lofs = ((np>>3)&3)*16 + (c&15);
      int eo = np & 7;
      ushort4 vq = *(const ushort4*)(hF + ((ktile*128 + (c>>4))*64 + lofs)*8 + eo);
      ushort4 uq = *(const ushort4*)(hF + ((ktile*128 + 64 + (c>>4))*64 + lofs)*8 + eo);
      float vv[4] = {bf2f(vq.x), bf2f(vq.y), bf2f(vq.z), bf2f(vq.w)};
      float uu[4] = {bf2f(uq.x), bf2f(uq.y), bf2f(uq.z), bf2f(uq.w)};
      #pragma unroll
      for (int i = 0; i < 4; ++i) {
        float av = accV[mr][nr][i] + cV;
        float au = accU[mr][nr][i] + cU;
        T2[(rowbase + np + i)*1024 + c] = f2bf(au * vv[i] * sigm(av * uu[i]));
      }
    }
}

// ---------------- conv / norm kernels ----------------

// th-branch depthwise conv, 64-row tiles -> hF + hsum. grid (cols/64, N/64)
__global__ __launch_bounds__(256) void dwconv_hf64(
    const u16* __restrict__ xin, int ldin, const float* __restrict__ kern,
    u16* __restrict__ hF, int colbase, float* __restrict__ hsum, int N)
{
  __shared__ float tile[80][64];
  __shared__ float psum[4][64];
  int c0 = blockIdx.x * 64;
  int n0 = blockIdx.y * 64;
  int t = threadIdx.x;
  int tx = t & 63, ty = t >> 6;
  #pragma unroll
  for (int it = 0; it < 5; ++it) {
    int idx = t + it*256;
    int r = idx >> 4, cq = (idx & 15)*4;
    int gn = n0 - 8 + r;
    float4 f;
    if (gn >= 0 && gn < N) {
      ushort4 q = *(const ushort4*)(xin + (size_t)gn*ldin + c0 + cq);
      f.x = bf2f(q.x); f.y = bf2f(q.y); f.z = bf2f(q.z); f.w = bf2f(q.w);
    } else { f.x = 0.f; f.y = 0.f; f.z = 0.f; f.w = 0.f; }
    *(float4*)&tile[r][cq] = f;
  }
  __syncthreads();
  int chl = c0 + tx;
  float kr[17];
  #pragma unroll
  for (int k = 0; k < 17; ++k) kr[k] = kern[chl*17 + k];
  int c = colbase + chl;
  float loc = 0.f;
  #pragma unroll
  for (int u = 0; u < 2; ++u) {
    u16x8 o;
    #pragma unroll
    for (int rr = 0; rr < 8; ++rr) {
      int r = ty*16 + u*8 + rr;
      float s = 0.0f;
      #pragma unroll
      for (int k = 0; k < 17; ++k) s = fmaf(kr[k], tile[r+k][tx], s);
      float val = tile[r+8][tx] + s;
      loc += val;
      o[rr] = f2bf(val);
    }
    int nn = n0 + ty*16 + u*8;
    *(u16x8*)(hF + ((((size_t)(nn>>5))*128 + (c>>4))*64 + ((nn>>3)&3)*16 + (c&15))*8) = o;
  }
  psum[ty][tx] = loc;
  __syncthreads();
  if (t < 64)
    atomicAdd(&hsum[colbase + c0 + t], psum[0][t]+psum[1][t]+psum[2][t]+psum[3][t]);
}

// qk dwconv (32-row): writes Eqk, Eq0, Ek2 (row-major), EqkF (fragment). grid (2, N/32)
__global__ __launch_bounds__(256) void dwconv_qk(
    const u16* __restrict__ xin, const float* __restrict__ kern,
    const float* __restrict__ osg, const float* __restrict__ osb,
    u16* __restrict__ Eqk, u16* __restrict__ Eq0, u16* __restrict__ Ek2,
    u16* __restrict__ EqkF, int N)
{
  __shared__ float tile[48][64];
  int c0 = blockIdx.x * 64;
  int n0 = blockIdx.y * 32;
  int t = threadIdx.x;
  int tx = t & 63, ty = t >> 6;
  #pragma unroll
  for (int it = 0; it < 3; ++it) {
    int idx = t + it*256;
    int r = idx >> 4, cq = (idx & 15)*4;
    int gn = n0 - 8 + r;
    float4 f;
    if (gn >= 0 && gn < N) {
      ushort4 q = *(const ushort4*)(xin + (size_t)gn*128 + c0 + cq);
      f.x = bf2f(q.x); f.y = bf2f(q.y); f.z = bf2f(q.z); f.w = bf2f(q.w);
    } else { f.x = 0.f; f.y = 0.f; f.z = 0.f; f.w = 0.f; }
    *(float4*)&tile[r][cq] = f;
  }
  __syncthreads();
  int ch = c0 + tx;
  float kr[17];
  #pragma unroll
  for (int k = 0; k < 17; ++k) kr[k] = kern[ch*17 + k];
  float g0 = osg[ch], b0 = osb[ch];
  float g2 = osg[2*128+ch], b2 = osb[2*128+ch];
  float vals[8];
  #pragma unroll
  for (int rr = 0; rr < 8; ++rr) {
    int r = ty*8 + rr;
    float s = 0.0f;
    #pragma unroll
    for (int k = 0; k < 17; ++k) s = fmaf(kr[k], tile[r+k][tx], s);
    vals[rr] = tile[r+8][tx] + s;
    size_t gi = (size_t)(n0 + r)*128 + ch;
    Eqk[gi] = f2bf(vals[rr]);
    Eq0[gi] = f2bf(fmaf(vals[rr], g0, b0));
    Ek2[gi] = f2bf(fmaf(vals[rr], g2, b2));
  }
  u16x8 o;
  #pragma unroll
  for (int rr = 0; rr < 8; ++rr) o[rr] = f2bf(vals[rr]);
  *(u16x8*)(EqkF + ((((size_t)(n0>>5))*8 + (ch>>4))*64 + ty*16 + (ch&15))*8) = o;
}

// final conv, 64-row tiles: out = resid + x + conv(x). grid (8, N/64)
__global__ __launch_bounds__(256) void dwconv_final64(
    const u16* __restrict__ xin, const float* __restrict__ kern,
    const float* __restrict__ resid, float* __restrict__ y, int N)
{
  __shared__ float tile[80][64];
  int c0 = blockIdx.x * 64;
  int n0 = blockIdx.y * 64;
  int t = threadIdx.x;
  int tx = t & 63, ty = t >> 6;
  #pragma unroll
  for (int it = 0; it < 5; ++it) {
    int idx = t + it*256;
    int r = idx >> 4, cq = (idx & 15)*4;
    int gn = n0 - 8 + r;
    float4 f;
    if (gn >= 0 && gn < N) {
      ushort4 q = *(const ushort4*)(xin + (size_t)gn*512 + c0 + cq);
      f.x = bf2f(q.x); f.y = bf2f(q.y); f.z = bf2f(q.z); f.w = bf2f(q.w);
    } else { f.x = 0.f; f.y = 0.f; f.z = 0.f; f.w = 0.f; }
    *(float4*)&tile[r][cq] = f;
  }
  __syncthreads();
  int ch = c0 + tx;
  float kr[17];
  #pragma unroll
  for (int k = 0; k < 17; ++k) kr[k] = kern[ch*17 + k];
  #pragma unroll
  for (int rr = 0; rr < 16; ++rr) {
    int r = ty*16 + rr;
    float s = 0.0f;
    #pragma unroll
    for (int k = 0; k < 17; ++k) s = fmaf(kr[k], tile[r+k][tx], s);
    size_t gi = (size_t)(n0 + r)*512 + ch;
    y[gi] = resid[gi] + tile[r+8][tx] + s;
  }
}

// ---------------- host launcher ----------------

extern "C" void kernel_launch(void* const* d_in, const int* in_sizes, int n_in,
                              void* d_out, int out_size, void* d_ws, size_t ws_size,
                              hipStream_t stream)
{
  const float* x        = (const float*)d_in[0];
  const float* th_ln_g  = (const float*)d_in[2];
  const float* th_ln_b  = (const float*)d_in[3];
  const float* th_w     = (const float*)d_in[4];
  const float* th_b     = (const float*)d_in[5];
  const float* th_conv  = (const float*)d_in[6];
  const float* qk_ln_g  = (const float*)d_in[7];
  const float* qk_ln_b  = (const float*)d_in[8];
  const float* qk_w     = (const float*)d_in[9];
  const float* qk_b     = (const float*)d_in[10];
  const float* qk_conv  = (const float*)d_in[11];
  const float* osg      = (const float*)d_in[12];
  const float* osb      = (const float*)d_in[13];
  const float* out_ln_g = (const float*)d_in[14];
  const float* out_ln_b = (const float*)d_in[15];
  const float* out_w    = (const float*)d_in[16];
  const float* out_b    = (const float*)d_in[17];
  const float* out_conv = (const float*)d_in[18];

  const int N = in_sizes[0] / 512;          // 16384
  const float inv_n = 1.0f / (float)N;
  const int G = N / GSZ;                    // 64
  char* wsb = (char*)d_ws;

  // ---- workspace layout (bytes), lifetime-aliased ----
  size_t o_hF   = 0;
  size_t o_T2   = o_hF  + (size_t)N*2048*2;
  size_t o_C    = o_T2  + (size_t)N*1024*2;
  size_t o_eqk  = o_C   + (size_t)N*512*2;
  size_t o_fr   = o_eqk + (size_t)N*128*2;
  size_t o_wth  = o_fr  + (size_t)N*128*2;
  size_t o_wqk  = o_wth + (size_t)2048*512*2;
  size_t o_wout = o_wqk + (size_t)128*512*2;
  size_t o_bth  = o_wout+ (size_t)1024*512*2;
  size_t o_bqk  = o_bth + 2048*4;
  size_t o_bout = o_bqk + 128*4;
  size_t o_hsum = o_bout + 512*4;
  size_t o_S    = o_hsum + 2048*4;          // S: 512 floats
  size_t o_mu   = o_S    + 512*4;           // mu: N floats
  size_t o_rs   = o_mu   + (size_t)N*4;     // rs: N floats
  size_t required = o_rs + (size_t)N*4;
  if (ws_size < required) return;

  u16*   hF   = (u16*)(wsb + o_hF);
  u16*   T2   = (u16*)(wsb + o_T2);
  u16*   Hpre = T2;
  u16*   Cu   = (u16*)(wsb + o_C);
  u16*   nx   = Cu;
  u16*   EqkF = Cu;
  u16*   Eq0  = Cu + (size_t)N*256;
  u16*   Ek2  = Cu + (size_t)N*384;
  u16*   attn = Cu;
  u16*   outtmp = Cu;
  u16*   Eqk  = (u16*)(wsb + o_eqk);
  u16*   Dqk  = (u16*)(wsb + o_fr);
  float* Fraw = (float*)(wsb + o_fr);
  u16*   FTg  = (u16*)(wsb + o_fr + (size_t)128*2048*4);
  float* cvec = (float*)(wsb + o_fr + (size_t)128*2048*4 + (size_t)2048*128*2);
  u16*   WthT = (u16*)(wsb + o_wth);
  u16*   WqkT = (u16*)(wsb + o_wqk);
  u16*   WoutT= (u16*)(wsb + o_wout);
  float* Bth  = (float*)(wsb + o_bth);
  float* Bqk  = (float*)(wsb + o_bqk);
  float* Bout = (float*)(wsb + o_bout);
  float* hsum = (float*)(wsb + o_hsum);
  float* Svec = (float*)(wsb + o_S);
  float* muv  = (float*)(wsb + o_mu);
  float* rsv  = (float*)(wsb + o_rs);

  // ---- weight prep + zeros ----
  hipLaunchKernelGGL(fuse_wT_kernel, dim3(16, 64), dim3(256), 0, stream, th_ln_g, th_w, WthT, 512, 2048);
  hipLaunchKernelGGL(fuse_wT_kernel, dim3(16, 4),  dim3(256), 0, stream, qk_ln_g, qk_w, WqkT, 512, 128);
  hipLaunchKernelGGL(fuse_wT_kernel, dim3(32, 16), dim3(256), 0, stream, out_ln_g, out_w, WoutT, 1024, 512);
  hipLaunchKernelGGL(copy_bias_kernel, dim3(8), dim3(256), 0, stream, th_b, Bth, 2048);
  hipLaunchKernelGGL(copy_bias_kernel, dim3(1), dim3(256), 0, stream, qk_b, Bqk, 128);
  hipLaunchKernelGGL(copy_bias_kernel, dim3(2), dim3(256), 0, stream, out_b, Bout, 512);
  hipLaunchKernelGGL(fuse_b_acc, dim3(8, 8),  dim3(256), 0, stream, th_ln_b,  th_w,  Bth, 512, 2048);
  hipLaunchKernelGGL(fuse_b_acc, dim3(1, 8),  dim3(256), 0, stream, qk_ln_b,  qk_w,  Bqk, 512, 128);
  hipLaunchKernelGGL(fuse_b_acc, dim3(2, 16), dim3(256), 0, stream, out_ln_b, out_w, Bout, 1024, 512);
  hipLaunchKernelGGL(zero_kernel, dim3(8), dim3(256), 0, stream, hsum, 2048LL);
  // S[c] = sum_k out_ln_g[k]*out_w[k][c]  (column sums of gamma-scaled weights)
  hipLaunchKernelGGL(zero_kernel, dim3(2), dim3(256), 0, stream, Svec, 512LL);
  hipLaunchKernelGGL(fuse_b_acc, dim3(2, 16), dim3(256), 0, stream, out_ln_g, out_w, Svec, 1024, 512);

  // ---- token shift + LN core ----
  hipLaunchKernelGGL(shift_ln_kernel, dim3(N), dim3(256), 0, stream, x, nx, N);

  // ---- th branch, 2 super-chunks of 1024 cols ----
  for (int sc = 0; sc < 2; ++sc) {
    hipLaunchKernelGGL(gemm_mfma_silu, dim3(8, N/128), dim3(256), 0, stream,
                       nx, 512, WthT, 512, sc*1024, Hpre, 1024, Bth, 512);
    hipLaunchKernelGGL(dwconv_hf64, dim3(16, N/64), dim3(256), 0, stream,
                       Hpre, 1024, th_conv + (size_t)sc*1024*17, hF, sc*1024, hsum, N);
  }

  // ---- qk branch ----
  hipLaunchKernelGGL(gemm_mfma_silu, dim3(1, N/128), dim3(256), 0, stream,
                     nx, 512, WqkT, 512, 0, Dqk, 128, Bqk, 512);
  hipLaunchKernelGGL(dwconv_qk, dim3(2, N/32), dim3(256), 0, stream,
                     Dqk, qk_conv, osg, osb, Eqk, Eq0, Ek2, EqkF, N);

  // ---- linear attention kv summary ----
  hipLaunchKernelGGL(zero_kernel, dim3(1024), dim3(256), 0, stream, Fraw, (long long)128*2048);
  hipLaunchKernelGGL(linkv_mfma, dim3(32, 16), dim3(256), 0, stream, EqkF, hF, Fraw, N);
  hipLaunchKernelGGL(fconv_kernel, dim3(8), dim3(256), 0, stream, Fraw, osg, osb, hsum, inv_n, FTg, cvec);

  // ---- quadratic attention scores ----
  hipLaunchKernelGGL(score_mfma2, dim3(2, 2, G), dim3(256), 0, stream, Eq0, Ek2, attn);

  // ---- fused quad + lin + gate -> T2 ----
  hipLaunchKernelGGL(quadlin_mfma, dim3(2*G*16), dim3(256), 0, stream,
                     attn, hF, Eqk, FTg, cvec, T2);

  // ---- out branch: row stats, then GEMM with fused LayerNorm epilogue ----
  hipLaunchKernelGGL(rowstat_kernel, dim3(N), dim3(256), 0, stream, T2, muv, rsv);
  hipLaunchKernelGGL(gemm_mfma_ln_silu, dim3(4, N/128), dim3(256), 0, stream,
                     T2, 1024, WoutT, 1024, outtmp, 512, Bout, Svec, muv, rsv, 1024);
  hipLaunchKernelGGL(dwconv_final64, dim3(8, N/64), dim3(256), 0, stream,
                     outtmp, out_conv, x, (float*)d_out, N);
}

// Round 14
// 384.958 us; speedup vs baseline: 1.0200x; 1.0200x over previous
//
#include <hip/hip_runtime.h>
#include <math.h>

#define GSZ 256

typedef unsigned short u16;
typedef short bf16x8 __attribute__((ext_vector_type(8)));
typedef u16 u16x8 __attribute__((ext_vector_type(8)));
typedef float f32x4 __attribute__((ext_vector_type(4)));
#define MFMA16 __builtin_amdgcn_mfma_f32_16x16x32_bf16

// hF fragment layout: unit(n,c) = hF + (((n>>5)*NCC + (c>>4))*64 + ((n>>3)&3)*16 + (c&15))*8,
// elem n&7.  NCC = 128 for h (2048 cols), 8 for EqkF (128 cols).

__device__ __forceinline__ float bf2f(u16 u){
  union { unsigned int i; float f; } x; x.i = ((unsigned int)u) << 16; return x.f;
}
__device__ __forceinline__ u16 f2bf(float f){
  union { float ff; unsigned int i; } x; x.ff = f;
  unsigned int r = x.i + 0x7fffu + ((x.i >> 16) & 1u);
  return (u16)(r >> 16);
}
__device__ __forceinline__ float sigm(float x){ return 1.0f/(1.0f+__expf(-x)); }
__device__ __forceinline__ float siluf(float x){ return x/(1.0f+__expf(-x)); }

__device__ __forceinline__ void gload16(const void* g, void* l){
  __builtin_amdgcn_global_load_lds(
      (const __attribute__((address_space(1))) void*)g,
      (__attribute__((address_space(3))) void*)l, 16, 0, 0);
}

__device__ __forceinline__ float2 blockReduce2(float s, float ss){
  __shared__ float red[8];
  #pragma unroll
  for (int off=32; off>0; off>>=1){
    s  += __shfl_down(s, off, 64);
    ss += __shfl_down(ss, off, 64);
  }
  int lane = threadIdx.x & 63, wid = threadIdx.x >> 6;
  if (lane==0){ red[wid]=s; red[4+wid]=ss; }
  __syncthreads();
  float2 r;
  r.x = red[0]+red[1]+red[2]+red[3];
  r.y = red[4]+red[5]+red[6]+red[7];
  return r;
}

// ---------------- small prep kernels ----------------

__global__ __launch_bounds__(256) void shift_ln_kernel(
    const float* __restrict__ x, u16* __restrict__ out, int N)
{
  int n = blockIdx.x;
  int t = threadIdx.x;
  float v0 = (n > 0) ? x[(long long)(n-1)*512 + t] : 0.0f;
  float v1 = x[(long long)n*512 + 256 + t];
  float2 r = blockReduce2(v0+v1, fmaf(v0,v0,v1*v1));
  float mu = r.x * (1.0f/512.0f);
  float var = r.y * (1.0f/512.0f) - mu*mu;
  float rs = rsqrtf(var + 1e-5f);
  long long base = (long long)n*512;
  out[base + t]       = f2bf((v0-mu)*rs);
  out[base + 256 + t] = f2bf((v1-mu)*rs);
}

__global__ __launch_bounds__(256) void fuse_wT_kernel(
    const float* __restrict__ g, const float* __restrict__ w,
    u16* __restrict__ wT, int K, int Nn)
{
  __shared__ float sL[32][33];
  int k0 = blockIdx.x*32, n0 = blockIdx.y*32;
  int t = threadIdx.x;
  int r = t >> 3, cq = t & 7;
  float4 v = *(const float4*)(w + (size_t)(k0+r)*Nn + n0 + cq*4);
  float gg = g[k0+r];
  sL[r][cq*4+0] = v.x*gg; sL[r][cq*4+1] = v.y*gg;
  sL[r][cq*4+2] = v.z*gg; sL[r][cq*4+3] = v.w*gg;
  __syncthreads();
  ushort4 o;
  o.x = f2bf(sL[cq*4+0][r]); o.y = f2bf(sL[cq*4+1][r]);
  o.z = f2bf(sL[cq*4+2][r]); o.w = f2bf(sL[cq*4+3][r]);
  *(ushort4*)(wT + (size_t)(n0+r)*K + k0 + cq*4) = o;
}

__global__ void copy_bias_kernel(const float* __restrict__ bias, float* __restrict__ bout, int Nn){
  int i = blockIdx.x*256 + threadIdx.x;
  if (i < Nn) bout[i] = bias[i];
}

__global__ __launch_bounds__(256) void fuse_b_acc(
    const float* __restrict__ bln, const float* __restrict__ w,
    float* __restrict__ bout, int K, int Nn)
{
  int n = blockIdx.x*256 + threadIdx.x;
  int k0 = blockIdx.y*64;
  if (n >= Nn) return;
  float acc = 0.f;
  #pragma unroll
  for (int k = 0; k < 64; ++k)
    acc = fmaf(bln[k0+k], w[(size_t)(k0+k)*Nn + n], acc);
  atomicAdd(&bout[n], acc);
}

__global__ void zero_kernel(float* __restrict__ p, long long total){
  long long i = (long long)blockIdx.x*256 + threadIdx.x;
  if (i < total) p[i] = 0.0f;
}

// ---------------- MFMA kernels (chunk-linear LDS + global_load_lds) --------------
// LDS chunk = 64 units x 16B; unit l of chunk = fragment of lane l.
// MFMA frags: A row=l&15 k=(l>>4)*8+j ; B col=l&15 ; D col=l&15 row=(l>>4)*4+i.
// GEMM family: depth-2 pipeline (3 buffers); quadlin: depth-1 (2 buffers, measured best).

// C = silu(A @ WT^T + bias).  BM=128, BN=128, BK=32, depth-2.
__global__ __launch_bounds__(256) void gemm_mfma_silu(
    const u16* __restrict__ A, int lda,
    const u16* __restrict__ BT, int ldbt, int wtc0,
    u16* __restrict__ C, int ldc,
    const float* __restrict__ bias, int K)
{
  __shared__ u16 lds[3*16*512];
  int t = threadIdx.x;
  int lane = t & 63, wid = t >> 6;
  int wm = wid >> 1, wn = wid & 1;
  int lrow = lane & 15, kcL = lane >> 4;
  int bm = blockIdx.y*128, bn = blockIdx.x*128;
  const u16* gA0 = A + (size_t)(bm + wid*16 + lrow)*lda + kcL*8;
  const u16* gA1 = A + (size_t)(bm + (wid+4)*16 + lrow)*lda + kcL*8;
  const u16* gB0 = BT + (size_t)(wtc0 + bn + wid*16 + lrow)*ldbt + kcL*8;
  const u16* gB1 = BT + (size_t)(wtc0 + bn + (wid+4)*16 + lrow)*ldbt + kcL*8;
  f32x4 acc[4][4] = {};
  int nt = K >> 5;
  auto issue = [&](int ti, u16* b){
    int k1 = ti << 5;
    gload16(gA0 + k1, b + (size_t)wid*512);
    gload16(gA1 + k1, b + (size_t)(wid+4)*512);
    gload16(gB0 + k1, b + (size_t)(8+wid)*512);
    gload16(gB1 + k1, b + (size_t)(12+wid)*512);
  };
  issue(0, lds);
  if (nt > 1) issue(1, lds + 8192);
  for (int ti = 0; ti < nt; ++ti) {
    if (ti + 2 < nt) {
      issue(ti + 2, lds + (size_t)((ti+2)%3)*8192);
      asm volatile("s_waitcnt vmcnt(8)" ::: "memory");
    } else if (ti + 1 < nt) {
      asm volatile("s_waitcnt vmcnt(4)" ::: "memory");
    } else {
      asm volatile("s_waitcnt vmcnt(0)" ::: "memory");
    }
    __builtin_amdgcn_s_barrier();
    asm volatile("" ::: "memory");
    const bf16x8* L = (const bf16x8*)(lds + (size_t)(ti%3)*8192);
    bf16x8 af[4], bfr[4];
    #pragma unroll
    for (int mr = 0; mr < 4; ++mr) af[mr] = L[(wm*4+mr)*64 + lane];
    #pragma unroll
    for (int nr = 0; nr < 4; ++nr) bfr[nr] = L[(8 + wn*4+nr)*64 + lane];
    #pragma unroll
    for (int mr = 0; mr < 4; ++mr)
      #pragma unroll
      for (int nr = 0; nr < 4; ++nr)
        acc[mr][nr] = MFMA16(af[mr], bfr[nr], acc[mr][nr], 0, 0, 0);
    asm volatile("" ::: "memory");
    __builtin_amdgcn_s_barrier();
  }
  #pragma unroll
  for (int mr = 0; mr < 4; ++mr)
    #pragma unroll
    for (int nr = 0; nr < 4; ++nr) {
      int col = bn + wn*64 + nr*16 + lrow;
      float bs = bias[wtc0 + col];
      #pragma unroll
      for (int i = 0; i < 4; ++i) {
        int row = bm + wm*64 + mr*16 + kcL*4 + i;
        C[(size_t)row*ldc + col] = f2bf(siluf(acc[mr][nr][i] + bs));
      }
    }
}

// attn = relu(Eq0 @ Ek2^T / GS)^2 per group — depth-2 GEMM. grid (2, 2, G)
__global__ __launch_bounds__(256) void score_mfma2(
    const u16* __restrict__ Eq0, const u16* __restrict__ Ek2,
    u16* __restrict__ attn)
{
  __shared__ u16 lds[3*16*512];
  int t = threadIdx.x;
  int lane = t & 63, wid = t >> 6;
  int wm = wid >> 1, wn = wid & 1;
  int lrow = lane & 15, kcL = lane >> 4;
  int g = blockIdx.z;
  int bm = blockIdx.y*128, bn = blockIdx.x*128;
  size_t rowbase = (size_t)g * GSZ;
  const u16* gA0 = Eq0 + (rowbase + bm + wid*16 + lrow)*128 + kcL*8;
  const u16* gA1 = Eq0 + (rowbase + bm + (wid+4)*16 + lrow)*128 + kcL*8;
  const u16* gB0 = Ek2 + (rowbase + bn + wid*16 + lrow)*128 + kcL*8;
  const u16* gB1 = Ek2 + (rowbase + bn + (wid+4)*16 + lrow)*128 + kcL*8;
  f32x4 acc[4][4] = {};
  auto issue = [&](int ti, u16* b){
    int k1 = ti << 5;
    gload16(gA0 + k1, b + (size_t)wid*512);
    gload16(gA1 + k1, b + (size_t)(wid+4)*512);
    gload16(gB0 + k1, b + (size_t)(8+wid)*512);
    gload16(gB1 + k1, b + (size_t)(12+wid)*512);
  };
  issue(0, lds);
  issue(1, lds + 8192);
  for (int ti = 0; ti < 4; ++ti) {
    if (ti + 2 < 4) {
      issue(ti + 2, lds + (size_t)((ti+2)%3)*8192);
      asm volatile("s_waitcnt vmcnt(8)" ::: "memory");
    } else if (ti + 1 < 4) {
      asm volatile("s_waitcnt vmcnt(4)" ::: "memory");
    } else {
      asm volatile("s_waitcnt vmcnt(0)" ::: "memory");
    }
    __builtin_amdgcn_s_barrier();
    asm volatile("" ::: "memory");
    const bf16x8* L = (const bf16x8*)(lds + (size_t)(ti%3)*8192);
    bf16x8 af[4], bfr[4];
    #pragma unroll
    for (int mr = 0; mr < 4; ++mr) af[mr] = L[(wm*4+mr)*64 + lane];
    #pragma unroll
    for (int nr = 0; nr < 4; ++nr) bfr[nr] = L[(8 + wn*4+nr)*64 + lane];
    #pragma unroll
    for (int mr = 0; mr < 4; ++mr)
      #pragma unroll
      for (int nr = 0; nr < 4; ++nr)
        acc[mr][nr] = MFMA16(af[mr], bfr[nr], acc[mr][nr], 0, 0, 0);
    asm volatile("" ::: "memory");
    __builtin_amdgcn_s_barrier();
  }
  #pragma unroll
  for (int mr = 0; mr < 4; ++mr)
    #pragma unroll
    for (int nr = 0; nr < 4; ++nr) {
      int col = bn + wn*64 + nr*16 + lrow;
      #pragma unroll
      for (int i = 0; i < 4; ++i) {
        int row = bm + wm*64 + mr*16 + kcL*4 + i;
        float s = fmaxf(acc[mr][nr][i] * (1.0f/GSZ), 0.0f);
        attn[(rowbase + row)*GSZ + col] = f2bf(s*s);
      }
    }
}

// Fraw[d][e] += sum_n EqkF(n,d) * hF(n,e) — pure gload dbuf GEMM. grid (32, 16)
__global__ __launch_bounds__(256) void linkv_mfma(
    const u16* __restrict__ EqkF, const u16* __restrict__ hF,
    float* __restrict__ Fraw, int N)
{
  __shared__ u16 lds[2*12*512];
  int t = threadIdx.x;
  int lane = t & 63, wid = t >> 6;
  int wm = wid >> 1, wn = wid & 1;
  int lrow = lane & 15, kcL = lane >> 4;
  int e0 = blockIdx.x * 64;
  int nkt = (N / gridDim.y) >> 5;
  size_t kt0 = (size_t)blockIdx.y * nkt;
  f32x4 acc[4][2] = {};
  auto issue = [&](int kt, u16* b) {
    size_t ktile = kt0 + kt;
    gload16(EqkF + ((ktile*8 + wid)*64 + lane)*8,           b + (size_t)wid*512);
    gload16(EqkF + ((ktile*8 + wid+4)*64 + lane)*8,         b + (size_t)(wid+4)*512);
    gload16(hF + ((ktile*128 + (e0>>4) + wid)*64 + lane)*8, b + (size_t)(8+wid)*512);
  };
  issue(0, lds);
  int cur = 0;
  for (int ti = 0; ti < nkt; ++ti) {
    if (ti + 1 < nkt) {
      issue(ti + 1, lds + (size_t)(cur^1)*6144);
      asm volatile("s_waitcnt vmcnt(3)" ::: "memory");
    } else {
      asm volatile("s_waitcnt vmcnt(0)" ::: "memory");
    }
    __builtin_amdgcn_s_barrier();
    asm volatile("" ::: "memory");
    const bf16x8* L = (const bf16x8*)(lds + (size_t)cur*6144);
    bf16x8 af[4], bfr[2];
    #pragma unroll
    for (int mr = 0; mr < 4; ++mr) af[mr] = L[(wm*4+mr)*64 + lane];
    #pragma unroll
    for (int nr = 0; nr < 2; ++nr) bfr[nr] = L[(8 + wn*2+nr)*64 + lane];
    #pragma unroll
    for (int mr = 0; mr < 4; ++mr)
      #pragma unroll
      for (int nr = 0; nr < 2; ++nr)
        acc[mr][nr] = MFMA16(af[mr], bfr[nr], acc[mr][nr], 0, 0, 0);
    asm volatile("" ::: "memory");
    __builtin_amdgcn_s_barrier();
    cur ^= 1;
  }
  #pragma unroll
  for (int mr = 0; mr < 4; ++mr)
    #pragma unroll
    for (int nr = 0; nr < 2; ++nr) {
      int e = e0 + wn*32 + nr*16 + lrow;
      #pragma unroll
      for (int i = 0; i < 4; ++i) {
        int d = wm*64 + mr*16 + kcL*4 + i;
        atomicAdd(&Fraw[(size_t)d*2048 + e], acc[mr][nr][i]);
      }
    }
}

// F = inv_n*(g3[d]*Fraw + b3[d]*hsum[e]); FTg[e][d] = g1[d]*F ; cvec[e] = sum_d b1[d]*F
__global__ __launch_bounds__(256) void fconv_kernel(
    const float* __restrict__ Fraw, const float* __restrict__ osg, const float* __restrict__ osb,
    const float* __restrict__ hsum, float inv_n,
    u16* __restrict__ FTg, float* __restrict__ cvec)
{
  __shared__ float g1s[128], b1s[128], g3s[128], b3s[128];
  int t = threadIdx.x;
  if (t < 128) { g1s[t] = osg[128+t]; b1s[t] = osb[128+t];
                 g3s[t] = osg[3*128+t]; b3s[t] = osb[3*128+t]; }
  __syncthreads();
  int e = blockIdx.x*256 + t;
  float hs = hsum[e];
  float c = 0.f;
  for (int d = 0; d < 128; ++d) {
    float f = inv_n * fmaf(g3s[d], Fraw[(size_t)d*2048 + e], b3s[d]*hs);
    c = fmaf(b1s[d], f, c);
    FTg[(size_t)e*128 + d] = f2bf(g1s[d] * f);
  }
  cvec[e] = c;
}

// fused quad+lin attention + gate. 2-buffer depth-1 (measured best: ~64 us). grid 2048.
__global__ __launch_bounds__(256) void quadlin_mfma(
    const u16* __restrict__ attn, const u16* __restrict__ hF,
    const u16* __restrict__ eqk, const u16* __restrict__ FTg,
    const float* __restrict__ cvec, u16* __restrict__ T2)
{
  __shared__ u16 lds[2*16*512];
  int bid = blockIdx.x;
  int wgid = (bid & 7)*256 + (bid >> 3);
  int g = wgid >> 5;
  int rem = wgid & 31;
  int bm = (rem >> 4) * 128;
  int cb = (rem & 15) * 64;
  int t = threadIdx.x;
  int lane = t & 63, wid = t >> 6;
  int wm = wid >> 1, wn = wid & 1;
  int lrow = lane & 15, kcL = lane >> 4;
  size_t rowbase = (size_t)g * GSZ;
  f32x4 accV[4][2] = {}, accU[4][2] = {};
  const u16* gA0q = attn + (rowbase + bm + wid*16 + lrow)*GSZ + kcL*8;
  const u16* gA1q = attn + (rowbase + bm + (wid+4)*16 + lrow)*GSZ + kcL*8;
  const u16* gA0l = eqk + (rowbase + bm + wid*16 + lrow)*128 + kcL*8;
  const u16* gA1l = eqk + (rowbase + bm + (wid+4)*16 + lrow)*128 + kcL*8;
  const u16* gBVl = FTg + (size_t)(cb + wid*16 + lrow)*128 + kcL*8;
  const u16* gBUl = FTg + (size_t)(1024 + cb + wid*16 + lrow)*128 + kcL*8;
  auto issue = [&](int ti, u16* b) {
    if (ti < 8) {
      int k0 = ti << 5;
      size_t ktile = (size_t)g*8 + ti;
      gload16(gA0q + k0, b + (size_t)wid*512);
      gload16(gA1q + k0, b + (size_t)(wid+4)*512);
      gload16(hF + ((ktile*128 + (cb>>4) + wid)*64 + lane)*8,      b + (size_t)(8+wid)*512);
      gload16(hF + ((ktile*128 + 64 + (cb>>4) + wid)*64 + lane)*8, b + (size_t)(12+wid)*512);
    } else {
      int k0 = (ti - 8) << 5;
      gload16(gA0l + k0, b + (size_t)wid*512);
      gload16(gA1l + k0, b + (size_t)(wid+4)*512);
      gload16(gBVl + k0, b + (size_t)(8+wid)*512);
      gload16(gBUl + k0, b + (size_t)(12+wid)*512);
    }
  };
  issue(0, lds);
  int cur = 0;
  for (int ti = 0; ti < 12; ++ti) {
    if (ti + 1 < 12) {
      issue(ti + 1, lds + (size_t)(cur^1)*8192);
      asm volatile("s_waitcnt vmcnt(4)" ::: "memory");
    } else {
      asm volatile("s_waitcnt vmcnt(0)" ::: "memory");
    }
    __builtin_amdgcn_s_barrier();
    asm volatile("" ::: "memory");
    const bf16x8* L = (const bf16x8*)(lds + (size_t)cur*8192);
    bf16x8 af[4], bv[2], bu[2];
    #pragma unroll
    for (int mr = 0; mr < 4; ++mr) af[mr] = L[(wm*4+mr)*64 + lane];
    #pragma unroll
    for (int nr = 0; nr < 2; ++nr) { bv[nr] = L[(8 + wn*2+nr)*64 + lane];
                                     bu[nr] = L[(12 + wn*2+nr)*64 + lane]; }
    #pragma unroll
    for (int mr = 0; mr < 4; ++mr)
      #pragma unroll
      for (int nr = 0; nr < 2; ++nr) {
        accV[mr][nr] = MFMA16(af[mr], bv[nr], accV[mr][nr], 0, 0, 0);
        accU[mr][nr] = MFMA16(af[mr], bu[nr], accU[mr][nr], 0, 0, 0);
      }
    asm volatile("" ::: "memory");
    __builtin_amdgcn_s_barrier();
    cur ^= 1;
  }
  #pragma unroll
  for (int mr = 0; mr < 4; ++mr)
    #pragma unroll
    for (int nr = 0; nr < 2; ++nr) {
      int c = cb + wn*32 + nr*16 + lrow;
      float cV = cvec[c], cU = cvec[1024 + c];
      int np = bm + wm*64 + mr*16 + kcL*4;
      size_t ktile = (size_t)g*8 + (np>>5);
      int lofs = ((np>>3)&3)*16 + (c&15);
      int eo = np & 7;
      ushort4 vq = *(const ushort4*)(hF + ((ktile*128 + (c>>4))*64 + lofs)*8 + eo);
      ushort4 uq = *(const ushort4*)(hF + ((ktile*128 + 64 + (c>>4))*64 + lofs)*8 + eo);
      float vv[4] = {bf2f(vq.x), bf2f(vq.y), bf2f(vq.z), bf2f(vq.w)};
      float uu[4] = {bf2f(uq.x), bf2f(uq.y), bf2f(uq.z), bf2f(uq.w)};
      #pragma unroll
      for (int i = 0; i < 4; ++i) {
        float av = accV[mr][nr][i] + cV;
        float au = accU[mr][nr][i] + cU;
        T2[(rowbase + np + i)*1024 + c] = f2bf(au * vv[i] * sigm(av * uu[i]));
      }
    }
}

// ---------------- conv / norm kernels ----------------

// th-branch depthwise conv, 64-row tiles -> hF + hsum. grid (cols/64, N/64)
__global__ __launch_bounds__(256) void dwconv_hf64(
    const u16* __restrict__ xin, int ldin, const float* __restrict__ kern,
    u16* __restrict__ hF, int colbase, float* __restrict__ hsum, int N)
{
  __shared__ float tile[80][64];
  __shared__ float psum[4][64];
  int c0 = blockIdx.x * 64;
  int n0 = blockIdx.y * 64;
  int t = threadIdx.x;
  int tx = t & 63, ty = t >> 6;
  #pragma unroll
  for (int it = 0; it < 5; ++it) {
    int idx = t + it*256;
    int r = idx >> 4, cq = (idx & 15)*4;
    int gn = n0 - 8 + r;
    float4 f;
    if (gn >= 0 && gn < N) {
      ushort4 q = *(const ushort4*)(xin + (size_t)gn*ldin + c0 + cq);
      f.x = bf2f(q.x); f.y = bf2f(q.y); f.z = bf2f(q.z); f.w = bf2f(q.w);
    } else { f.x = 0.f; f.y = 0.f; f.z = 0.f; f.w = 0.f; }
    *(float4*)&tile[r][cq] = f;
  }
  __syncthreads();
  int chl = c0 + tx;
  float kr[17];
  #pragma unroll
  for (int k = 0; k < 17; ++k) kr[k] = kern[chl*17 + k];
  int c = colbase + chl;
  float loc = 0.f;
  #pragma unroll
  for (int u = 0; u < 2; ++u) {
    u16x8 o;
    #pragma unroll
    for (int rr = 0; rr < 8; ++rr) {
      int r = ty*16 + u*8 + rr;
      float s = 0.0f;
      #pragma unroll
      for (int k = 0; k < 17; ++k) s = fmaf(kr[k], tile[r+k][tx], s);
      float val = tile[r+8][tx] + s;
      loc += val;
      o[rr] = f2bf(val);
    }
    int nn = n0 + ty*16 + u*8;
    *(u16x8*)(hF + ((((size_t)(nn>>5))*128 + (c>>4))*64 + ((nn>>3)&3)*16 + (c&15))*8) = o;
  }
  psum[ty][tx] = loc;
  __syncthreads();
  if (t < 64)
    atomicAdd(&hsum[colbase + c0 + t], psum[0][t]+psum[1][t]+psum[2][t]+psum[3][t]);
}

// qk dwconv (32-row): writes Eqk, Eq0, Ek2 (row-major), EqkF (fragment). grid (2, N/32)
__global__ __launch_bounds__(256) void dwconv_qk(
    const u16* __restrict__ xin, const float* __restrict__ kern,
    const float* __restrict__ osg, const float* __restrict__ osb,
    u16* __restrict__ Eqk, u16* __restrict__ Eq0, u16* __restrict__ Ek2,
    u16* __restrict__ EqkF, int N)
{
  __shared__ float tile[48][64];
  int c0 = blockIdx.x * 64;
  int n0 = blockIdx.y * 32;
  int t = threadIdx.x;
  int tx = t & 63, ty = t >> 6;
  #pragma unroll
  for (int it = 0; it < 3; ++it) {
    int idx = t + it*256;
    int r = idx >> 4, cq = (idx & 15)*4;
    int gn = n0 - 8 + r;
    float4 f;
    if (gn >= 0 && gn < N) {
      ushort4 q = *(const ushort4*)(xin + (size_t)gn*128 + c0 + cq);
      f.x = bf2f(q.x); f.y = bf2f(q.y); f.z = bf2f(q.z); f.w = bf2f(q.w);
    } else { f.x = 0.f; f.y = 0.f; f.z = 0.f; f.w = 0.f; }
    *(float4*)&tile[r][cq] = f;
  }
  __syncthreads();
  int ch = c0 + tx;
  float kr[17];
  #pragma unroll
  for (int k = 0; k < 17; ++k) kr[k] = kern[ch*17 + k];
  float g0 = osg[ch], b0 = osb[ch];
  float g2 = osg[2*128+ch], b2 = osb[2*128+ch];
  float vals[8];
  #pragma unroll
  for (int rr = 0; rr < 8; ++rr) {
    int r = ty*8 + rr;
    float s = 0.0f;
    #pragma unroll
    for (int k = 0; k < 17; ++k) s = fmaf(kr[k], tile[r+k][tx], s);
    vals[rr] = tile[r+8][tx] + s;
    size_t gi = (size_t)(n0 + r)*128 + ch;
    Eqk[gi] = f2bf(vals[rr]);
    Eq0[gi] = f2bf(fmaf(vals[rr], g0, b0));
    Ek2[gi] = f2bf(fmaf(vals[rr], g2, b2));
  }
  u16x8 o;
  #pragma unroll
  for (int rr = 0; rr < 8; ++rr) o[rr] = f2bf(vals[rr]);
  *(u16x8*)(EqkF + ((((size_t)(n0>>5))*8 + (ch>>4))*64 + ty*16 + (ch&15))*8) = o;
}

// final conv, 64-row tiles: out = resid + x + conv(x). grid (8, N/64)
__global__ __launch_bounds__(256) void dwconv_final64(
    const u16* __restrict__ xin, const float* __restrict__ kern,
    const float* __restrict__ resid, float* __restrict__ y, int N)
{
  __shared__ float tile[80][64];
  int c0 = blockIdx.x * 64;
  int n0 = blockIdx.y * 64;
  int t = threadIdx.x;
  int tx = t & 63, ty = t >> 6;
  #pragma unroll
  for (int it = 0; it < 5; ++it) {
    int idx = t + it*256;
    int r = idx >> 4, cq = (idx & 15)*4;
    int gn = n0 - 8 + r;
    float4 f;
    if (gn >= 0 && gn < N) {
      ushort4 q = *(const ushort4*)(xin + (size_t)gn*512 + c0 + cq);
      f.x = bf2f(q.x); f.y = bf2f(q.y); f.z = bf2f(q.z); f.w = bf2f(q.w);
    } else { f.x = 0.f; f.y = 0.f; f.z = 0.f; f.w = 0.f; }
    *(float4*)&tile[r][cq] = f;
  }
  __syncthreads();
  int ch = c0 + tx;
  float kr[17];
  #pragma unroll
  for (int k = 0; k < 17; ++k) kr[k] = kern[ch*17 + k];
  #pragma unroll
  for (int rr = 0; rr < 16; ++rr) {
    int r = ty*16 + rr;
    float s = 0.0f;
    #pragma unroll
    for (int k = 0; k < 17; ++k) s = fmaf(kr[k], tile[r+k][tx], s);
    size_t gi = (size_t)(n0 + r)*512 + ch;
    y[gi] = resid[gi] + tile[r+8][tx] + s;
  }
}

__global__ __launch_bounds__(256) void ln1024_kernel(u16* __restrict__ buf)
{
  long long n = blockIdx.x;
  ushort4* p = (ushort4*)(buf + n*1024) + threadIdx.x;
  ushort4 q = *p;
  float a = bf2f(q.x), b = bf2f(q.y), c = bf2f(q.z), d = bf2f(q.w);
  float s = a+b+c+d;
  float ss = fmaf(a,a, fmaf(b,b, fmaf(c,c, d*d)));
  float2 r = blockReduce2(s, ss);
  float mu = r.x * (1.0f/1024.0f);
  float var = r.y * (1.0f/1024.0f) - mu*mu;
  float rs = rsqrtf(var + 1e-5f);
  q.x = f2bf((a-mu)*rs); q.y = f2bf((b-mu)*rs);
  q.z = f2bf((c-mu)*rs); q.w = f2bf((d-mu)*rs);
  *p = q;
}

// ---------------- host launcher ----------------

extern "C" void kernel_launch(void* const* d_in, const int* in_sizes, int n_in,
                              void* d_out, int out_size, void* d_ws, size_t ws_size,
                              hipStream_t stream)
{
  const float* x        = (const float*)d_in[0];
  const float* th_ln_g  = (const float*)d_in[2];
  const float* th_ln_b  = (const float*)d_in[3];
  const float* th_w     = (const float*)d_in[4];
  const float* th_b     = (const float*)d_in[5];
  const float* th_conv  = (const float*)d_in[6];
  const float* qk_ln_g  = (const float*)d_in[7];
  const float* qk_ln_b  = (const float*)d_in[8];
  const float* qk_w     = (const float*)d_in[9];
  const float* qk_b     = (const float*)d_in[10];
  const float* qk_conv  = (const float*)d_in[11];
  const float* osg      = (const float*)d_in[12];
  const float* osb      = (const float*)d_in[13];
  const float* out_ln_g = (const float*)d_in[14];
  const float* out_ln_b = (const float*)d_in[15];
  const float* out_w    = (const float*)d_in[16];
  const float* out_b    = (const float*)d_in[17];
  const float* out_conv = (const float*)d_in[18];

  const int N = in_sizes[0] / 512;          // 16384
  const float inv_n = 1.0f / (float)N;
  const int G = N / GSZ;                    // 64
  char* wsb = (char*)d_ws;

  // ---- workspace layout (bytes), lifetime-aliased ----
  size_t o_hF   = 0;
  size_t o_T2   = o_hF  + (size_t)N*2048*2;
  size_t o_C    = o_T2  + (size_t)N*1024*2;
  size_t o_eqk  = o_C   + (size_t)N*512*2;
  size_t o_fr   = o_eqk + (size_t)N*128*2;
  size_t o_wth  = o_fr  + (size_t)N*128*2;
  size_t o_wqk  = o_wth + (size_t)2048*512*2;
  size_t o_wout = o_wqk + (size_t)128*512*2;
  size_t o_bth  = o_wout+ (size_t)1024*512*2;
  size_t o_bqk  = o_bth + 2048*4;
  size_t o_bout = o_bqk + 128*4;
  size_t o_hsum = o_bout + 512*4;
  size_t required = o_hsum + 2048*4;
  if (ws_size < required) return;

  u16*   hF   = (u16*)(wsb + o_hF);
  u16*   T2   = (u16*)(wsb + o_T2);
  u16*   Hpre = T2;
  u16*   Cu   = (u16*)(wsb + o_C);
  u16*   nx   = Cu;
  u16*   EqkF = Cu;
  u16*   Eq0  = Cu + (size_t)N*256;
  u16*   Ek2  = Cu + (size_t)N*384;
  u16*   attn = Cu;
  u16*   outtmp = Cu;
  u16*   Eqk  = (u16*)(wsb + o_eqk);
  u16*   Dqk  = (u16*)(wsb + o_fr);
  float* Fraw = (float*)(wsb + o_fr);
  u16*   FTg  = (u16*)(wsb + o_fr + (size_t)128*2048*4);
  float* cvec = (float*)(wsb + o_fr + (size_t)128*2048*4 + (size_t)2048*128*2);
  u16*   WthT = (u16*)(wsb + o_wth);
  u16*   WqkT = (u16*)(wsb + o_wqk);
  u16*   WoutT= (u16*)(wsb + o_wout);
  float* Bth  = (float*)(wsb + o_bth);
  float* Bqk  = (float*)(wsb + o_bqk);
  float* Bout = (float*)(wsb + o_bout);
  float* hsum = (float*)(wsb + o_hsum);

  // ---- weight prep + zeros ----
  hipLaunchKernelGGL(fuse_wT_kernel, dim3(16, 64), dim3(256), 0, stream, th_ln_g, th_w, WthT, 512, 2048);
  hipLaunchKernelGGL(fuse_wT_kernel, dim3(16, 4),  dim3(256), 0, stream, qk_ln_g, qk_w, WqkT, 512, 128);
  hipLaunchKernelGGL(fuse_wT_kernel, dim3(32, 16), dim3(256), 0, stream, out_ln_g, out_w, WoutT, 1024, 512);
  hipLaunchKernelGGL(copy_bias_kernel, dim3(8), dim3(256), 0, stream, th_b, Bth, 2048);
  hipLaunchKernelGGL(copy_bias_kernel, dim3(1), dim3(256), 0, stream, qk_b, Bqk, 128);
  hipLaunchKernelGGL(copy_bias_kernel, dim3(2), dim3(256), 0, stream, out_b, Bout, 512);
  hipLaunchKernelGGL(fuse_b_acc, dim3(8, 8),  dim3(256), 0, stream, th_ln_b,  th_w,  Bth, 512, 2048);
  hipLaunchKernelGGL(fuse_b_acc, dim3(1, 8),  dim3(256), 0, stream, qk_ln_b,  qk_w,  Bqk, 512, 128);
  hipLaunchKernelGGL(fuse_b_acc, dim3(2, 16), dim3(256), 0, stream, out_ln_b, out_w, Bout, 1024, 512);
  hipLaunchKernelGGL(zero_kernel, dim3(8), dim3(256), 0, stream, hsum, 2048LL);

  // ---- token shift + LN core ----
  hipLaunchKernelGGL(shift_ln_kernel, dim3(N), dim3(256), 0, stream, x, nx, N);

  // ---- th branch, 2 super-chunks of 1024 cols ----
  for (int sc = 0; sc < 2; ++sc) {
    hipLaunchKernelGGL(gemm_mfma_silu, dim3(8, N/128), dim3(256), 0, stream,
                       nx, 512, WthT, 512, sc*1024, Hpre, 1024, Bth, 512);
    hipLaunchKernelGGL(dwconv_hf64, dim3(16, N/64), dim3(256), 0, stream,
                       Hpre, 1024, th_conv + (size_t)sc*1024*17, hF, sc*1024, hsum, N);
  }

  // ---- qk branch ----
  hipLaunchKernelGGL(gemm_mfma_silu, dim3(1, N/128), dim3(256), 0, stream,
                     nx, 512, WqkT, 512, 0, Dqk, 128, Bqk, 512);
  hipLaunchKernelGGL(dwconv_qk, dim3(2, N/32), dim3(256), 0, stream,
                     Dqk, qk_conv, osg, osb, Eqk, Eq0, Ek2, EqkF, N);

  // ---- linear attention kv summary ----
  hipLaunchKernelGGL(zero_kernel, dim3(1024), dim3(256), 0, stream, Fraw, (long long)128*2048);
  hipLaunchKernelGGL(linkv_mfma, dim3(32, 16), dim3(256), 0, stream, EqkF, hF, Fraw, N);
  hipLaunchKernelGGL(fconv_kernel, dim3(8), dim3(256), 0, stream, Fraw, osg, osb, hsum, inv_n, FTg, cvec);

  // ---- quadratic attention scores ----
  hipLaunchKernelGGL(score_mfma2, dim3(2, 2, G), dim3(256), 0, stream, Eq0, Ek2, attn);

  // ---- fused quad + lin + gate -> T2 ----
  hipLaunchKernelGGL(quadlin_mfma, dim3(2*G*16), dim3(256), 0, stream,
                     attn, hF, Eqk, FTg, cvec, T2);

  // ---- out branch ----
  hipLaunchKernelGGL(ln1024_kernel, dim3(N), dim3(256), 0, stream, T2);
  hipLaunchKernelGGL(gemm_mfma_silu, dim3(4, N/128), dim3(256), 0, stream,
                     T2, 1024, WoutT, 1024, 0, outtmp, 512, Bout, 1024);
  hipLaunchKernelGGL(dwconv_final64, dim3(8, N/64), dim3(256), 0, stream,
                     outtmp, out_conv, x, (float*)d_out, N);
}

// Round 15
// 384.178 us; speedup vs baseline: 1.0220x; 1.0020x over previous
//
#include <hip/hip_runtime.h>
#include <math.h>

#define GSZ 256

typedef unsigned short u16;
typedef short bf16x8 __attribute__((ext_vector_type(8)));
typedef u16 u16x8 __attribute__((ext_vector_type(8)));
typedef float f32x4 __attribute__((ext_vector_type(4)));
#define MFMA16 __builtin_amdgcn_mfma_f32_16x16x32_bf16

// hF fragment layout: unit(n,c) = hF + (((n>>5)*NCC + (c>>4))*64 + ((n>>3)&3)*16 + (c&15))*8,
// elem n&7.  NCC = 128 for h (2048 cols), 8 for EqkF (128 cols).

__device__ __forceinline__ float bf2f(u16 u){
  union { unsigned int i; float f; } x; x.i = ((unsigned int)u) << 16; return x.f;
}
__device__ __forceinline__ u16 f2bf(float f){
  union { float ff; unsigned int i; } x; x.ff = f;
  unsigned int r = x.i + 0x7fffu + ((x.i >> 16) & 1u);
  return (u16)(r >> 16);
}
__device__ __forceinline__ float sigm(float x){ return 1.0f/(1.0f+__expf(-x)); }
__device__ __forceinline__ float siluf(float x){ return x/(1.0f+__expf(-x)); }

__device__ __forceinline__ void gload16(const void* g, void* l){
  __builtin_amdgcn_global_load_lds(
      (const __attribute__((address_space(1))) void*)g,
      (__attribute__((address_space(3))) void*)l, 16, 0, 0);
}

__device__ __forceinline__ float2 blockReduce2(float s, float ss){
  __shared__ float red[8];
  #pragma unroll
  for (int off=32; off>0; off>>=1){
    s  += __shfl_down(s, off, 64);
    ss += __shfl_down(ss, off, 64);
  }
  int lane = threadIdx.x & 63, wid = threadIdx.x >> 6;
  if (lane==0){ red[wid]=s; red[4+wid]=ss; }
  __syncthreads();
  float2 r;
  r.x = red[0]+red[1]+red[2]+red[3];
  r.y = red[4]+red[5]+red[6]+red[7];
  return r;
}

// ---------------- small prep kernels ----------------

__global__ __launch_bounds__(256) void shift_ln_kernel(
    const float* __restrict__ x, u16* __restrict__ out, int N)
{
  int n = blockIdx.x;
  int t = threadIdx.x;
  float v0 = (n > 0) ? x[(long long)(n-1)*512 + t] : 0.0f;
  float v1 = x[(long long)n*512 + 256 + t];
  float2 r = blockReduce2(v0+v1, fmaf(v0,v0,v1*v1));
  float mu = r.x * (1.0f/512.0f);
  float var = r.y * (1.0f/512.0f) - mu*mu;
  float rs = rsqrtf(var + 1e-5f);
  long long base = (long long)n*512;
  out[base + t]       = f2bf((v0-mu)*rs);
  out[base + 256 + t] = f2bf((v1-mu)*rs);
}

__global__ __launch_bounds__(256) void fuse_wT_kernel(
    const float* __restrict__ g, const float* __restrict__ w,
    u16* __restrict__ wT, int K, int Nn)
{
  __shared__ float sL[32][33];
  int k0 = blockIdx.x*32, n0 = blockIdx.y*32;
  int t = threadIdx.x;
  int r = t >> 3, cq = t & 7;
  float4 v = *(const float4*)(w + (size_t)(k0+r)*Nn + n0 + cq*4);
  float gg = g[k0+r];
  sL[r][cq*4+0] = v.x*gg; sL[r][cq*4+1] = v.y*gg;
  sL[r][cq*4+2] = v.z*gg; sL[r][cq*4+3] = v.w*gg;
  __syncthreads();
  ushort4 o;
  o.x = f2bf(sL[cq*4+0][r]); o.y = f2bf(sL[cq*4+1][r]);
  o.z = f2bf(sL[cq*4+2][r]); o.w = f2bf(sL[cq*4+3][r]);
  *(ushort4*)(wT + (size_t)(n0+r)*K + k0 + cq*4) = o;
}

__global__ void copy_bias_kernel(const float* __restrict__ bias, float* __restrict__ bout, int Nn){
  int i = blockIdx.x*256 + threadIdx.x;
  if (i < Nn) bout[i] = bias[i];
}

__global__ __launch_bounds__(256) void fuse_b_acc(
    const float* __restrict__ bln, const float* __restrict__ w,
    float* __restrict__ bout, int K, int Nn)
{
  int n = blockIdx.x*256 + threadIdx.x;
  int k0 = blockIdx.y*64;
  if (n >= Nn) return;
  float acc = 0.f;
  #pragma unroll
  for (int k = 0; k < 64; ++k)
    acc = fmaf(bln[k0+k], w[(size_t)(k0+k)*Nn + n], acc);
  atomicAdd(&bout[n], acc);
}

__global__ void zero_kernel(float* __restrict__ p, long long total){
  long long i = (long long)blockIdx.x*256 + threadIdx.x;
  if (i < total) p[i] = 0.0f;
}

// ---------------- MFMA kernels (chunk-linear LDS + global_load_lds) --------------
// LDS chunk = 64 units x 16B; unit l of chunk = fragment of lane l.
// MFMA frags: A row=l&15 k=(l>>4)*8+j ; B col=l&15 ; D col=l&15 row=(l>>4)*4+i.
// GEMM family: depth-2 pipeline (3 buffers); quadlin: depth-1 (2 buffers, measured best).

// C = silu(A @ WT^T + bias).  BM=128, BN=128, BK=32, depth-2.
// 1D grid nwg = nbn*nbm (nwg%8==0); bijective XCD co-location: all blocks sharing
// an A-panel (same bm) land on one XCD -> A-panel stays in that XCD's L2.
__global__ __launch_bounds__(256) void gemm_mfma_silu(
    const u16* __restrict__ A, int lda,
    const u16* __restrict__ BT, int ldbt, int wtc0,
    u16* __restrict__ C, int ldc,
    const float* __restrict__ bias, int K, int nbn)
{
  __shared__ u16 lds[3*16*512];
  int nwg = gridDim.x;
  int bid = blockIdx.x;
  int gidx = (bid & 7) * (nwg >> 3) + (bid >> 3);   // bijective (nwg%8==0)
  int bm = (gidx / nbn) * 128;
  int bn = (gidx % nbn) * 128;
  int t = threadIdx.x;
  int lane = t & 63, wid = t >> 6;
  int wm = wid >> 1, wn = wid & 1;
  int lrow = lane & 15, kcL = lane >> 4;
  const u16* gA0 = A + (size_t)(bm + wid*16 + lrow)*lda + kcL*8;
  const u16* gA1 = A + (size_t)(bm + (wid+4)*16 + lrow)*lda + kcL*8;
  const u16* gB0 = BT + (size_t)(wtc0 + bn + wid*16 + lrow)*ldbt + kcL*8;
  const u16* gB1 = BT + (size_t)(wtc0 + bn + (wid+4)*16 + lrow)*ldbt + kcL*8;
  f32x4 acc[4][4] = {};
  int nt = K >> 5;
  auto issue = [&](int ti, u16* b){
    int k1 = ti << 5;
    gload16(gA0 + k1, b + (size_t)wid*512);
    gload16(gA1 + k1, b + (size_t)(wid+4)*512);
    gload16(gB0 + k1, b + (size_t)(8+wid)*512);
    gload16(gB1 + k1, b + (size_t)(12+wid)*512);
  };
  issue(0, lds);
  if (nt > 1) issue(1, lds + 8192);
  for (int ti = 0; ti < nt; ++ti) {
    if (ti + 2 < nt) {
      issue(ti + 2, lds + (size_t)((ti+2)%3)*8192);
      asm volatile("s_waitcnt vmcnt(8)" ::: "memory");
    } else if (ti + 1 < nt) {
      asm volatile("s_waitcnt vmcnt(4)" ::: "memory");
    } else {
      asm volatile("s_waitcnt vmcnt(0)" ::: "memory");
    }
    __builtin_amdgcn_s_barrier();
    asm volatile("" ::: "memory");
    const bf16x8* L = (const bf16x8*)(lds + (size_t)(ti%3)*8192);
    bf16x8 af[4], bfr[4];
    #pragma unroll
    for (int mr = 0; mr < 4; ++mr) af[mr] = L[(wm*4+mr)*64 + lane];
    #pragma unroll
    for (int nr = 0; nr < 4; ++nr) bfr[nr] = L[(8 + wn*4+nr)*64 + lane];
    #pragma unroll
    for (int mr = 0; mr < 4; ++mr)
      #pragma unroll
      for (int nr = 0; nr < 4; ++nr)
        acc[mr][nr] = MFMA16(af[mr], bfr[nr], acc[mr][nr], 0, 0, 0);
    asm volatile("" ::: "memory");
    __builtin_amdgcn_s_barrier();
  }
  #pragma unroll
  for (int mr = 0; mr < 4; ++mr)
    #pragma unroll
    for (int nr = 0; nr < 4; ++nr) {
      int col = bn + wn*64 + nr*16 + lrow;
      float bs = bias[wtc0 + col];
      #pragma unroll
      for (int i = 0; i < 4; ++i) {
        int row = bm + wm*64 + mr*16 + kcL*4 + i;
        C[(size_t)row*ldc + col] = f2bf(siluf(acc[mr][nr][i] + bs));
      }
    }
}

// attn = relu(Eq0 @ Ek2^T / GS)^2 per group — depth-2 GEMM. grid (2, 2, G)
__global__ __launch_bounds__(256) void score_mfma2(
    const u16* __restrict__ Eq0, const u16* __restrict__ Ek2,
    u16* __restrict__ attn)
{
  __shared__ u16 lds[3*16*512];
  int t = threadIdx.x;
  int lane = t & 63, wid = t >> 6;
  int wm = wid >> 1, wn = wid & 1;
  int lrow = lane & 15, kcL = lane >> 4;
  int g = blockIdx.z;
  int bm = blockIdx.y*128, bn = blockIdx.x*128;
  size_t rowbase = (size_t)g * GSZ;
  const u16* gA0 = Eq0 + (rowbase + bm + wid*16 + lrow)*128 + kcL*8;
  const u16* gA1 = Eq0 + (rowbase + bm + (wid+4)*16 + lrow)*128 + kcL*8;
  const u16* gB0 = Ek2 + (rowbase + bn + wid*16 + lrow)*128 + kcL*8;
  const u16* gB1 = Ek2 + (rowbase + bn + (wid+4)*16 + lrow)*128 + kcL*8;
  f32x4 acc[4][4] = {};
  auto issue = [&](int ti, u16* b){
    int k1 = ti << 5;
    gload16(gA0 + k1, b + (size_t)wid*512);
    gload16(gA1 + k1, b + (size_t)(wid+4)*512);
    gload16(gB0 + k1, b + (size_t)(8+wid)*512);
    gload16(gB1 + k1, b + (size_t)(12+wid)*512);
  };
  issue(0, lds);
  issue(1, lds + 8192);
  for (int ti = 0; ti < 4; ++ti) {
    if (ti + 2 < 4) {
      issue(ti + 2, lds + (size_t)((ti+2)%3)*8192);
      asm volatile("s_waitcnt vmcnt(8)" ::: "memory");
    } else if (ti + 1 < 4) {
      asm volatile("s_waitcnt vmcnt(4)" ::: "memory");
    } else {
      asm volatile("s_waitcnt vmcnt(0)" ::: "memory");
    }
    __builtin_amdgcn_s_barrier();
    asm volatile("" ::: "memory");
    const bf16x8* L = (const bf16x8*)(lds + (size_t)(ti%3)*8192);
    bf16x8 af[4], bfr[4];
    #pragma unroll
    for (int mr = 0; mr < 4; ++mr) af[mr] = L[(wm*4+mr)*64 + lane];
    #pragma unroll
    for (int nr = 0; nr < 4; ++nr) bfr[nr] = L[(8 + wn*4+nr)*64 + lane];
    #pragma unroll
    for (int mr = 0; mr < 4; ++mr)
      #pragma unroll
      for (int nr = 0; nr < 4; ++nr)
        acc[mr][nr] = MFMA16(af[mr], bfr[nr], acc[mr][nr], 0, 0, 0);
    asm volatile("" ::: "memory");
    __builtin_amdgcn_s_barrier();
  }
  #pragma unroll
  for (int mr = 0; mr < 4; ++mr)
    #pragma unroll
    for (int nr = 0; nr < 4; ++nr) {
      int col = bn + wn*64 + nr*16 + lrow;
      #pragma unroll
      for (int i = 0; i < 4; ++i) {
        int row = bm + wm*64 + mr*16 + kcL*4 + i;
        float s = fmaxf(acc[mr][nr][i] * (1.0f/GSZ), 0.0f);
        attn[(rowbase + row)*GSZ + col] = f2bf(s*s);
      }
    }
}

// Fraw[d][e] += sum_n EqkF(n,d) * hF(n,e) — pure gload dbuf GEMM. grid (32, 16)
__global__ __launch_bounds__(256) void linkv_mfma(
    const u16* __restrict__ EqkF, const u16* __restrict__ hF,
    float* __restrict__ Fraw, int N)
{
  __shared__ u16 lds[2*12*512];
  int t = threadIdx.x;
  int lane = t & 63, wid = t >> 6;
  int wm = wid >> 1, wn = wid & 1;
  int lrow = lane & 15, kcL = lane >> 4;
  int e0 = blockIdx.x * 64;
  int nkt = (N / gridDim.y) >> 5;
  size_t kt0 = (size_t)blockIdx.y * nkt;
  f32x4 acc[4][2] = {};
  auto issue = [&](int kt, u16* b) {
    size_t ktile = kt0 + kt;
    gload16(EqkF + ((ktile*8 + wid)*64 + lane)*8,           b + (size_t)wid*512);
    gload16(EqkF + ((ktile*8 + wid+4)*64 + lane)*8,         b + (size_t)(wid+4)*512);
    gload16(hF + ((ktile*128 + (e0>>4) + wid)*64 + lane)*8, b + (size_t)(8+wid)*512);
  };
  issue(0, lds);
  int cur = 0;
  for (int ti = 0; ti < nkt; ++ti) {
    if (ti + 1 < nkt) {
      issue(ti + 1, lds + (size_t)(cur^1)*6144);
      asm volatile("s_waitcnt vmcnt(3)" ::: "memory");
    } else {
      asm volatile("s_waitcnt vmcnt(0)" ::: "memory");
    }
    __builtin_amdgcn_s_barrier();
    asm volatile("" ::: "memory");
    const bf16x8* L = (const bf16x8*)(lds + (size_t)cur*6144);
    bf16x8 af[4], bfr[2];
    #pragma unroll
    for (int mr = 0; mr < 4; ++mr) af[mr] = L[(wm*4+mr)*64 + lane];
    #pragma unroll
    for (int nr = 0; nr < 2; ++nr) bfr[nr] = L[(8 + wn*2+nr)*64 + lane];
    #pragma unroll
    for (int mr = 0; mr < 4; ++mr)
      #pragma unroll
      for (int nr = 0; nr < 2; ++nr)
        acc[mr][nr] = MFMA16(af[mr], bfr[nr], acc[mr][nr], 0, 0, 0);
    asm volatile("" ::: "memory");
    __builtin_amdgcn_s_barrier();
    cur ^= 1;
  }
  #pragma unroll
  for (int mr = 0; mr < 4; ++mr)
    #pragma unroll
    for (int nr = 0; nr < 2; ++nr) {
      int e = e0 + wn*32 + nr*16 + lrow;
      #pragma unroll
      for (int i = 0; i < 4; ++i) {
        int d = wm*64 + mr*16 + kcL*4 + i;
        atomicAdd(&Fraw[(size_t)d*2048 + e], acc[mr][nr][i]);
      }
    }
}

// F = inv_n*(g3[d]*Fraw + b3[d]*hsum[e]); FTg[e][d] = g1[d]*F ; cvec[e] = sum_d b1[d]*F
__global__ __launch_bounds__(256) void fconv_kernel(
    const float* __restrict__ Fraw, const float* __restrict__ osg, const float* __restrict__ osb,
    const float* __restrict__ hsum, float inv_n,
    u16* __restrict__ FTg, float* __restrict__ cvec)
{
  __shared__ float g1s[128], b1s[128], g3s[128], b3s[128];
  int t = threadIdx.x;
  if (t < 128) { g1s[t] = osg[128+t]; b1s[t] = osb[128+t];
                 g3s[t] = osg[3*128+t]; b3s[t] = osb[3*128+t]; }
  __syncthreads();
  int e = blockIdx.x*256 + t;
  float hs = hsum[e];
  float c = 0.f;
  for (int d = 0; d < 128; ++d) {
    float f = inv_n * fmaf(g3s[d], Fraw[(size_t)d*2048 + e], b3s[d]*hs);
    c = fmaf(b1s[d], f, c);
    FTg[(size_t)e*128 + d] = f2bf(g1s[d] * f);
  }
  cvec[e] = c;
}

// fused quad+lin attention + gate. 2-buffer depth-1 (measured best: ~64 us). grid 2048.
__global__ __launch_bounds__(256) void quadlin_mfma(
    const u16* __restrict__ attn, const u16* __restrict__ hF,
    const u16* __restrict__ eqk, const u16* __restrict__ FTg,
    const float* __restrict__ cvec, u16* __restrict__ T2)
{
  __shared__ u16 lds[2*16*512];
  int bid = blockIdx.x;
  int wgid = (bid & 7)*256 + (bid >> 3);
  int g = wgid >> 5;
  int rem = wgid & 31;
  int bm = (rem >> 4) * 128;
  int cb = (rem & 15) * 64;
  int t = threadIdx.x;
  int lane = t & 63, wid = t >> 6;
  int wm = wid >> 1, wn = wid & 1;
  int lrow = lane & 15, kcL = lane >> 4;
  size_t rowbase = (size_t)g * GSZ;
  f32x4 accV[4][2] = {}, accU[4][2] = {};
  const u16* gA0q = attn + (rowbase + bm + wid*16 + lrow)*GSZ + kcL*8;
  const u16* gA1q = attn + (rowbase + bm + (wid+4)*16 + lrow)*GSZ + kcL*8;
  const u16* gA0l = eqk + (rowbase + bm + wid*16 + lrow)*128 + kcL*8;
  const u16* gA1l = eqk + (rowbase + bm + (wid+4)*16 + lrow)*128 + kcL*8;
  const u16* gBVl = FTg + (size_t)(cb + wid*16 + lrow)*128 + kcL*8;
  const u16* gBUl = FTg + (size_t)(1024 + cb + wid*16 + lrow)*128 + kcL*8;
  auto issue = [&](int ti, u16* b) {
    if (ti < 8) {
      int k0 = ti << 5;
      size_t ktile = (size_t)g*8 + ti;
      gload16(gA0q + k0, b + (size_t)wid*512);
      gload16(gA1q + k0, b + (size_t)(wid+4)*512);
      gload16(hF + ((ktile*128 + (cb>>4) + wid)*64 + lane)*8,      b + (size_t)(8+wid)*512);
      gload16(hF + ((ktile*128 + 64 + (cb>>4) + wid)*64 + lane)*8, b + (size_t)(12+wid)*512);
    } else {
      int k0 = (ti - 8) << 5;
      gload16(gA0l + k0, b + (size_t)wid*512);
      gload16(gA1l + k0, b + (size_t)(wid+4)*512);
      gload16(gBVl + k0, b + (size_t)(8+wid)*512);
      gload16(gBUl + k0, b + (size_t)(12+wid)*512);
    }
  };
  issue(0, lds);
  int cur = 0;
  for (int ti = 0; ti < 12; ++ti) {
    if (ti + 1 < 12) {
      issue(ti + 1, lds + (size_t)(cur^1)*8192);
      asm volatile("s_waitcnt vmcnt(4)" ::: "memory");
    } else {
      asm volatile("s_waitcnt vmcnt(0)" ::: "memory");
    }
    __builtin_amdgcn_s_barrier();
    asm volatile("" ::: "memory");
    const bf16x8* L = (const bf16x8*)(lds + (size_t)cur*8192);
    bf16x8 af[4], bv[2], bu[2];
    #pragma unroll
    for (int mr = 0; mr < 4; ++mr) af[mr] = L[(wm*4+mr)*64 + lane];
    #pragma unroll
    for (int nr = 0; nr < 2; ++nr) { bv[nr] = L[(8 + wn*2+nr)*64 + lane];
                                     bu[nr] = L[(12 + wn*2+nr)*64 + lane]; }
    #pragma unroll
    for (int mr = 0; mr < 4; ++mr)
      #pragma unroll
      for (int nr = 0; nr < 2; ++nr) {
        accV[mr][nr] = MFMA16(af[mr], bv[nr], accV[mr][nr], 0, 0, 0);
        accU[mr][nr] = MFMA16(af[mr], bu[nr], accU[mr][nr], 0, 0, 0);
      }
    asm volatile("" ::: "memory");
    __builtin_amdgcn_s_barrier();
    cur ^= 1;
  }
  #pragma unroll
  for (int mr = 0; mr < 4; ++mr)
    #pragma unroll
    for (int nr = 0; nr < 2; ++nr) {
      int c = cb + wn*32 + nr*16 + lrow;
      float cV = cvec[c], cU = cvec[1024 + c];
      int np = bm + wm*64 + mr*16 + kcL*4;
      size_t ktile = (size_t)g*8 + (np>>5);
      int lofs = ((np>>3)&3)*16 + (c&15);
      int eo = np & 7;
      ushort4 vq = *(const ushort4*)(hF + ((ktile*128 + (c>>4))*64 + lofs)*8 + eo);
      ushort4 uq = *(const ushort4*)(hF + ((ktile*128 + 64 + (c>>4))*64 + lofs)*8 + eo);
      float vv[4] = {bf2f(vq.x), bf2f(vq.y), bf2f(vq.z), bf2f(vq.w)};
      float uu[4] = {bf2f(uq.x), bf2f(uq.y), bf2f(uq.z), bf2f(uq.w)};
      #pragma unroll
      for (int i = 0; i < 4; ++i) {
        float av = accV[mr][nr][i] + cV;
        float au = accU[mr][nr][i] + cU;
        T2[(rowbase + np + i)*1024 + c] = f2bf(au * vv[i] * sigm(av * uu[i]));
      }
    }
}

// ---------------- conv / norm kernels ----------------

// th-branch depthwise conv, 64-row tiles -> hF + hsum. grid (cols/64, N/64)
__global__ __launch_bounds__(256) void dwconv_hf64(
    const u16* __restrict__ xin, int ldin, const float* __restrict__ kern,
    u16* __restrict__ hF, int colbase, float* __restrict__ hsum, int N)
{
  __shared__ float tile[80][64];
  __shared__ float psum[4][64];
  int c0 = blockIdx.x * 64;
  int n0 = blockIdx.y * 64;
  int t = threadIdx.x;
  int tx = t & 63, ty = t >> 6;
  #pragma unroll
  for (int it = 0; it < 5; ++it) {
    int idx = t + it*256;
    int r = idx >> 4, cq = (idx & 15)*4;
    int gn = n0 - 8 + r;
    float4 f;
    if (gn >= 0 && gn < N) {
      ushort4 q = *(const ushort4*)(xin + (size_t)gn*ldin + c0 + cq);
      f.x = bf2f(q.x); f.y = bf2f(q.y); f.z = bf2f(q.z); f.w = bf2f(q.w);
    } else { f.x = 0.f; f.y = 0.f; f.z = 0.f; f.w = 0.f; }
    *(float4*)&tile[r][cq] = f;
  }
  __syncthreads();
  int chl = c0 + tx;
  float kr[17];
  #pragma unroll
  for (int k = 0; k < 17; ++k) kr[k] = kern[chl*17 + k];
  int c = colbase + chl;
  float loc = 0.f;
  #pragma unroll
  for (int u = 0; u < 2; ++u) {
    u16x8 o;
    #pragma unroll
    for (int rr = 0; rr < 8; ++rr) {
      int r = ty*16 + u*8 + rr;
      float s = 0.0f;
      #pragma unroll
      for (int k = 0; k < 17; ++k) s = fmaf(kr[k], tile[r+k][tx], s);
      float val = tile[r+8][tx] + s;
      loc += val;
      o[rr] = f2bf(val);
    }
    int nn = n0 + ty*16 + u*8;
    *(u16x8*)(hF + ((((size_t)(nn>>5))*128 + (c>>4))*64 + ((nn>>3)&3)*16 + (c&15))*8) = o;
  }
  psum[ty][tx] = loc;
  __syncthreads();
  if (t < 64)
    atomicAdd(&hsum[colbase + c0 + t], psum[0][t]+psum[1][t]+psum[2][t]+psum[3][t]);
}

// qk dwconv (32-row): writes Eqk, Eq0, Ek2 (row-major), EqkF (fragment). grid (2, N/32)
__global__ __launch_bounds__(256) void dwconv_qk(
    const u16* __restrict__ xin, const float* __restrict__ kern,
    const float* __restrict__ osg, const float* __restrict__ osb,
    u16* __restrict__ Eqk, u16* __restrict__ Eq0, u16* __restrict__ Ek2,
    u16* __restrict__ EqkF, int N)
{
  __shared__ float tile[48][64];
  int c0 = blockIdx.x * 64;
  int n0 = blockIdx.y * 32;
  int t = threadIdx.x;
  int tx = t & 63, ty = t >> 6;
  #pragma unroll
  for (int it = 0; it < 3; ++it) {
    int idx = t + it*256;
    int r = idx >> 4, cq = (idx & 15)*4;
    int gn = n0 - 8 + r;
    float4 f;
    if (gn >= 0 && gn < N) {
      ushort4 q = *(const ushort4*)(xin + (size_t)gn*128 + c0 + cq);
      f.x = bf2f(q.x); f.y = bf2f(q.y); f.z = bf2f(q.z); f.w = bf2f(q.w);
    } else { f.x = 0.f; f.y = 0.f; f.z = 0.f; f.w = 0.f; }
    *(float4*)&tile[r][cq] = f;
  }
  __syncthreads();
  int ch = c0 + tx;
  float kr[17];
  #pragma unroll
  for (int k = 0; k < 17; ++k) kr[k] = kern[ch*17 + k];
  float g0 = osg[ch], b0 = osb[ch];
  float g2 = osg[2*128+ch], b2 = osb[2*128+ch];
  float vals[8];
  #pragma unroll
  for (int rr = 0; rr < 8; ++rr) {
    int r = ty*8 + rr;
    float s = 0.0f;
    #pragma unroll
    for (int k = 0; k < 17; ++k) s = fmaf(kr[k], tile[r+k][tx], s);
    vals[rr] = tile[r+8][tx] + s;
    size_t gi = (size_t)(n0 + r)*128 + ch;
    Eqk[gi] = f2bf(vals[rr]);
    Eq0[gi] = f2bf(fmaf(vals[rr], g0, b0));
    Ek2[gi] = f2bf(fmaf(vals[rr], g2, b2));
  }
  u16x8 o;
  #pragma unroll
  for (int rr = 0; rr < 8; ++rr) o[rr] = f2bf(vals[rr]);
  *(u16x8*)(EqkF + ((((size_t)(n0>>5))*8 + (ch>>4))*64 + ty*16 + (ch&15))*8) = o;
}

// final conv, 64-row tiles: out = resid + x + conv(x). grid (8, N/64)
__global__ __launch_bounds__(256) void dwconv_final64(
    const u16* __restrict__ xin, const float* __restrict__ kern,
    const float* __restrict__ resid, float* __restrict__ y, int N)
{
  __shared__ float tile[80][64];
  int c0 = blockIdx.x * 64;
  int n0 = blockIdx.y * 64;
  int t = threadIdx.x;
  int tx = t & 63, ty = t >> 6;
  #pragma unroll
  for (int it = 0; it < 5; ++it) {
    int idx = t + it*256;
    int r = idx >> 4, cq = (idx & 15)*4;
    int gn = n0 - 8 + r;
    float4 f;
    if (gn >= 0 && gn < N) {
      ushort4 q = *(const ushort4*)(xin + (size_t)gn*512 + c0 + cq);
      f.x = bf2f(q.x); f.y = bf2f(q.y); f.z = bf2f(q.z); f.w = bf2f(q.w);
    } else { f.x = 0.f; f.y = 0.f; f.z = 0.f; f.w = 0.f; }
    *(float4*)&tile[r][cq] = f;
  }
  __syncthreads();
  int ch = c0 + tx;
  float kr[17];
  #pragma unroll
  for (int k = 0; k < 17; ++k) kr[k] = kern[ch*17 + k];
  #pragma unroll
  for (int rr = 0; rr < 16; ++rr) {
    int r = ty*16 + rr;
    float s = 0.0f;
    #pragma unroll
    for (int k = 0; k < 17; ++k) s = fmaf(kr[k], tile[r+k][tx], s);
    size_t gi = (size_t)(n0 + r)*512 + ch;
    y[gi] = resid[gi] + tile[r+8][tx] + s;
  }
}

__global__ __launch_bounds__(256) void ln1024_kernel(u16* __restrict__ buf)
{
  long long n = blockIdx.x;
  ushort4* p = (ushort4*)(buf + n*1024) + threadIdx.x;
  ushort4 q = *p;
  float a = bf2f(q.x), b = bf2f(q.y), c = bf2f(q.z), d = bf2f(q.w);
  float s = a+b+c+d;
  float ss = fmaf(a,a, fmaf(b,b, fmaf(c,c, d*d)));
  float2 r = blockReduce2(s, ss);
  float mu = r.x * (1.0f/1024.0f);
  float var = r.y * (1.0f/1024.0f) - mu*mu;
  float rs = rsqrtf(var + 1e-5f);
  q.x = f2bf((a-mu)*rs); q.y = f2bf((b-mu)*rs);
  q.z = f2bf((c-mu)*rs); q.w = f2bf((d-mu)*rs);
  *p = q;
}

// ---------------- host launcher ----------------

extern "C" void kernel_launch(void* const* d_in, const int* in_sizes, int n_in,
                              void* d_out, int out_size, void* d_ws, size_t ws_size,
                              hipStream_t stream)
{
  const float* x        = (const float*)d_in[0];
  const float* th_ln_g  = (const float*)d_in[2];
  const float* th_ln_b  = (const float*)d_in[3];
  const float* th_w     = (const float*)d_in[4];
  const float* th_b     = (const float*)d_in[5];
  const float* th_conv  = (const float*)d_in[6];
  const float* qk_ln_g  = (const float*)d_in[7];
  const float* qk_ln_b  = (const float*)d_in[8];
  const float* qk_w     = (const float*)d_in[9];
  const float* qk_b     = (const float*)d_in[10];
  const float* qk_conv  = (const float*)d_in[11];
  const float* osg      = (const float*)d_in[12];
  const float* osb      = (const float*)d_in[13];
  const float* out_ln_g = (const float*)d_in[14];
  const float* out_ln_b = (const float*)d_in[15];
  const float* out_w    = (const float*)d_in[16];
  const float* out_b    = (const float*)d_in[17];
  const float* out_conv = (const float*)d_in[18];

  const int N = in_sizes[0] / 512;          // 16384
  const float inv_n = 1.0f / (float)N;
  const int G = N / GSZ;                    // 64
  char* wsb = (char*)d_ws;

  // ---- workspace layout (bytes), lifetime-aliased ----
  size_t o_hF   = 0;
  size_t o_T2   = o_hF  + (size_t)N*2048*2;
  size_t o_C    = o_T2  + (size_t)N*1024*2;
  size_t o_eqk  = o_C   + (size_t)N*512*2;
  size_t o_fr   = o_eqk + (size_t)N*128*2;
  size_t o_wth  = o_fr  + (size_t)N*128*2;
  size_t o_wqk  = o_wth + (size_t)2048*512*2;
  size_t o_wout = o_wqk + (size_t)128*512*2;
  size_t o_bth  = o_wout+ (size_t)1024*512*2;
  size_t o_bqk  = o_bth + 2048*4;
  size_t o_bout = o_bqk + 128*4;
  size_t o_hsum = o_bout + 512*4;
  size_t required = o_hsum + 2048*4;
  if (ws_size < required) return;

  u16*   hF   = (u16*)(wsb + o_hF);
  u16*   T2   = (u16*)(wsb + o_T2);
  u16*   Hpre = T2;
  u16*   Cu   = (u16*)(wsb + o_C);
  u16*   nx   = Cu;
  u16*   EqkF = Cu;
  u16*   Eq0  = Cu + (size_t)N*256;
  u16*   Ek2  = Cu + (size_t)N*384;
  u16*   attn = Cu;
  u16*   outtmp = Cu;
  u16*   Eqk  = (u16*)(wsb + o_eqk);
  u16*   Dqk  = (u16*)(wsb + o_fr);
  float* Fraw = (float*)(wsb + o_fr);
  u16*   FTg  = (u16*)(wsb + o_fr + (size_t)128*2048*4);
  float* cvec = (float*)(wsb + o_fr + (size_t)128*2048*4 + (size_t)2048*128*2);
  u16*   WthT = (u16*)(wsb + o_wth);
  u16*   WqkT = (u16*)(wsb + o_wqk);
  u16*   WoutT= (u16*)(wsb + o_wout);
  float* Bth  = (float*)(wsb + o_bth);
  float* Bqk  = (float*)(wsb + o_bqk);
  float* Bout = (float*)(wsb + o_bout);
  float* hsum = (float*)(wsb + o_hsum);

  // ---- weight prep + zeros ----
  hipLaunchKernelGGL(fuse_wT_kernel, dim3(16, 64), dim3(256), 0, stream, th_ln_g, th_w, WthT, 512, 2048);
  hipLaunchKernelGGL(fuse_wT_kernel, dim3(16, 4),  dim3(256), 0, stream, qk_ln_g, qk_w, WqkT, 512, 128);
  hipLaunchKernelGGL(fuse_wT_kernel, dim3(32, 16), dim3(256), 0, stream, out_ln_g, out_w, WoutT, 1024, 512);
  hipLaunchKernelGGL(copy_bias_kernel, dim3(8), dim3(256), 0, stream, th_b, Bth, 2048);
  hipLaunchKernelGGL(copy_bias_kernel, dim3(1), dim3(256), 0, stream, qk_b, Bqk, 128);
  hipLaunchKernelGGL(copy_bias_kernel, dim3(2), dim3(256), 0, stream, out_b, Bout, 512);
  hipLaunchKernelGGL(fuse_b_acc, dim3(8, 8),  dim3(256), 0, stream, th_ln_b,  th_w,  Bth, 512, 2048);
  hipLaunchKernelGGL(fuse_b_acc, dim3(1, 8),  dim3(256), 0, stream, qk_ln_b,  qk_w,  Bqk, 512, 128);
  hipLaunchKernelGGL(fuse_b_acc, dim3(2, 16), dim3(256), 0, stream, out_ln_b, out_w, Bout, 1024, 512);
  hipLaunchKernelGGL(zero_kernel, dim3(8), dim3(256), 0, stream, hsum, 2048LL);

  // ---- token shift + LN core ----
  hipLaunchKernelGGL(shift_ln_kernel, dim3(N), dim3(256), 0, stream, x, nx, N);

  // ---- th branch, 2 super-chunks of 1024 cols (XCD-colocated GEMM grid) ----
  for (int sc = 0; sc < 2; ++sc) {
    hipLaunchKernelGGL(gemm_mfma_silu, dim3(8 * (N/128)), dim3(256), 0, stream,
                       nx, 512, WthT, 512, sc*1024, Hpre, 1024, Bth, 512, 8);
    hipLaunchKernelGGL(dwconv_hf64, dim3(16, N/64), dim3(256), 0, stream,
                       Hpre, 1024, th_conv + (size_t)sc*1024*17, hF, sc*1024, hsum, N);
  }

  // ---- qk branch ----
  hipLaunchKernelGGL(gemm_mfma_silu, dim3(1 * (N/128)), dim3(256), 0, stream,
                     nx, 512, WqkT, 512, 0, Dqk, 128, Bqk, 512, 1);
  hipLaunchKernelGGL(dwconv_qk, dim3(2, N/32), dim3(256), 0, stream,
                     Dqk, qk_conv, osg, osb, Eqk, Eq0, Ek2, EqkF, N);

  // ---- linear attention kv summary ----
  hipLaunchKernelGGL(zero_kernel, dim3(1024), dim3(256), 0, stream, Fraw, (long long)128*2048);
  hipLaunchKernelGGL(linkv_mfma, dim3(32, 16), dim3(256), 0, stream, EqkF, hF, Fraw, N);
  hipLaunchKernelGGL(fconv_kernel, dim3(8), dim3(256), 0, stream, Fraw, osg, osb, hsum, inv_n, FTg, cvec);

  // ---- quadratic attention scores ----
  hipLaunchKernelGGL(score_mfma2, dim3(2, 2, G), dim3(256), 0, stream, Eq0, Ek2, attn);

  // ---- fused quad + lin + gate -> T2 ----
  hipLaunchKernelGGL(quadlin_mfma, dim3(2*G*16), dim3(256), 0, stream,
                     attn, hF, Eqk, FTg, cvec, T2);

  // ---- out branch (XCD-colocated GEMM grid) ----
  hipLaunchKernelGGL(ln1024_kernel, dim3(N), dim3(256), 0, stream, T2);
  hipLaunchKernelGGL(gemm_mfma_silu, dim3(4 * (N/128)), dim3(256), 0, stream,
                     T2, 1024, WoutT, 1024, 0, outtmp, 512, Bout, 1024, 4);
  hipLaunchKernelGGL(dwconv_final64, dim3(8, N/64), dim3(256), 0, stream,
                     outtmp, out_conv, x, (float*)d_out, N);
}

// Round 16
// 339.859 us; speedup vs baseline: 1.1553x; 1.1304x over previous
//
#include <hip/hip_runtime.h>
#include <math.h>

#define GSZ 256

typedef unsigned short u16;
typedef short bf16x8 __attribute__((ext_vector_type(8)));
typedef u16 u16x8 __attribute__((ext_vector_type(8)));
typedef float f32x4 __attribute__((ext_vector_type(4)));
#define MFMA16 __builtin_amdgcn_mfma_f32_16x16x32_bf16

// hF fragment layout: unit(n,c) = hF + (((n>>5)*NCC + (c>>4))*64 + ((n>>3)&3)*16 + (c&15))*8,
// elem n&7.  NCC = 128 for h (2048 cols), 8 for EqkF (128 cols).

__device__ __forceinline__ float bf2f(u16 u){
  union { unsigned int i; float f; } x; x.i = ((unsigned int)u) << 16; return x.f;
}
__device__ __forceinline__ u16 f2bf(float f){
  union { float ff; unsigned int i; } x; x.ff = f;
  unsigned int r = x.i + 0x7fffu + ((x.i >> 16) & 1u);
  return (u16)(r >> 16);
}
__device__ __forceinline__ float sigm(float x){ return 1.0f/(1.0f+__expf(-x)); }
__device__ __forceinline__ float siluf(float x){ return x/(1.0f+__expf(-x)); }

__device__ __forceinline__ void gload16(const void* g, void* l){
  __builtin_amdgcn_global_load_lds(
      (const __attribute__((address_space(1))) void*)g,
      (__attribute__((address_space(3))) void*)l, 16, 0, 0);
}

__device__ __forceinline__ float2 blockReduce2(float s, float ss){
  __shared__ float red[8];
  #pragma unroll
  for (int off=32; off>0; off>>=1){
    s  += __shfl_down(s, off, 64);
    ss += __shfl_down(ss, off, 64);
  }
  int lane = threadIdx.x & 63, wid = threadIdx.x >> 6;
  if (lane==0){ red[wid]=s; red[4+wid]=ss; }
  __syncthreads();
  float2 r;
  r.x = red[0]+red[1]+red[2]+red[3];
  r.y = red[4]+red[5]+red[6]+red[7];
  return r;
}

// ---------------- consolidated prep kernels ----------------

__device__ __forceinline__ void wT_body(float (*sL)[33],
    const float* __restrict__ g, const float* __restrict__ w,
    u16* __restrict__ wT, int K, int Nn, int bx, int by)
{
  int k0 = bx*32, n0 = by*32;
  int t = threadIdx.x;
  int r = t >> 3, cq = t & 7;
  float4 v = *(const float4*)(w + (size_t)(k0+r)*Nn + n0 + cq*4);
  float gg = g[k0+r];
  sL[r][cq*4+0] = v.x*gg; sL[r][cq*4+1] = v.y*gg;
  sL[r][cq*4+2] = v.z*gg; sL[r][cq*4+3] = v.w*gg;
  __syncthreads();
  ushort4 o;
  o.x = f2bf(sL[cq*4+0][r]); o.y = f2bf(sL[cq*4+1][r]);
  o.z = f2bf(sL[cq*4+2][r]); o.w = f2bf(sL[cq*4+3][r]);
  *(ushort4*)(wT + (size_t)(n0+r)*K + k0 + cq*4) = o;
}

// one launch: all 3 weight transposes + hsum zero.  grid 1608 blocks.
__global__ __launch_bounds__(256) void prep_trzero(
    const float* __restrict__ thg, const float* __restrict__ thw, u16* __restrict__ WthT,
    const float* __restrict__ qkg, const float* __restrict__ qkw, u16* __restrict__ WqkT,
    const float* __restrict__ og,  const float* __restrict__ ow,  u16* __restrict__ WoutT,
    float* __restrict__ hsum)
{
  __shared__ float sL[32][33];
  int b = blockIdx.x;
  if (b < 1024) {                       // th: 512x2048, grid (16,64)
    wT_body(sL, thg, thw, WthT, 512, 2048, b & 15, b >> 4);
  } else if (b < 1088) {                // qk: 512x128, grid (16,4)
    int lb = b - 1024;
    wT_body(sL, qkg, qkw, WqkT, 512, 128, lb & 15, lb >> 4);
  } else if (b < 1600) {                // out: 1024x512, grid (32,16)
    int lb = b - 1088;
    wT_body(sL, og, ow, WoutT, 1024, 512, lb & 31, lb >> 5);
  } else {                              // hsum zero: 8 blocks x 256
    hsum[(b - 1600)*256 + threadIdx.x] = 0.f;
  }
}

__device__ __forceinline__ void bias_body(
    const float* __restrict__ bln, const float* __restrict__ w,
    const float* __restrict__ bias, float* __restrict__ bout,
    int K, int Nn, int cb)
{
  __shared__ float red[4][64];
  int t = threadIdx.x;
  int tc = t & 63, ts = t >> 6;
  int c = cb + tc;
  int kper = K >> 2;
  float acc = 0.f;
  for (int k = ts*kper; k < (ts+1)*kper; ++k)
    acc = fmaf(bln[k], w[(size_t)k*Nn + c], acc);
  red[ts][tc] = acc;
  __syncthreads();
  if (t < 64)
    bout[cb + t] = bias[cb + t] + red[0][t]+red[1][t]+red[2][t]+red[3][t];
}

// one launch: all 3 fused-bias reductions.  grid 42 blocks.
__global__ __launch_bounds__(256) void prep_bias(
    const float* __restrict__ thbln, const float* __restrict__ thw,
    const float* __restrict__ thb, float* __restrict__ Bth,
    const float* __restrict__ qkbln, const float* __restrict__ qkw,
    const float* __restrict__ qkb, float* __restrict__ Bqk,
    const float* __restrict__ obln,  const float* __restrict__ ow,
    const float* __restrict__ ob,  float* __restrict__ Bout)
{
  int b = blockIdx.x;
  if (b < 32)      bias_body(thbln, thw, thb, Bth, 512, 2048, b*64);
  else if (b < 34) bias_body(qkbln, qkw, qkb, Bqk, 512, 128, (b-32)*64);
  else             bias_body(obln,  ow,  ob,  Bout, 1024, 512, (b-34)*64);
}

__global__ void zero_kernel(float* __restrict__ p, long long total){
  long long i = (long long)blockIdx.x*256 + threadIdx.x;
  if (i < total) p[i] = 0.0f;
}

// ---------------- small pipeline kernels ----------------

__global__ __launch_bounds__(256) void shift_ln_kernel(
    const float* __restrict__ x, u16* __restrict__ out, int N)
{
  int n = blockIdx.x;
  int t = threadIdx.x;
  float v0 = (n > 0) ? x[(long long)(n-1)*512 + t] : 0.0f;
  float v1 = x[(long long)n*512 + 256 + t];
  float2 r = blockReduce2(v0+v1, fmaf(v0,v0,v1*v1));
  float mu = r.x * (1.0f/512.0f);
  float var = r.y * (1.0f/512.0f) - mu*mu;
  float rs = rsqrtf(var + 1e-5f);
  long long base = (long long)n*512;
  out[base + t]       = f2bf((v0-mu)*rs);
  out[base + 256 + t] = f2bf((v1-mu)*rs);
}

// ---------------- MFMA kernels (chunk-linear LDS + global_load_lds) --------------
// LDS chunk = 64 units x 16B; unit l of chunk = fragment of lane l.
// MFMA frags: A row=l&15 k=(l>>4)*8+j ; B col=l&15 ; D col=l&15 row=(l>>4)*4+i.

// C = silu(A @ WT^T + bias).  BM=128, BN=128, BK=32, depth-2; XCD-colocated 1D grid.
__global__ __launch_bounds__(256) void gemm_mfma_silu(
    const u16* __restrict__ A, int lda,
    const u16* __restrict__ BT, int ldbt, int wtc0,
    u16* __restrict__ C, int ldc,
    const float* __restrict__ bias, int K, int nbn)
{
  __shared__ u16 lds[3*16*512];
  int nwg = gridDim.x;
  int bid = blockIdx.x;
  int gidx = (bid & 7) * (nwg >> 3) + (bid >> 3);   // bijective (nwg%8==0)
  int bm = (gidx / nbn) * 128;
  int bn = (gidx % nbn) * 128;
  int t = threadIdx.x;
  int lane = t & 63, wid = t >> 6;
  int wm = wid >> 1, wn = wid & 1;
  int lrow = lane & 15, kcL = lane >> 4;
  const u16* gA0 = A + (size_t)(bm + wid*16 + lrow)*lda + kcL*8;
  const u16* gA1 = A + (size_t)(bm + (wid+4)*16 + lrow)*lda + kcL*8;
  const u16* gB0 = BT + (size_t)(wtc0 + bn + wid*16 + lrow)*ldbt + kcL*8;
  const u16* gB1 = BT + (size_t)(wtc0 + bn + (wid+4)*16 + lrow)*ldbt + kcL*8;
  f32x4 acc[4][4] = {};
  int nt = K >> 5;
  auto issue = [&](int ti, u16* b){
    int k1 = ti << 5;
    gload16(gA0 + k1, b + (size_t)wid*512);
    gload16(gA1 + k1, b + (size_t)(wid+4)*512);
    gload16(gB0 + k1, b + (size_t)(8+wid)*512);
    gload16(gB1 + k1, b + (size_t)(12+wid)*512);
  };
  issue(0, lds);
  if (nt > 1) issue(1, lds + 8192);
  for (int ti = 0; ti < nt; ++ti) {
    if (ti + 2 < nt) {
      issue(ti + 2, lds + (size_t)((ti+2)%3)*8192);
      asm volatile("s_waitcnt vmcnt(8)" ::: "memory");
    } else if (ti + 1 < nt) {
      asm volatile("s_waitcnt vmcnt(4)" ::: "memory");
    } else {
      asm volatile("s_waitcnt vmcnt(0)" ::: "memory");
    }
    __builtin_amdgcn_s_barrier();
    asm volatile("" ::: "memory");
    const bf16x8* L = (const bf16x8*)(lds + (size_t)(ti%3)*8192);
    bf16x8 af[4], bfr[4];
    #pragma unroll
    for (int mr = 0; mr < 4; ++mr) af[mr] = L[(wm*4+mr)*64 + lane];
    #pragma unroll
    for (int nr = 0; nr < 4; ++nr) bfr[nr] = L[(8 + wn*4+nr)*64 + lane];
    #pragma unroll
    for (int mr = 0; mr < 4; ++mr)
      #pragma unroll
      for (int nr = 0; nr < 4; ++nr)
        acc[mr][nr] = MFMA16(af[mr], bfr[nr], acc[mr][nr], 0, 0, 0);
    asm volatile("" ::: "memory");
    __builtin_amdgcn_s_barrier();
  }
  #pragma unroll
  for (int mr = 0; mr < 4; ++mr)
    #pragma unroll
    for (int nr = 0; nr < 4; ++nr) {
      int col = bn + wn*64 + nr*16 + lrow;
      float bs = bias[wtc0 + col];
      #pragma unroll
      for (int i = 0; i < 4; ++i) {
        int row = bm + wm*64 + mr*16 + kcL*4 + i;
        C[(size_t)row*ldc + col] = f2bf(siluf(acc[mr][nr][i] + bs));
      }
    }
}

// attn = relu(Eq0 @ Ek2^T / GS)^2 per group — depth-2 GEMM. grid (2, 2, G)
__global__ __launch_bounds__(256) void score_mfma2(
    const u16* __restrict__ Eq0, const u16* __restrict__ Ek2,
    u16* __restrict__ attn)
{
  __shared__ u16 lds[3*16*512];
  int t = threadIdx.x;
  int lane = t & 63, wid = t >> 6;
  int wm = wid >> 1, wn = wid & 1;
  int lrow = lane & 15, kcL = lane >> 4;
  int g = blockIdx.z;
  int bm = blockIdx.y*128, bn = blockIdx.x*128;
  size_t rowbase = (size_t)g * GSZ;
  const u16* gA0 = Eq0 + (rowbase + bm + wid*16 + lrow)*128 + kcL*8;
  const u16* gA1 = Eq0 + (rowbase + bm + (wid+4)*16 + lrow)*128 + kcL*8;
  const u16* gB0 = Ek2 + (rowbase + bn + wid*16 + lrow)*128 + kcL*8;
  const u16* gB1 = Ek2 + (rowbase + bn + (wid+4)*16 + lrow)*128 + kcL*8;
  f32x4 acc[4][4] = {};
  auto issue = [&](int ti, u16* b){
    int k1 = ti << 5;
    gload16(gA0 + k1, b + (size_t)wid*512);
    gload16(gA1 + k1, b + (size_t)(wid+4)*512);
    gload16(gB0 + k1, b + (size_t)(8+wid)*512);
    gload16(gB1 + k1, b + (size_t)(12+wid)*512);
  };
  issue(0, lds);
  issue(1, lds + 8192);
  for (int ti = 0; ti < 4; ++ti) {
    if (ti + 2 < 4) {
      issue(ti + 2, lds + (size_t)((ti+2)%3)*8192);
      asm volatile("s_waitcnt vmcnt(8)" ::: "memory");
    } else if (ti + 1 < 4) {
      asm volatile("s_waitcnt vmcnt(4)" ::: "memory");
    } else {
      asm volatile("s_waitcnt vmcnt(0)" ::: "memory");
    }
    __builtin_amdgcn_s_barrier();
    asm volatile("" ::: "memory");
    const bf16x8* L = (const bf16x8*)(lds + (size_t)(ti%3)*8192);
    bf16x8 af[4], bfr[4];
    #pragma unroll
    for (int mr = 0; mr < 4; ++mr) af[mr] = L[(wm*4+mr)*64 + lane];
    #pragma unroll
    for (int nr = 0; nr < 4; ++nr) bfr[nr] = L[(8 + wn*4+nr)*64 + lane];
    #pragma unroll
    for (int mr = 0; mr < 4; ++mr)
      #pragma unroll
      for (int nr = 0; nr < 4; ++nr)
        acc[mr][nr] = MFMA16(af[mr], bfr[nr], acc[mr][nr], 0, 0, 0);
    asm volatile("" ::: "memory");
    __builtin_amdgcn_s_barrier();
  }
  #pragma unroll
  for (int mr = 0; mr < 4; ++mr)
    #pragma unroll
    for (int nr = 0; nr < 4; ++nr) {
      int col = bn + wn*64 + nr*16 + lrow;
      #pragma unroll
      for (int i = 0; i < 4; ++i) {
        int row = bm + wm*64 + mr*16 + kcL*4 + i;
        float s = fmaxf(acc[mr][nr][i] * (1.0f/GSZ), 0.0f);
        attn[(rowbase + row)*GSZ + col] = f2bf(s*s);
      }
    }
}

// Fraw[d][e] += sum_n EqkF(n,d) * hF(n,e) — pure gload dbuf GEMM. grid (32, 16)
__global__ __launch_bounds__(256) void linkv_mfma(
    const u16* __restrict__ EqkF, const u16* __restrict__ hF,
    float* __restrict__ Fraw, int N)
{
  __shared__ u16 lds[2*12*512];
  int t = threadIdx.x;
  int lane = t & 63, wid = t >> 6;
  int wm = wid >> 1, wn = wid & 1;
  int lrow = lane & 15, kcL = lane >> 4;
  int e0 = blockIdx.x * 64;
  int nkt = (N / gridDim.y) >> 5;
  size_t kt0 = (size_t)blockIdx.y * nkt;
  f32x4 acc[4][2] = {};
  auto issue = [&](int kt, u16* b) {
    size_t ktile = kt0 + kt;
    gload16(EqkF + ((ktile*8 + wid)*64 + lane)*8,           b + (size_t)wid*512);
    gload16(EqkF + ((ktile*8 + wid+4)*64 + lane)*8,         b + (size_t)(wid+4)*512);
    gload16(hF + ((ktile*128 + (e0>>4) + wid)*64 + lane)*8, b + (size_t)(8+wid)*512);
  };
  issue(0, lds);
  int cur = 0;
  for (int ti = 0; ti < nkt; ++ti) {
    if (ti + 1 < nkt) {
      issue(ti + 1, lds + (size_t)(cur^1)*6144);
      asm volatile("s_waitcnt vmcnt(3)" ::: "memory");
    } else {
      asm volatile("s_waitcnt vmcnt(0)" ::: "memory");
    }
    __builtin_amdgcn_s_barrier();
    asm volatile("" ::: "memory");
    const bf16x8* L = (const bf16x8*)(lds + (size_t)cur*6144);
    bf16x8 af[4], bfr[2];
    #pragma unroll
    for (int mr = 0; mr < 4; ++mr) af[mr] = L[(wm*4+mr)*64 + lane];
    #pragma unroll
    for (int nr = 0; nr < 2; ++nr) bfr[nr] = L[(8 + wn*2+nr)*64 + lane];
    #pragma unroll
    for (int mr = 0; mr < 4; ++mr)
      #pragma unroll
      for (int nr = 0; nr < 2; ++nr)
        acc[mr][nr] = MFMA16(af[mr], bfr[nr], acc[mr][nr], 0, 0, 0);
    asm volatile("" ::: "memory");
    __builtin_amdgcn_s_barrier();
    cur ^= 1;
  }
  #pragma unroll
  for (int mr = 0; mr < 4; ++mr)
    #pragma unroll
    for (int nr = 0; nr < 2; ++nr) {
      int e = e0 + wn*32 + nr*16 + lrow;
      #pragma unroll
      for (int i = 0; i < 4; ++i) {
        int d = wm*64 + mr*16 + kcL*4 + i;
        atomicAdd(&Fraw[(size_t)d*2048 + e], acc[mr][nr][i]);
      }
    }
}

// F = inv_n*(g3[d]*Fraw + b3[d]*hsum[e]); FTg[e][d] = g1[d]*F ; cvec[e] = sum_d b1[d]*F
__global__ __launch_bounds__(256) void fconv_kernel(
    const float* __restrict__ Fraw, const float* __restrict__ osg, const float* __restrict__ osb,
    const float* __restrict__ hsum, float inv_n,
    u16* __restrict__ FTg, float* __restrict__ cvec)
{
  __shared__ float g1s[128], b1s[128], g3s[128], b3s[128];
  int t = threadIdx.x;
  if (t < 128) { g1s[t] = osg[128+t]; b1s[t] = osb[128+t];
                 g3s[t] = osg[3*128+t]; b3s[t] = osb[3*128+t]; }
  __syncthreads();
  int e = blockIdx.x*256 + t;
  float hs = hsum[e];
  float c = 0.f;
  for (int d = 0; d < 128; ++d) {
    float f = inv_n * fmaf(g3s[d], Fraw[(size_t)d*2048 + e], b3s[d]*hs);
    c = fmaf(b1s[d], f, c);
    FTg[(size_t)e*128 + d] = f2bf(g1s[d] * f);
  }
  cvec[e] = c;
}

// fused quad+lin attention + gate. 2-buffer depth-1 (measured best: ~64 us). grid 2048.
__global__ __launch_bounds__(256) void quadlin_mfma(
    const u16* __restrict__ attn, const u16* __restrict__ hF,
    const u16* __restrict__ eqk, const u16* __restrict__ FTg,
    const float* __restrict__ cvec, u16* __restrict__ T2)
{
  __shared__ u16 lds[2*16*512];
  int bid = blockIdx.x;
  int wgid = (bid & 7)*256 + (bid >> 3);
  int g = wgid >> 5;
  int rem = wgid & 31;
  int bm = (rem >> 4) * 128;
  int cb = (rem & 15) * 64;
  int t = threadIdx.x;
  int lane = t & 63, wid = t >> 6;
  int wm = wid >> 1, wn = wid & 1;
  int lrow = lane & 15, kcL = lane >> 4;
  size_t rowbase = (size_t)g * GSZ;
  f32x4 accV[4][2] = {}, accU[4][2] = {};
  const u16* gA0q = attn + (rowbase + bm + wid*16 + lrow)*GSZ + kcL*8;
  const u16* gA1q = attn + (rowbase + bm + (wid+4)*16 + lrow)*GSZ + kcL*8;
  const u16* gA0l = eqk + (rowbase + bm + wid*16 + lrow)*128 + kcL*8;
  const u16* gA1l = eqk + (rowbase + bm + (wid+4)*16 + lrow)*128 + kcL*8;
  const u16* gBVl = FTg + (size_t)(cb + wid*16 + lrow)*128 + kcL*8;
  const u16* gBUl = FTg + (size_t)(1024 + cb + wid*16 + lrow)*128 + kcL*8;
  auto issue = [&](int ti, u16* b) {
    if (ti < 8) {
      int k0 = ti << 5;
      size_t ktile = (size_t)g*8 + ti;
      gload16(gA0q + k0, b + (size_t)wid*512);
      gload16(gA1q + k0, b + (size_t)(wid+4)*512);
      gload16(hF + ((ktile*128 + (cb>>4) + wid)*64 + lane)*8,      b + (size_t)(8+wid)*512);
      gload16(hF + ((ktile*128 + 64 + (cb>>4) + wid)*64 + lane)*8, b + (size_t)(12+wid)*512);
    } else {
      int k0 = (ti - 8) << 5;
      gload16(gA0l + k0, b + (size_t)wid*512);
      gload16(gA1l + k0, b + (size_t)(wid+4)*512);
      gload16(gBVl + k0, b + (size_t)(8+wid)*512);
      gload16(gBUl + k0, b + (size_t)(12+wid)*512);
    }
  };
  issue(0, lds);
  int cur = 0;
  for (int ti = 0; ti < 12; ++ti) {
    if (ti + 1 < 12) {
      issue(ti + 1, lds + (size_t)(cur^1)*8192);
      asm volatile("s_waitcnt vmcnt(4)" ::: "memory");
    } else {
      asm volatile("s_waitcnt vmcnt(0)" ::: "memory");
    }
    __builtin_amdgcn_s_barrier();
    asm volatile("" ::: "memory");
    const bf16x8* L = (const bf16x8*)(lds + (size_t)cur*8192);
    bf16x8 af[4], bv[2], bu[2];
    #pragma unroll
    for (int mr = 0; mr < 4; ++mr) af[mr] = L[(wm*4+mr)*64 + lane];
    #pragma unroll
    for (int nr = 0; nr < 2; ++nr) { bv[nr] = L[(8 + wn*2+nr)*64 + lane];
                                     bu[nr] = L[(12 + wn*2+nr)*64 + lane]; }
    #pragma unroll
    for (int mr = 0; mr < 4; ++mr)
      #pragma unroll
      for (int nr = 0; nr < 2; ++nr) {
        accV[mr][nr] = MFMA16(af[mr], bv[nr], accV[mr][nr], 0, 0, 0);
        accU[mr][nr] = MFMA16(af[mr], bu[nr], accU[mr][nr], 0, 0, 0);
      }
    asm volatile("" ::: "memory");
    __builtin_amdgcn_s_barrier();
    cur ^= 1;
  }
  #pragma unroll
  for (int mr = 0; mr < 4; ++mr)
    #pragma unroll
    for (int nr = 0; nr < 2; ++nr) {
      int c = cb + wn*32 + nr*16 + lrow;
      float cV = cvec[c], cU = cvec[1024 + c];
      int np = bm + wm*64 + mr*16 + kcL*4;
      size_t ktile = (size_t)g*8 + (np>>5);
      int lofs = ((np>>3)&3)*16 + (c&15);
      int eo = np & 7;
      ushort4 vq = *(const ushort4*)(hF + ((ktile*128 + (c>>4))*64 + lofs)*8 + eo);
      ushort4 uq = *(const ushort4*)(hF + ((ktile*128 + 64 + (c>>4))*64 + lofs)*8 + eo);
      float vv[4] = {bf2f(vq.x), bf2f(vq.y), bf2f(vq.z), bf2f(vq.w)};
      float uu[4] = {bf2f(uq.x), bf2f(uq.y), bf2f(uq.z), bf2f(uq.w)};
      #pragma unroll
      for (int i = 0; i < 4; ++i) {
        float av = accV[mr][nr][i] + cV;
        float au = accU[mr][nr][i] + cU;
        T2[(rowbase + np + i)*1024 + c] = f2bf(au * vv[i] * sigm(av * uu[i]));
      }
    }
}

// ---------------- conv / norm kernels ----------------

// th-branch depthwise conv, 64-row tiles -> hF + hsum. grid (cols/64, N/64)
__global__ __launch_bounds__(256) void dwconv_hf64(
    const u16* __restrict__ xin, int ldin, const float* __restrict__ kern,
    u16* __restrict__ hF, int colbase, float* __restrict__ hsum, int N)
{
  __shared__ float tile[80][64];
  __shared__ float psum[4][64];
  int c0 = blockIdx.x * 64;
  int n0 = blockIdx.y * 64;
  int t = threadIdx.x;
  int tx = t & 63, ty = t >> 6;
  #pragma unroll
  for (int it = 0; it < 5; ++it) {
    int idx = t + it*256;
    int r = idx >> 4, cq = (idx & 15)*4;
    int gn = n0 - 8 + r;
    float4 f;
    if (gn >= 0 && gn < N) {
      ushort4 q = *(const ushort4*)(xin + (size_t)gn*ldin + c0 + cq);
      f.x = bf2f(q.x); f.y = bf2f(q.y); f.z = bf2f(q.z); f.w = bf2f(q.w);
    } else { f.x = 0.f; f.y = 0.f; f.z = 0.f; f.w = 0.f; }
    *(float4*)&tile[r][cq] = f;
  }
  __syncthreads();
  int chl = c0 + tx;
  float kr[17];
  #pragma unroll
  for (int k = 0; k < 17; ++k) kr[k] = kern[chl*17 + k];
  int c = colbase + chl;
  float loc = 0.f;
  #pragma unroll
  for (int u = 0; u < 2; ++u) {
    u16x8 o;
    #pragma unroll
    for (int rr = 0; rr < 8; ++rr) {
      int r = ty*16 + u*8 + rr;
      float s = 0.0f;
      #pragma unroll
      for (int k = 0; k < 17; ++k) s = fmaf(kr[k], tile[r+k][tx], s);
      float val = tile[r+8][tx] + s;
      loc += val;
      o[rr] = f2bf(val);
    }
    int nn = n0 + ty*16 + u*8;
    *(u16x8*)(hF + ((((size_t)(nn>>5))*128 + (c>>4))*64 + ((nn>>3)&3)*16 + (c&15))*8) = o;
  }
  psum[ty][tx] = loc;
  __syncthreads();
  if (t < 64)
    atomicAdd(&hsum[colbase + c0 + t], psum[0][t]+psum[1][t]+psum[2][t]+psum[3][t]);
}

// qk dwconv (32-row): writes Eqk, Eq0, Ek2 (row-major), EqkF (fragment). grid (2, N/32)
__global__ __launch_bounds__(256) void dwconv_qk(
    const u16* __restrict__ xin, const float* __restrict__ kern,
    const float* __restrict__ osg, const float* __restrict__ osb,
    u16* __restrict__ Eqk, u16* __restrict__ Eq0, u16* __restrict__ Ek2,
    u16* __restrict__ EqkF, int N)
{
  __shared__ float tile[48][64];
  int c0 = blockIdx.x * 64;
  int n0 = blockIdx.y * 32;
  int t = threadIdx.x;
  int tx = t & 63, ty = t >> 6;
  #pragma unroll
  for (int it = 0; it < 3; ++it) {
    int idx = t + it*256;
    int r = idx >> 4, cq = (idx & 15)*4;
    int gn = n0 - 8 + r;
    float4 f;
    if (gn >= 0 && gn < N) {
      ushort4 q = *(const ushort4*)(xin + (size_t)gn*128 + c0 + cq);
      f.x = bf2f(q.x); f.y = bf2f(q.y); f.z = bf2f(q.z); f.w = bf2f(q.w);
    } else { f.x = 0.f; f.y = 0.f; f.z = 0.f; f.w = 0.f; }
    *(float4*)&tile[r][cq] = f;
  }
  __syncthreads();
  int ch = c0 + tx;
  float kr[17];
  #pragma unroll
  for (int k = 0; k < 17; ++k) kr[k] = kern[ch*17 + k];
  float g0 = osg[ch], b0 = osb[ch];
  float g2 = osg[2*128+ch], b2 = osb[2*128+ch];
  float vals[8];
  #pragma unroll
  for (int rr = 0; rr < 8; ++rr) {
    int r = ty*8 + rr;
    float s = 0.0f;
    #pragma unroll
    for (int k = 0; k < 17; ++k) s = fmaf(kr[k], tile[r+k][tx], s);
    vals[rr] = tile[r+8][tx] + s;
    size_t gi = (size_t)(n0 + r)*128 + ch;
    Eqk[gi] = f2bf(vals[rr]);
    Eq0[gi] = f2bf(fmaf(vals[rr], g0, b0));
    Ek2[gi] = f2bf(fmaf(vals[rr], g2, b2));
  }
  u16x8 o;
  #pragma unroll
  for (int rr = 0; rr < 8; ++rr) o[rr] = f2bf(vals[rr]);
  *(u16x8*)(EqkF + ((((size_t)(n0>>5))*8 + (ch>>4))*64 + ty*16 + (ch&15))*8) = o;
}

// final conv, 64-row tiles: out = resid + x + conv(x). grid (8, N/64)
__global__ __launch_bounds__(256) void dwconv_final64(
    const u16* __restrict__ xin, const float* __restrict__ kern,
    const float* __restrict__ resid, float* __restrict__ y, int N)
{
  __shared__ float tile[80][64];
  int c0 = blockIdx.x * 64;
  int n0 = blockIdx.y * 64;
  int t = threadIdx.x;
  int tx = t & 63, ty = t >> 6;
  #pragma unroll
  for (int it = 0; it < 5; ++it) {
    int idx = t + it*256;
    int r = idx >> 4, cq = (idx & 15)*4;
    int gn = n0 - 8 + r;
    float4 f;
    if (gn >= 0 && gn < N) {
      ushort4 q = *(const ushort4*)(xin + (size_t)gn*512 + c0 + cq);
      f.x = bf2f(q.x); f.y = bf2f(q.y); f.z = bf2f(q.z); f.w = bf2f(q.w);
    } else { f.x = 0.f; f.y = 0.f; f.z = 0.f; f.w = 0.f; }
    *(float4*)&tile[r][cq] = f;
  }
  __syncthreads();
  int ch = c0 + tx;
  float kr[17];
  #pragma unroll
  for (int k = 0; k < 17; ++k) kr[k] = kern[ch*17 + k];
  #pragma unroll
  for (int rr = 0; rr < 16; ++rr) {
    int r = ty*16 + rr;
    float s = 0.0f;
    #pragma unroll
    for (int k = 0; k < 17; ++k) s = fmaf(kr[k], tile[r+k][tx], s);
    size_t gi = (size_t)(n0 + r)*512 + ch;
    y[gi] = resid[gi] + tile[r+8][tx] + s;
  }
}

__global__ __launch_bounds__(256) void ln1024_kernel(u16* __restrict__ buf)
{
  long long n = blockIdx.x;
  ushort4* p = (ushort4*)(buf + n*1024) + threadIdx.x;
  ushort4 q = *p;
  float a = bf2f(q.x), b = bf2f(q.y), c = bf2f(q.z), d = bf2f(q.w);
  float s = a+b+c+d;
  float ss = fmaf(a,a, fmaf(b,b, fmaf(c,c, d*d)));
  float2 r = blockReduce2(s, ss);
  float mu = r.x * (1.0f/1024.0f);
  float var = r.y * (1.0f/1024.0f) - mu*mu;
  float rs = rsqrtf(var + 1e-5f);
  q.x = f2bf((a-mu)*rs); q.y = f2bf((b-mu)*rs);
  q.z = f2bf((c-mu)*rs); q.w = f2bf((d-mu)*rs);
  *p = q;
}

// ---------------- host launcher ----------------

extern "C" void kernel_launch(void* const* d_in, const int* in_sizes, int n_in,
                              void* d_out, int out_size, void* d_ws, size_t ws_size,
                              hipStream_t stream)
{
  const float* x        = (const float*)d_in[0];
  const float* th_ln_g  = (const float*)d_in[2];
  const float* th_ln_b  = (const float*)d_in[3];
  const float* th_w     = (const float*)d_in[4];
  const float* th_b     = (const float*)d_in[5];
  const float* th_conv  = (const float*)d_in[6];
  const float* qk_ln_g  = (const float*)d_in[7];
  const float* qk_ln_b  = (const float*)d_in[8];
  const float* qk_w     = (const float*)d_in[9];
  const float* qk_b     = (const float*)d_in[10];
  const float* qk_conv  = (const float*)d_in[11];
  const float* osg      = (const float*)d_in[12];
  const float* osb      = (const float*)d_in[13];
  const float* out_ln_g = (const float*)d_in[14];
  const float* out_ln_b = (const float*)d_in[15];
  const float* out_w    = (const float*)d_in[16];
  const float* out_b    = (const float*)d_in[17];
  const float* out_conv = (const float*)d_in[18];

  const int N = in_sizes[0] / 512;          // 16384
  const float inv_n = 1.0f / (float)N;
  const int G = N / GSZ;                    // 64
  char* wsb = (char*)d_ws;

  // ---- workspace layout (bytes), lifetime-aliased ----
  size_t o_hF   = 0;
  size_t o_T2   = o_hF  + (size_t)N*2048*2;
  size_t o_C    = o_T2  + (size_t)N*1024*2;
  size_t o_eqk  = o_C   + (size_t)N*512*2;
  size_t o_fr   = o_eqk + (size_t)N*128*2;
  size_t o_wth  = o_fr  + (size_t)N*128*2;
  size_t o_wqk  = o_wth + (size_t)2048*512*2;
  size_t o_wout = o_wqk + (size_t)128*512*2;
  size_t o_bth  = o_wout+ (size_t)1024*512*2;
  size_t o_bqk  = o_bth + 2048*4;
  size_t o_bout = o_bqk + 128*4;
  size_t o_hsum = o_bout + 512*4;
  size_t required = o_hsum + 2048*4;
  if (ws_size < required) return;

  u16*   hF   = (u16*)(wsb + o_hF);
  u16*   T2   = (u16*)(wsb + o_T2);
  u16*   Hpre = T2;
  u16*   Cu   = (u16*)(wsb + o_C);
  u16*   nx   = Cu;
  u16*   EqkF = Cu;
  u16*   Eq0  = Cu + (size_t)N*256;
  u16*   Ek2  = Cu + (size_t)N*384;
  u16*   attn = Cu;
  u16*   outtmp = Cu;
  u16*   Eqk  = (u16*)(wsb + o_eqk);
  u16*   Dqk  = (u16*)(wsb + o_fr);
  float* Fraw = (float*)(wsb + o_fr);
  u16*   FTg  = (u16*)(wsb + o_fr + (size_t)128*2048*4);
  float* cvec = (float*)(wsb + o_fr + (size_t)128*2048*4 + (size_t)2048*128*2);
  u16*   WthT = (u16*)(wsb + o_wth);
  u16*   WqkT = (u16*)(wsb + o_wqk);
  u16*   WoutT= (u16*)(wsb + o_wout);
  float* Bth  = (float*)(wsb + o_bth);
  float* Bqk  = (float*)(wsb + o_bqk);
  float* Bout = (float*)(wsb + o_bout);
  float* hsum = (float*)(wsb + o_hsum);

  // ---- consolidated prep: transposes + hsum zero (1), fused biases (1) ----
  hipLaunchKernelGGL(prep_trzero, dim3(1608), dim3(256), 0, stream,
                     th_ln_g, th_w, WthT, qk_ln_g, qk_w, WqkT, out_ln_g, out_w, WoutT, hsum);
  hipLaunchKernelGGL(prep_bias, dim3(42), dim3(256), 0, stream,
                     th_ln_b, th_w, th_b, Bth,
                     qk_ln_b, qk_w, qk_b, Bqk,
                     out_ln_b, out_w, out_b, Bout);

  // ---- token shift + LN core ----
  hipLaunchKernelGGL(shift_ln_kernel, dim3(N), dim3(256), 0, stream, x, nx, N);

  // ---- th branch, 2 super-chunks of 1024 cols ----
  for (int sc = 0; sc < 2; ++sc) {
    hipLaunchKernelGGL(gemm_mfma_silu, dim3(8 * (N/128)), dim3(256), 0, stream,
                       nx, 512, WthT, 512, sc*1024, Hpre, 1024, Bth, 512, 8);
    hipLaunchKernelGGL(dwconv_hf64, dim3(16, N/64), dim3(256), 0, stream,
                       Hpre, 1024, th_conv + (size_t)sc*1024*17, hF, sc*1024, hsum, N);
  }

  // ---- qk branch ----
  hipLaunchKernelGGL(gemm_mfma_silu, dim3(1 * (N/128)), dim3(256), 0, stream,
                     nx, 512, WqkT, 512, 0, Dqk, 128, Bqk, 512, 1);
  hipLaunchKernelGGL(dwconv_qk, dim3(2, N/32), dim3(256), 0, stream,
                     Dqk, qk_conv, osg, osb, Eqk, Eq0, Ek2, EqkF, N);

  // ---- linear attention kv summary (Fraw zero must follow dwconv_qk: aliases Dqk) ----
  hipLaunchKernelGGL(zero_kernel, dim3(1024), dim3(256), 0, stream, Fraw, (long long)128*2048);
  hipLaunchKernelGGL(linkv_mfma, dim3(32, 16), dim3(256), 0, stream, EqkF, hF, Fraw, N);
  hipLaunchKernelGGL(fconv_kernel, dim3(8), dim3(256), 0, stream, Fraw, osg, osb, hsum, inv_n, FTg, cvec);

  // ---- quadratic attention scores ----
  hipLaunchKernelGGL(score_mfma2, dim3(2, 2, G), dim3(256), 0, stream, Eq0, Ek2, attn);

  // ---- fused quad + lin + gate -> T2 ----
  hipLaunchKernelGGL(quadlin_mfma, dim3(2*G*16), dim3(256), 0, stream,
                     attn, hF, Eqk, FTg, cvec, T2);

  // ---- out branch ----
  hipLaunchKernelGGL(ln1024_kernel, dim3(N), dim3(256), 0, stream, T2);
  hipLaunchKernelGGL(gemm_mfma_silu, dim3(4 * (N/128)), dim3(256), 0, stream,
                     T2, 1024, WoutT, 1024, 0, outtmp, 512, Bout, 1024, 4);
  hipLaunchKernelGGL(dwconv_final64, dim3(8, N/64), dim3(256), 0, stream,
                     outtmp, out_conv, x, (float*)d_out, N);
}

// Round 17
// 316.222 us; speedup vs baseline: 1.2417x; 1.0747x over previous
//
#include <hip/hip_runtime.h>
#include <math.h>

#define GSZ 256

typedef unsigned short u16;
typedef short bf16x8 __attribute__((ext_vector_type(8)));
typedef u16 u16x8 __attribute__((ext_vector_type(8)));
typedef float f32x4 __attribute__((ext_vector_type(4)));
#define MFMA16 __builtin_amdgcn_mfma_f32_16x16x32_bf16

// hF fragment layout: unit(n,c) = hF + (((n>>5)*NCC + (c>>4))*64 + ((n>>3)&3)*16 + (c&15))*8,
// elem n&7.  NCC = 128 for h (2048 cols), 8 for EqkF (128 cols).

__device__ __forceinline__ float bf2f(u16 u){
  union { unsigned int i; float f; } x; x.i = ((unsigned int)u) << 16; return x.f;
}
__device__ __forceinline__ u16 f2bf(float f){
  union { float ff; unsigned int i; } x; x.ff = f;
  unsigned int r = x.i + 0x7fffu + ((x.i >> 16) & 1u);
  return (u16)(r >> 16);
}
__device__ __forceinline__ float sigm(float x){ return 1.0f/(1.0f+__expf(-x)); }
__device__ __forceinline__ float siluf(float x){ return x/(1.0f+__expf(-x)); }

__device__ __forceinline__ void gload16(const void* g, void* l){
  __builtin_amdgcn_global_load_lds(
      (const __attribute__((address_space(1))) void*)g,
      (__attribute__((address_space(3))) void*)l, 16, 0, 0);
}

__device__ __forceinline__ float2 blockReduce2(float s, float ss){
  __shared__ float red[8];
  #pragma unroll
  for (int off=32; off>0; off>>=1){
    s  += __shfl_down(s, off, 64);
    ss += __shfl_down(ss, off, 64);
  }
  int lane = threadIdx.x & 63, wid = threadIdx.x >> 6;
  if (lane==0){ red[wid]=s; red[4+wid]=ss; }
  __syncthreads();
  float2 r;
  r.x = red[0]+red[1]+red[2]+red[3];
  r.y = red[4]+red[5]+red[6]+red[7];
  return r;
}

// ---------------- prep bodies ----------------

__device__ __forceinline__ void wT_body(float (*sL)[33],
    const float* __restrict__ g, const float* __restrict__ w,
    u16* __restrict__ wT, int K, int Nn, int bx, int by)
{
  int k0 = bx*32, n0 = by*32;
  int t = threadIdx.x;
  int r = t >> 3, cq = t & 7;
  float4 v = *(const float4*)(w + (size_t)(k0+r)*Nn + n0 + cq*4);
  float gg = g[k0+r];
  sL[r][cq*4+0] = v.x*gg; sL[r][cq*4+1] = v.y*gg;
  sL[r][cq*4+2] = v.z*gg; sL[r][cq*4+3] = v.w*gg;
  __syncthreads();
  ushort4 o;
  o.x = f2bf(sL[cq*4+0][r]); o.y = f2bf(sL[cq*4+1][r]);
  o.z = f2bf(sL[cq*4+2][r]); o.w = f2bf(sL[cq*4+3][r]);
  *(ushort4*)(wT + (size_t)(n0+r)*K + k0 + cq*4) = o;
}

__device__ __forceinline__ void bias_body(
    const float* __restrict__ bln, const float* __restrict__ w,
    const float* __restrict__ bias, float* __restrict__ bout,
    int K, int Nn, int cb)
{
  __shared__ float red[4][64];
  int t = threadIdx.x;
  int tc = t & 63, ts = t >> 6;
  int c = cb + tc;
  int kper = K >> 2;
  float acc = 0.f;
  for (int k = ts*kper; k < (ts+1)*kper; ++k)
    acc = fmaf(bln[k], w[(size_t)k*Nn + c], acc);
  red[ts][tc] = acc;
  __syncthreads();
  if (t < 64)
    bout[cb + t] = bias[cb + t] + red[0][t]+red[1][t]+red[2][t]+red[3][t];
}

__device__ __forceinline__ void shift_ln_body(
    const float* __restrict__ x, u16* __restrict__ out, int n, int N)
{
  int t = threadIdx.x;
  float v0 = (n > 0) ? x[(long long)(n-1)*512 + t] : 0.0f;
  float v1 = x[(long long)n*512 + 256 + t];
  float2 r = blockReduce2(v0+v1, fmaf(v0,v0,v1*v1));
  float mu = r.x * (1.0f/512.0f);
  float var = r.y * (1.0f/512.0f) - mu*mu;
  float rs = rsqrtf(var + 1e-5f);
  long long base = (long long)n*512;
  out[base + t]       = f2bf((v0-mu)*rs);
  out[base + 256 + t] = f2bf((v1-mu)*rs);
}

// one launch: shift_ln + all weight transposes + hsum/Fraw zero + fused biases.
// grid = N + 2674
__global__ __launch_bounds__(256) void prep_all(
    const float* __restrict__ x, u16* __restrict__ nx, int N,
    const float* __restrict__ thg, const float* __restrict__ thw, u16* __restrict__ WthT,
    const float* __restrict__ qkg, const float* __restrict__ qkw, u16* __restrict__ WqkT,
    const float* __restrict__ og,  const float* __restrict__ ow,  u16* __restrict__ WoutT,
    float* __restrict__ hsum, float* __restrict__ Fraw,
    const float* __restrict__ thbln, const float* __restrict__ thb, float* __restrict__ Bth,
    const float* __restrict__ qkbln, const float* __restrict__ qkb, float* __restrict__ Bqk,
    const float* __restrict__ obln,  const float* __restrict__ ob,  float* __restrict__ Bout)
{
  __shared__ float sL[32][33];
  int b = blockIdx.x;
  if (b < N) {
    shift_ln_body(x, nx, b, N);
  } else if (b < N + 1024) {
    int lb = b - N;
    wT_body(sL, thg, thw, WthT, 512, 2048, lb & 15, lb >> 4);
  } else if (b < N + 1088) {
    int lb = b - (N + 1024);
    wT_body(sL, qkg, qkw, WqkT, 512, 128, lb & 15, lb >> 4);
  } else if (b < N + 1600) {
    int lb = b - (N + 1088);
    wT_body(sL, og, ow, WoutT, 1024, 512, lb & 31, lb >> 5);
  } else if (b < N + 1608) {
    hsum[(b - (N + 1600))*256 + threadIdx.x] = 0.f;
  } else if (b < N + 2632) {
    Fraw[(size_t)(b - (N + 1608))*256 + threadIdx.x] = 0.f;
  } else {
    int lb = b - (N + 2632);
    if (lb < 32)      bias_body(thbln, thw, thb, Bth, 512, 2048, lb*64);
    else if (lb < 34) bias_body(qkbln, qkw, qkb, Bqk, 512, 128, (lb-32)*64);
    else              bias_body(obln,  ow,  ob,  Bout, 1024, 512, (lb-34)*64);
  }
}

// ---------------- MFMA bodies (chunk-linear LDS + global_load_lds) --------------
// LDS chunk = 64 units x 16B; unit l of chunk = fragment of lane l.
// MFMA frags: A row=l&15 k=(l>>4)*8+j ; B col=l&15 ; D col=l&15 row=(l>>4)*4+i.

// depth-2 GEMM body: C = silu(A @ BT^T + bias) for one 128x128 tile.
__device__ __forceinline__ void gemm_body(u16* lds,
    const u16* __restrict__ A, int lda,
    const u16* __restrict__ BT, int ldbt, int wtc0,
    u16* __restrict__ C, int ldc,
    const float* __restrict__ bias, int K, int bm, int bn)
{
  int t = threadIdx.x;
  int lane = t & 63, wid = t >> 6;
  int wm = wid >> 1, wn = wid & 1;
  int lrow = lane & 15, kcL = lane >> 4;
  const u16* gA0 = A + (size_t)(bm + wid*16 + lrow)*lda + kcL*8;
  const u16* gA1 = A + (size_t)(bm + (wid+4)*16 + lrow)*lda + kcL*8;
  const u16* gB0 = BT + (size_t)(wtc0 + bn + wid*16 + lrow)*ldbt + kcL*8;
  const u16* gB1 = BT + (size_t)(wtc0 + bn + (wid+4)*16 + lrow)*ldbt + kcL*8;
  f32x4 acc[4][4] = {};
  int nt = K >> 5;
  auto issue = [&](int ti, u16* b){
    int k1 = ti << 5;
    gload16(gA0 + k1, b + (size_t)wid*512);
    gload16(gA1 + k1, b + (size_t)(wid+4)*512);
    gload16(gB0 + k1, b + (size_t)(8+wid)*512);
    gload16(gB1 + k1, b + (size_t)(12+wid)*512);
  };
  issue(0, lds);
  if (nt > 1) issue(1, lds + 8192);
  for (int ti = 0; ti < nt; ++ti) {
    if (ti + 2 < nt) {
      issue(ti + 2, lds + (size_t)((ti+2)%3)*8192);
      asm volatile("s_waitcnt vmcnt(8)" ::: "memory");
    } else if (ti + 1 < nt) {
      asm volatile("s_waitcnt vmcnt(4)" ::: "memory");
    } else {
      asm volatile("s_waitcnt vmcnt(0)" ::: "memory");
    }
    __builtin_amdgcn_s_barrier();
    asm volatile("" ::: "memory");
    const bf16x8* L = (const bf16x8*)(lds + (size_t)(ti%3)*8192);
    bf16x8 af[4], bfr[4];
    #pragma unroll
    for (int mr = 0; mr < 4; ++mr) af[mr] = L[(wm*4+mr)*64 + lane];
    #pragma unroll
    for (int nr = 0; nr < 4; ++nr) bfr[nr] = L[(8 + wn*4+nr)*64 + lane];
    #pragma unroll
    for (int mr = 0; mr < 4; ++mr)
      #pragma unroll
      for (int nr = 0; nr < 4; ++nr)
        acc[mr][nr] = MFMA16(af[mr], bfr[nr], acc[mr][nr], 0, 0, 0);
    asm volatile("" ::: "memory");
    __builtin_amdgcn_s_barrier();
  }
  #pragma unroll
  for (int mr = 0; mr < 4; ++mr)
    #pragma unroll
    for (int nr = 0; nr < 4; ++nr) {
      int col = bn + wn*64 + nr*16 + lrow;
      float bs = bias[wtc0 + col];
      #pragma unroll
      for (int i = 0; i < 4; ++i) {
        int row = bm + wm*64 + mr*16 + kcL*4 + i;
        C[(size_t)row*ldc + col] = f2bf(siluf(acc[mr][nr][i] + bs));
      }
    }
}

// standalone GEMM: XCD-colocated 1D grid
__global__ __launch_bounds__(256) void gemm_mfma_silu(
    const u16* __restrict__ A, int lda,
    const u16* __restrict__ BT, int ldbt, int wtc0,
    u16* __restrict__ C, int ldc,
    const float* __restrict__ bias, int K, int nbn)
{
  __shared__ u16 lds[3*16*512];
  int nwg = gridDim.x;
  int bid = blockIdx.x;
  int gidx = (bid & 7) * (nwg >> 3) + (bid >> 3);
  int bm = (gidx / nbn) * 128;
  int bn = (gidx % nbn) * 128;
  gemm_body(lds, A, lda, BT, ldbt, wtc0, C, ldc, bias, K, bm, bn);
}

// merged: th super-chunk 1 (1024 blocks) + qk GEMM (128 blocks). grid 1152.
__global__ __launch_bounds__(256) void gemm_th_qk(
    const u16* __restrict__ nx,
    const u16* __restrict__ WthT, u16* __restrict__ Hpre, const float* __restrict__ Bth,
    const u16* __restrict__ WqkT, u16* __restrict__ Dqk,  const float* __restrict__ Bqk)
{
  __shared__ u16 lds[3*16*512];
  int bid = blockIdx.x;
  if (bid < 1024) {
    int gidx = (bid & 7) * 128 + (bid >> 3);
    int bm = (gidx >> 3) * 128;
    int bn = (gidx & 7) * 128;
    gemm_body(lds, nx, 512, WthT, 512, 1024, Hpre, 1024, Bth, 512, bm, bn);
  } else {
    int lb = bid - 1024;
    int gidx = (lb & 7) * 16 + (lb >> 3);
    gemm_body(lds, nx, 512, WqkT, 512, 0, Dqk, 128, Bqk, 512, gidx * 128, 0);
  }
}

// score body: attn = relu(Eq0 @ Ek2^T / GS)^2 for one 128x128 tile of group g.
__device__ __forceinline__ void score_body(u16* lds,
    const u16* __restrict__ Eq0, const u16* __restrict__ Ek2,
    u16* __restrict__ attn, int g, int bm, int bn)
{
  int t = threadIdx.x;
  int lane = t & 63, wid = t >> 6;
  int wm = wid >> 1, wn = wid & 1;
  int lrow = lane & 15, kcL = lane >> 4;
  size_t rowbase = (size_t)g * GSZ;
  const u16* gA0 = Eq0 + (rowbase + bm + wid*16 + lrow)*128 + kcL*8;
  const u16* gA1 = Eq0 + (rowbase + bm + (wid+4)*16 + lrow)*128 + kcL*8;
  const u16* gB0 = Ek2 + (rowbase + bn + wid*16 + lrow)*128 + kcL*8;
  const u16* gB1 = Ek2 + (rowbase + bn + (wid+4)*16 + lrow)*128 + kcL*8;
  f32x4 acc[4][4] = {};
  auto issue = [&](int ti, u16* b){
    int k1 = ti << 5;
    gload16(gA0 + k1, b + (size_t)wid*512);
    gload16(gA1 + k1, b + (size_t)(wid+4)*512);
    gload16(gB0 + k1, b + (size_t)(8+wid)*512);
    gload16(gB1 + k1, b + (size_t)(12+wid)*512);
  };
  issue(0, lds);
  issue(1, lds + 8192);
  for (int ti = 0; ti < 4; ++ti) {
    if (ti + 2 < 4) {
      issue(ti + 2, lds + (size_t)((ti+2)%3)*8192);
      asm volatile("s_waitcnt vmcnt(8)" ::: "memory");
    } else if (ti + 1 < 4) {
      asm volatile("s_waitcnt vmcnt(4)" ::: "memory");
    } else {
      asm volatile("s_waitcnt vmcnt(0)" ::: "memory");
    }
    __builtin_amdgcn_s_barrier();
    asm volatile("" ::: "memory");
    const bf16x8* L = (const bf16x8*)(lds + (size_t)(ti%3)*8192);
    bf16x8 af[4], bfr[4];
    #pragma unroll
    for (int mr = 0; mr < 4; ++mr) af[mr] = L[(wm*4+mr)*64 + lane];
    #pragma unroll
    for (int nr = 0; nr < 4; ++nr) bfr[nr] = L[(8 + wn*4+nr)*64 + lane];
    #pragma unroll
    for (int mr = 0; mr < 4; ++mr)
      #pragma unroll
      for (int nr = 0; nr < 4; ++nr)
        acc[mr][nr] = MFMA16(af[mr], bfr[nr], acc[mr][nr], 0, 0, 0);
    asm volatile("" ::: "memory");
    __builtin_amdgcn_s_barrier();
  }
  #pragma unroll
  for (int mr = 0; mr < 4; ++mr)
    #pragma unroll
    for (int nr = 0; nr < 4; ++nr) {
      int col = bn + wn*64 + nr*16 + lrow;
      #pragma unroll
      for (int i = 0; i < 4; ++i) {
        int row = bm + wm*64 + mr*16 + kcL*4 + i;
        float s = fmaxf(acc[mr][nr][i] * (1.0f/GSZ), 0.0f);
        attn[(rowbase + row)*GSZ + col] = f2bf(s*s);
      }
    }
}

__device__ __forceinline__ void fconv_body(float* shf,
    const float* __restrict__ Fraw, const float* __restrict__ osg, const float* __restrict__ osb,
    const float* __restrict__ hsum, float inv_n,
    u16* __restrict__ FTg, float* __restrict__ cvec, int blk)
{
  float* g1s = shf; float* b1s = shf + 128; float* g3s = shf + 256; float* b3s = shf + 384;
  int t = threadIdx.x;
  if (t < 128) { g1s[t] = osg[128+t]; b1s[t] = osb[128+t];
                 g3s[t] = osg[3*128+t]; b3s[t] = osb[3*128+t]; }
  __syncthreads();
  int e = blk*256 + t;
  float hs = hsum[e];
  float c = 0.f;
  for (int d = 0; d < 128; ++d) {
    float f = inv_n * fmaf(g3s[d], Fraw[(size_t)d*2048 + e], b3s[d]*hs);
    c = fmaf(b1s[d], f, c);
    FTg[(size_t)e*128 + d] = f2bf(g1s[d] * f);
  }
  cvec[e] = c;
}

// merged: score (256 blocks: g = b>>2, bm = ((b>>1)&1)*128, bn = (b&1)*128) + fconv (8).
__global__ __launch_bounds__(256) void fconv_score(
    const u16* __restrict__ Eq0, const u16* __restrict__ Ek2, u16* __restrict__ attn,
    const float* __restrict__ Fraw, const float* __restrict__ osg, const float* __restrict__ osb,
    const float* __restrict__ hsum, float inv_n,
    u16* __restrict__ FTg, float* __restrict__ cvec)
{
  __shared__ u16 lds[3*16*512];
  int b = blockIdx.x;
  if (b < 256) {
    score_body(lds, Eq0, Ek2, attn, b >> 2, ((b >> 1) & 1)*128, (b & 1)*128);
  } else {
    fconv_body((float*)lds, Fraw, osg, osb, hsum, inv_n, FTg, cvec, b - 256);
  }
}

// Fraw[d][e] += sum_n EqkF(n,d) * hF(n,e) — pure gload dbuf GEMM. grid (32, 16)
__global__ __launch_bounds__(256) void linkv_mfma(
    const u16* __restrict__ EqkF, const u16* __restrict__ hF,
    float* __restrict__ Fraw, int N)
{
  __shared__ u16 lds[2*12*512];
  int t = threadIdx.x;
  int lane = t & 63, wid = t >> 6;
  int wm = wid >> 1, wn = wid & 1;
  int lrow = lane & 15, kcL = lane >> 4;
  int e0 = blockIdx.x * 64;
  int nkt = (N / gridDim.y) >> 5;
  size_t kt0 = (size_t)blockIdx.y * nkt;
  f32x4 acc[4][2] = {};
  auto issue = [&](int kt, u16* b) {
    size_t ktile = kt0 + kt;
    gload16(EqkF + ((ktile*8 + wid)*64 + lane)*8,           b + (size_t)wid*512);
    gload16(EqkF + ((ktile*8 + wid+4)*64 + lane)*8,         b + (size_t)(wid+4)*512);
    gload16(hF + ((ktile*128 + (e0>>4) + wid)*64 + lane)*8, b + (size_t)(8+wid)*512);
  };
  issue(0, lds);
  int cur = 0;
  for (int ti = 0; ti < nkt; ++ti) {
    if (ti + 1 < nkt) {
      issue(ti + 1, lds + (size_t)(cur^1)*6144);
      asm volatile("s_waitcnt vmcnt(3)" ::: "memory");
    } else {
      asm volatile("s_waitcnt vmcnt(0)" ::: "memory");
    }
    __builtin_amdgcn_s_barrier();
    asm volatile("" ::: "memory");
    const bf16x8* L = (const bf16x8*)(lds + (size_t)cur*6144);
    bf16x8 af[4], bfr[2];
    #pragma unroll
    for (int mr = 0; mr < 4; ++mr) af[mr] = L[(wm*4+mr)*64 + lane];
    #pragma unroll
    for (int nr = 0; nr < 2; ++nr) bfr[nr] = L[(8 + wn*2+nr)*64 + lane];
    #pragma unroll
    for (int mr = 0; mr < 4; ++mr)
      #pragma unroll
      for (int nr = 0; nr < 2; ++nr)
        acc[mr][nr] = MFMA16(af[mr], bfr[nr], acc[mr][nr], 0, 0, 0);
    asm volatile("" ::: "memory");
    __builtin_amdgcn_s_barrier();
    cur ^= 1;
  }
  #pragma unroll
  for (int mr = 0; mr < 4; ++mr)
    #pragma unroll
    for (int nr = 0; nr < 2; ++nr) {
      int e = e0 + wn*32 + nr*16 + lrow;
      #pragma unroll
      for (int i = 0; i < 4; ++i) {
        int d = wm*64 + mr*16 + kcL*4 + i;
        atomicAdd(&Fraw[(size_t)d*2048 + e], acc[mr][nr][i]);
      }
    }
}

// fused quad+lin attention + gate. 2-buffer depth-1 (measured best). grid 2048.
__global__ __launch_bounds__(256) void quadlin_mfma(
    const u16* __restrict__ attn, const u16* __restrict__ hF,
    const u16* __restrict__ eqk, const u16* __restrict__ FTg,
    const float* __restrict__ cvec, u16* __restrict__ T2)
{
  __shared__ u16 lds[2*16*512];
  int bid = blockIdx.x;
  int wgid = (bid & 7)*256 + (bid >> 3);
  int g = wgid >> 5;
  int rem = wgid & 31;
  int bm = (rem >> 4) * 128;
  int cb = (rem & 15) * 64;
  int t = threadIdx.x;
  int lane = t & 63, wid = t >> 6;
  int wm = wid >> 1, wn = wid & 1;
  int lrow = lane & 15, kcL = lane >> 4;
  size_t rowbase = (size_t)g * GSZ;
  f32x4 accV[4][2] = {}, accU[4][2] = {};
  const u16* gA0q = attn + (rowbase + bm + wid*16 + lrow)*GSZ + kcL*8;
  const u16* gA1q = attn + (rowbase + bm + (wid+4)*16 + lrow)*GSZ + kcL*8;
  const u16* gA0l = eqk + (rowbase + bm + wid*16 + lrow)*128 + kcL*8;
  const u16* gA1l = eqk + (rowbase + bm + (wid+4)*16 + lrow)*128 + kcL*8;
  const u16* gBVl = FTg + (size_t)(cb + wid*16 + lrow)*128 + kcL*8;
  const u16* gBUl = FTg + (size_t)(1024 + cb + wid*16 + lrow)*128 + kcL*8;
  auto issue = [&](int ti, u16* b) {
    if (ti < 8) {
      int k0 = ti << 5;
      size_t ktile = (size_t)g*8 + ti;
      gload16(gA0q + k0, b + (size_t)wid*512);
      gload16(gA1q + k0, b + (size_t)(wid+4)*512);
      gload16(hF + ((ktile*128 + (cb>>4) + wid)*64 + lane)*8,      b + (size_t)(8+wid)*512);
      gload16(hF + ((ktile*128 + 64 + (cb>>4) + wid)*64 + lane)*8, b + (size_t)(12+wid)*512);
    } else {
      int k0 = (ti - 8) << 5;
      gload16(gA0l + k0, b + (size_t)wid*512);
      gload16(gA1l + k0, b + (size_t)(wid+4)*512);
      gload16(gBVl + k0, b + (size_t)(8+wid)*512);
      gload16(gBUl + k0, b + (size_t)(12+wid)*512);
    }
  };
  issue(0, lds);
  int cur = 0;
  for (int ti = 0; ti < 12; ++ti) {
    if (ti + 1 < 12) {
      issue(ti + 1, lds + (size_t)(cur^1)*8192);
      asm volatile("s_waitcnt vmcnt(4)" ::: "memory");
    } else {
      asm volatile("s_waitcnt vmcnt(0)" ::: "memory");
    }
    __builtin_amdgcn_s_barrier();
    asm volatile("" ::: "memory");
    const bf16x8* L = (const bf16x8*)(lds + (size_t)cur*8192);
    bf16x8 af[4], bv[2], bu[2];
    #pragma unroll
    for (int mr = 0; mr < 4; ++mr) af[mr] = L[(wm*4+mr)*64 + lane];
    #pragma unroll
    for (int nr = 0; nr < 2; ++nr) { bv[nr] = L[(8 + wn*2+nr)*64 + lane];
                                     bu[nr] = L[(12 + wn*2+nr)*64 + lane]; }
    #pragma unroll
    for (int mr = 0; mr < 4; ++mr)
      #pragma unroll
      for (int nr = 0; nr < 2; ++nr) {
        accV[mr][nr] = MFMA16(af[mr], bv[nr], accV[mr][nr], 0, 0, 0);
        accU[mr][nr] = MFMA16(af[mr], bu[nr], accU[mr][nr], 0, 0, 0);
      }
    asm volatile("" ::: "memory");
    __builtin_amdgcn_s_barrier();
    cur ^= 1;
  }
  #pragma unroll
  for (int mr = 0; mr < 4; ++mr)
    #pragma unroll
    for (int nr = 0; nr < 2; ++nr) {
      int c = cb + wn*32 + nr*16 + lrow;
      float cV = cvec[c], cU = cvec[1024 + c];
      int np = bm + wm*64 + mr*16 + kcL*4;
      size_t ktile = (size_t)g*8 + (np>>5);
      int lofs = ((np>>3)&3)*16 + (c&15);
      int eo = np & 7;
      ushort4 vq = *(const ushort4*)(hF + ((ktile*128 + (c>>4))*64 + lofs)*8 + eo);
      ushort4 uq = *(const ushort4*)(hF + ((ktile*128 + 64 + (c>>4))*64 + lofs)*8 + eo);
      float vv[4] = {bf2f(vq.x), bf2f(vq.y), bf2f(vq.z), bf2f(vq.w)};
      float uu[4] = {bf2f(uq.x), bf2f(uq.y), bf2f(uq.z), bf2f(uq.w)};
      #pragma unroll
      for (int i = 0; i < 4; ++i) {
        float av = accV[mr][nr][i] + cV;
        float au = accU[mr][nr][i] + cU;
        T2[(rowbase + np + i)*1024 + c] = f2bf(au * vv[i] * sigm(av * uu[i]));
      }
    }
}

// ---------------- conv / norm kernels ----------------

__global__ __launch_bounds__(256) void dwconv_hf64(
    const u16* __restrict__ xin, int ldin, const float* __restrict__ kern,
    u16* __restrict__ hF, int colbase, float* __restrict__ hsum, int N)
{
  __shared__ float tile[80][64];
  __shared__ float psum[4][64];
  int c0 = blockIdx.x * 64;
  int n0 = blockIdx.y * 64;
  int t = threadIdx.x;
  int tx = t & 63, ty = t >> 6;
  #pragma unroll
  for (int it = 0; it < 5; ++it) {
    int idx = t + it*256;
    int r = idx >> 4, cq = (idx & 15)*4;
    int gn = n0 - 8 + r;
    float4 f;
    if (gn >= 0 && gn < N) {
      ushort4 q = *(const ushort4*)(xin + (size_t)gn*ldin + c0 + cq);
      f.x = bf2f(q.x); f.y = bf2f(q.y); f.z = bf2f(q.z); f.w = bf2f(q.w);
    } else { f.x = 0.f; f.y = 0.f; f.z = 0.f; f.w = 0.f; }
    *(float4*)&tile[r][cq] = f;
  }
  __syncthreads();
  int chl = c0 + tx;
  float kr[17];
  #pragma unroll
  for (int k = 0; k < 17; ++k) kr[k] = kern[chl*17 + k];
  int c = colbase + chl;
  float loc = 0.f;
  #pragma unroll
  for (int u = 0; u < 2; ++u) {
    u16x8 o;
    #pragma unroll
    for (int rr = 0; rr < 8; ++rr) {
      int r = ty*16 + u*8 + rr;
      float s = 0.0f;
      #pragma unroll
      for (int k = 0; k < 17; ++k) s = fmaf(kr[k], tile[r+k][tx], s);
      float val = tile[r+8][tx] + s;
      loc += val;
      o[rr] = f2bf(val);
    }
    int nn = n0 + ty*16 + u*8;
    *(u16x8*)(hF + ((((size_t)(nn>>5))*128 + (c>>4))*64 + ((nn>>3)&3)*16 + (c&15))*8) = o;
  }
  psum[ty][tx] = loc;
  __syncthreads();
  if (t < 64)
    atomicAdd(&hsum[colbase + c0 + t], psum[0][t]+psum[1][t]+psum[2][t]+psum[3][t]);
}

__global__ __launch_bounds__(256) void dwconv_qk(
    const u16* __restrict__ xin, const float* __restrict__ kern,
    const float* __restrict__ osg, const float* __restrict__ osb,
    u16* __restrict__ Eqk, u16* __restrict__ Eq0, u16* __restrict__ Ek2,
    u16* __restrict__ EqkF, int N)
{
  __shared__ float tile[48][64];
  int c0 = blockIdx.x * 64;
  int n0 = blockIdx.y * 32;
  int t = threadIdx.x;
  int tx = t & 63, ty = t >> 6;
  #pragma unroll
  for (int it = 0; it < 3; ++it) {
    int idx = t + it*256;
    int r = idx >> 4, cq = (idx & 15)*4;
    int gn = n0 - 8 + r;
    float4 f;
    if (gn >= 0 && gn < N) {
      ushort4 q = *(const ushort4*)(xin + (size_t)gn*128 + c0 + cq);
      f.x = bf2f(q.x); f.y = bf2f(q.y); f.z = bf2f(q.z); f.w = bf2f(q.w);
    } else { f.x = 0.f; f.y = 0.f; f.z = 0.f; f.w = 0.f; }
    *(float4*)&tile[r][cq] = f;
  }
  __syncthreads();
  int ch = c0 + tx;
  float kr[17];
  #pragma unroll
  for (int k = 0; k < 17; ++k) kr[k] = kern[ch*17 + k];
  float g0 = osg[ch], b0 = osb[ch];
  float g2 = osg[2*128+ch], b2 = osb[2*128+ch];
  float vals[8];
  #pragma unroll
  for (int rr = 0; rr < 8; ++rr) {
    int r = ty*8 + rr;
    float s = 0.0f;
    #pragma unroll
    for (int k = 0; k < 17; ++k) s = fmaf(kr[k], tile[r+k][tx], s);
    vals[rr] = tile[r+8][tx] + s;
    size_t gi = (size_t)(n0 + r)*128 + ch;
    Eqk[gi] = f2bf(vals[rr]);
    Eq0[gi] = f2bf(fmaf(vals[rr], g0, b0));
    Ek2[gi] = f2bf(fmaf(vals[rr], g2, b2));
  }
  u16x8 o;
  #pragma unroll
  for (int rr = 0; rr < 8; ++rr) o[rr] = f2bf(vals[rr]);
  *(u16x8*)(EqkF + ((((size_t)(n0>>5))*8 + (ch>>4))*64 + ty*16 + (ch&15))*8) = o;
}

__global__ __launch_bounds__(256) void dwconv_final64(
    const u16* __restrict__ xin, const float* __restrict__ kern,
    const float* __restrict__ resid, float* __restrict__ y, int N)
{
  __shared__ float tile[80][64];
  int c0 = blockIdx.x * 64;
  int n0 = blockIdx.y * 64;
  int t = threadIdx.x;
  int tx = t & 63, ty = t >> 6;
  #pragma unroll
  for (int it = 0; it < 5; ++it) {
    int idx = t + it*256;
    int r = idx >> 4, cq = (idx & 15)*4;
    int gn = n0 - 8 + r;
    float4 f;
    if (gn >= 0 && gn < N) {
      ushort4 q = *(const ushort4*)(xin + (size_t)gn*512 + c0 + cq);
      f.x = bf2f(q.x); f.y = bf2f(q.y); f.z = bf2f(q.z); f.w = bf2f(q.w);
    } else { f.x = 0.f; f.y = 0.f; f.z = 0.f; f.w = 0.f; }
    *(float4*)&tile[r][cq] = f;
  }
  __syncthreads();
  int ch = c0 + tx;
  float kr[17];
  #pragma unroll
  for (int k = 0; k < 17; ++k) kr[k] = kern[ch*17 + k];
  #pragma unroll
  for (int rr = 0; rr < 16; ++rr) {
    int r = ty*16 + rr;
    float s = 0.0f;
    #pragma unroll
    for (int k = 0; k < 17; ++k) s = fmaf(kr[k], tile[r+k][tx], s);
    size_t gi = (size_t)(n0 + r)*512 + ch;
    y[gi] = resid[gi] + tile[r+8][tx] + s;
  }
}

__global__ __launch_bounds__(256) void ln1024_kernel(u16* __restrict__ buf)
{
  long long n = blockIdx.x;
  ushort4* p = (ushort4*)(buf + n*1024) + threadIdx.x;
  ushort4 q = *p;
  float a = bf2f(q.x), b = bf2f(q.y), c = bf2f(q.z), d = bf2f(q.w);
  float s = a+b+c+d;
  float ss = fmaf(a,a, fmaf(b,b, fmaf(c,c, d*d)));
  float2 r = blockReduce2(s, ss);
  float mu = r.x * (1.0f/1024.0f);
  float var = r.y * (1.0f/1024.0f) - mu*mu;
  float rs = rsqrtf(var + 1e-5f);
  q.x = f2bf((a-mu)*rs); q.y = f2bf((b-mu)*rs);
  q.z = f2bf((c-mu)*rs); q.w = f2bf((d-mu)*rs);
  *p = q;
}

// ---------------- host launcher ----------------

extern "C" void kernel_launch(void* const* d_in, const int* in_sizes, int n_in,
                              void* d_out, int out_size, void* d_ws, size_t ws_size,
                              hipStream_t stream)
{
  const float* x        = (const float*)d_in[0];
  const float* th_ln_g  = (const float*)d_in[2];
  const float* th_ln_b  = (const float*)d_in[3];
  const float* th_w     = (const float*)d_in[4];
  const float* th_b     = (const float*)d_in[5];
  const float* th_conv  = (const float*)d_in[6];
  const float* qk_ln_g  = (const float*)d_in[7];
  const float* qk_ln_b  = (const float*)d_in[8];
  const float* qk_w     = (const float*)d_in[9];
  const float* qk_b     = (const float*)d_in[10];
  const float* qk_conv  = (const float*)d_in[11];
  const float* osg      = (const float*)d_in[12];
  const float* osb      = (const float*)d_in[13];
  const float* out_ln_g = (const float*)d_in[14];
  const float* out_ln_b = (const float*)d_in[15];
  const float* out_w    = (const float*)d_in[16];
  const float* out_b    = (const float*)d_in[17];
  const float* out_conv = (const float*)d_in[18];

  const int N = in_sizes[0] / 512;          // 16384
  const float inv_n = 1.0f / (float)N;
  const int G = N / GSZ;                    // 64
  char* wsb = (char*)d_ws;

  // ---- workspace layout (bytes), lifetime-aliased ----
  size_t o_hF   = 0;
  size_t o_T2   = o_hF  + (size_t)N*2048*2;
  size_t o_C    = o_T2  + (size_t)N*1024*2;
  size_t o_eqk  = o_C   + (size_t)N*512*2;
  size_t o_fr   = o_eqk + (size_t)N*128*2;            // Dqk (4MB); FTg/cvec after Dqk dead
  size_t o_wth  = o_fr  + (size_t)N*128*2;
  size_t o_wqk  = o_wth + (size_t)2048*512*2;
  size_t o_wout = o_wqk + (size_t)128*512*2;
  size_t o_bth  = o_wout+ (size_t)1024*512*2;
  size_t o_bqk  = o_bth + 2048*4;
  size_t o_bout = o_bqk + 128*4;
  size_t o_hsum = o_bout + 512*4;
  size_t o_fraw = o_hsum + 2048*4;                    // dedicated Fraw: 1MB
  size_t required = o_fraw + (size_t)128*2048*4;
  if (ws_size < required) return;

  u16*   hF   = (u16*)(wsb + o_hF);
  u16*   T2   = (u16*)(wsb + o_T2);
  u16*   Hpre = T2;
  u16*   Cu   = (u16*)(wsb + o_C);
  u16*   nx   = Cu;
  u16*   EqkF = Cu;
  u16*   Eq0  = Cu + (size_t)N*256;
  u16*   Ek2  = Cu + (size_t)N*384;
  u16*   attn = Cu;
  u16*   outtmp = Cu;
  u16*   Eqk  = (u16*)(wsb + o_eqk);
  u16*   Dqk  = (u16*)(wsb + o_fr);
  u16*   FTg  = (u16*)(wsb + o_fr);                        // after Dqk dead
  float* cvec = (float*)(wsb + o_fr + (size_t)2048*128*2);
  float* Fraw = (float*)(wsb + o_fraw);
  u16*   WthT = (u16*)(wsb + o_wth);
  u16*   WqkT = (u16*)(wsb + o_wqk);
  u16*   WoutT= (u16*)(wsb + o_wout);
  float* Bth  = (float*)(wsb + o_bth);
  float* Bqk  = (float*)(wsb + o_bqk);
  float* Bout = (float*)(wsb + o_bout);
  float* hsum = (float*)(wsb + o_hsum);

  // ---- single prep launch: shift_ln + transposes + zeros + biases ----
  hipLaunchKernelGGL(prep_all, dim3(N + 2674), dim3(256), 0, stream,
                     x, nx, N,
                     th_ln_g, th_w, WthT, qk_ln_g, qk_w, WqkT, out_ln_g, out_w, WoutT,
                     hsum, Fraw,
                     th_ln_b, th_b, Bth, qk_ln_b, qk_b, Bqk, out_ln_b, out_b, Bout);

  // ---- th branch super-chunk 0 ----
  hipLaunchKernelGGL(gemm_mfma_silu, dim3(8 * (N/128)), dim3(256), 0, stream,
                     nx, 512, WthT, 512, 0, Hpre, 1024, Bth, 512, 8);
  hipLaunchKernelGGL(dwconv_hf64, dim3(16, N/64), dim3(256), 0, stream,
                     Hpre, 1024, th_conv, hF, 0, hsum, N);

  // ---- th super-chunk 1 + qk GEMM (merged launch) ----
  hipLaunchKernelGGL(gemm_th_qk, dim3(1152), dim3(256), 0, stream,
                     nx, WthT, Hpre, Bth, WqkT, Dqk, Bqk);
  hipLaunchKernelGGL(dwconv_hf64, dim3(16, N/64), dim3(256), 0, stream,
                     Hpre, 1024, th_conv + (size_t)1024*17, hF, 1024, hsum, N);
  hipLaunchKernelGGL(dwconv_qk, dim3(2, N/32), dim3(256), 0, stream,
                     Dqk, qk_conv, osg, osb, Eqk, Eq0, Ek2, EqkF, N);

  // ---- linear attention kv summary (Fraw pre-zeroed in prep) ----
  hipLaunchKernelGGL(linkv_mfma, dim3(32, 16), dim3(256), 0, stream, EqkF, hF, Fraw, N);

  // ---- fconv + quadratic attention scores (merged, independent) ----
  hipLaunchKernelGGL(fconv_score, dim3(264), dim3(256), 0, stream,
                     Eq0, Ek2, attn, Fraw, osg, osb, hsum, inv_n, FTg, cvec);

  // ---- fused quad + lin + gate -> T2 ----
  hipLaunchKernelGGL(quadlin_mfma, dim3(2*G*16), dim3(256), 0, stream,
                     attn, hF, Eqk, FTg, cvec, T2);

  // ---- out branch ----
  hipLaunchKernelGGL(ln1024_kernel, dim3(N), dim3(256), 0, stream, T2);
  hipLaunchKernelGGL(gemm_mfma_silu, dim3(4 * (N/128)), dim3(256), 0, stream,
                     T2, 1024, WoutT, 1024, 0, outtmp, 512, Bout, 1024, 4);
  hipLaunchKernelGGL(dwconv_final64, dim3(8, N/64), dim3(256), 0, stream,
                     outtmp, out_conv, x, (float*)d_out, N);
}

// Round 18
// 312.837 us; speedup vs baseline: 1.2551x; 1.0108x over previous
//
#include <hip/hip_runtime.h>
#include <math.h>

#define GSZ 256

typedef unsigned short u16;
typedef short bf16x8 __attribute__((ext_vector_type(8)));
typedef u16 u16x8 __attribute__((ext_vector_type(8)));
typedef float f32x4 __attribute__((ext_vector_type(4)));
#define MFMA16 __builtin_amdgcn_mfma_f32_16x16x32_bf16

// hF fragment layout: unit(n,c) = hF + (((n>>5)*NCC + (c>>4))*64 + ((n>>3)&3)*16 + (c&15))*8,
// elem n&7.  NCC = 128 for h (2048 cols), 8 for EqkF (128 cols).

__device__ __forceinline__ float bf2f(u16 u){
  union { unsigned int i; float f; } x; x.i = ((unsigned int)u) << 16; return x.f;
}
__device__ __forceinline__ u16 f2bf(float f){
  union { float ff; unsigned int i; } x; x.ff = f;
  unsigned int r = x.i + 0x7fffu + ((x.i >> 16) & 1u);
  return (u16)(r >> 16);
}
__device__ __forceinline__ float sigm(float x){ return 1.0f/(1.0f+__expf(-x)); }
__device__ __forceinline__ float siluf(float x){ return x/(1.0f+__expf(-x)); }

__device__ __forceinline__ void gload16(const void* g, void* l){
  __builtin_amdgcn_global_load_lds(
      (const __attribute__((address_space(1))) void*)g,
      (__attribute__((address_space(3))) void*)l, 16, 0, 0);
}

__device__ __forceinline__ float2 blockReduce2(float s, float ss){
  __shared__ float red[8];
  #pragma unroll
  for (int off=32; off>0; off>>=1){
    s  += __shfl_down(s, off, 64);
    ss += __shfl_down(ss, off, 64);
  }
  int lane = threadIdx.x & 63, wid = threadIdx.x >> 6;
  if (lane==0){ red[wid]=s; red[4+wid]=ss; }
  __syncthreads();
  float2 r;
  r.x = red[0]+red[1]+red[2]+red[3];
  r.y = red[4]+red[5]+red[6]+red[7];
  return r;
}

// ---------------- prep bodies ----------------

__device__ __forceinline__ void wT_body(float (*sL)[33],
    const float* __restrict__ g, const float* __restrict__ w,
    u16* __restrict__ wT, int K, int Nn, int bx, int by)
{
  int k0 = bx*32, n0 = by*32;
  int t = threadIdx.x;
  int r = t >> 3, cq = t & 7;
  float4 v = *(const float4*)(w + (size_t)(k0+r)*Nn + n0 + cq*4);
  float gg = g[k0+r];
  sL[r][cq*4+0] = v.x*gg; sL[r][cq*4+1] = v.y*gg;
  sL[r][cq*4+2] = v.z*gg; sL[r][cq*4+3] = v.w*gg;
  __syncthreads();
  ushort4 o;
  o.x = f2bf(sL[cq*4+0][r]); o.y = f2bf(sL[cq*4+1][r]);
  o.z = f2bf(sL[cq*4+2][r]); o.w = f2bf(sL[cq*4+3][r]);
  *(ushort4*)(wT + (size_t)(n0+r)*K + k0 + cq*4) = o;
}

__device__ __forceinline__ void bias_body(
    const float* __restrict__ bln, const float* __restrict__ w,
    const float* __restrict__ bias, float* __restrict__ bout,
    int K, int Nn, int cb)
{
  __shared__ float red[4][64];
  int t = threadIdx.x;
  int tc = t & 63, ts = t >> 6;
  int c = cb + tc;
  int kper = K >> 2;
  float acc = 0.f;
  for (int k = ts*kper; k < (ts+1)*kper; ++k)
    acc = fmaf(bln[k], w[(size_t)k*Nn + c], acc);
  red[ts][tc] = acc;
  __syncthreads();
  if (t < 64)
    bout[cb + t] = bias[cb + t] + red[0][t]+red[1][t]+red[2][t]+red[3][t];
}

__device__ __forceinline__ void shift_ln_body(
    const float* __restrict__ x, u16* __restrict__ out, int n, int N)
{
  int t = threadIdx.x;
  float v0 = (n > 0) ? x[(long long)(n-1)*512 + t] : 0.0f;
  float v1 = x[(long long)n*512 + 256 + t];
  float2 r = blockReduce2(v0+v1, fmaf(v0,v0,v1*v1));
  float mu = r.x * (1.0f/512.0f);
  float var = r.y * (1.0f/512.0f) - mu*mu;
  float rs = rsqrtf(var + 1e-5f);
  long long base = (long long)n*512;
  out[base + t]       = f2bf((v0-mu)*rs);
  out[base + 256 + t] = f2bf((v1-mu)*rs);
}

// one launch: shift_ln + all weight transposes + hsum/Fraw zero + fused biases.
// grid = N + 2674
__global__ __launch_bounds__(256) void prep_all(
    const float* __restrict__ x, u16* __restrict__ nx, int N,
    const float* __restrict__ thg, const float* __restrict__ thw, u16* __restrict__ WthT,
    const float* __restrict__ qkg, const float* __restrict__ qkw, u16* __restrict__ WqkT,
    const float* __restrict__ og,  const float* __restrict__ ow,  u16* __restrict__ WoutT,
    float* __restrict__ hsum, float* __restrict__ Fraw,
    const float* __restrict__ thbln, const float* __restrict__ thb, float* __restrict__ Bth,
    const float* __restrict__ qkbln, const float* __restrict__ qkb, float* __restrict__ Bqk,
    const float* __restrict__ obln,  const float* __restrict__ ob,  float* __restrict__ Bout)
{
  __shared__ float sL[32][33];
  int b = blockIdx.x;
  if (b < N) {
    shift_ln_body(x, nx, b, N);
  } else if (b < N + 1024) {
    int lb = b - N;
    wT_body(sL, thg, thw, WthT, 512, 2048, lb & 15, lb >> 4);
  } else if (b < N + 1088) {
    int lb = b - (N + 1024);
    wT_body(sL, qkg, qkw, WqkT, 512, 128, lb & 15, lb >> 4);
  } else if (b < N + 1600) {
    int lb = b - (N + 1088);
    wT_body(sL, og, ow, WoutT, 1024, 512, lb & 31, lb >> 5);
  } else if (b < N + 1608) {
    hsum[(b - (N + 1600))*256 + threadIdx.x] = 0.f;
  } else if (b < N + 2632) {
    Fraw[(size_t)(b - (N + 1608))*256 + threadIdx.x] = 0.f;
  } else {
    int lb = b - (N + 2632);
    if (lb < 32)      bias_body(thbln, thw, thb, Bth, 512, 2048, lb*64);
    else if (lb < 34) bias_body(qkbln, qkw, qkb, Bqk, 512, 128, (lb-32)*64);
    else              bias_body(obln,  ow,  ob,  Bout, 1024, 512, (lb-34)*64);
  }
}

// ---------------- MFMA bodies (chunk-linear LDS + global_load_lds) --------------
// LDS chunk = 64 units x 16B; unit l of chunk = fragment of lane l.
// MFMA frags: A row=l&15 k=(l>>4)*8+j ; B col=l&15 ; D col=l&15 row=(l>>4)*4+i.

// depth-1 2-buffer GEMM body (quadlin-proven schedule): C = silu(A @ BT^T + bias).
__device__ __forceinline__ void gemm_body(u16* lds,
    const u16* __restrict__ A, int lda,
    const u16* __restrict__ BT, int ldbt, int wtc0,
    u16* __restrict__ C, int ldc,
    const float* __restrict__ bias, int K, int bm, int bn)
{
  int t = threadIdx.x;
  int lane = t & 63, wid = t >> 6;
  int wm = wid >> 1, wn = wid & 1;
  int lrow = lane & 15, kcL = lane >> 4;
  const u16* gA0 = A + (size_t)(bm + wid*16 + lrow)*lda + kcL*8;
  const u16* gA1 = A + (size_t)(bm + (wid+4)*16 + lrow)*lda + kcL*8;
  const u16* gB0 = BT + (size_t)(wtc0 + bn + wid*16 + lrow)*ldbt + kcL*8;
  const u16* gB1 = BT + (size_t)(wtc0 + bn + (wid+4)*16 + lrow)*ldbt + kcL*8;
  f32x4 acc[4][4] = {};
  int nt = K >> 5;
  auto issue = [&](int ti, u16* b){
    int k1 = ti << 5;
    gload16(gA0 + k1, b + (size_t)wid*512);
    gload16(gA1 + k1, b + (size_t)(wid+4)*512);
    gload16(gB0 + k1, b + (size_t)(8+wid)*512);
    gload16(gB1 + k1, b + (size_t)(12+wid)*512);
  };
  issue(0, lds);
  int cur = 0;
  for (int ti = 0; ti < nt; ++ti) {
    if (ti + 1 < nt) {
      issue(ti + 1, lds + (size_t)(cur^1)*8192);
      asm volatile("s_waitcnt vmcnt(4)" ::: "memory");
    } else {
      asm volatile("s_waitcnt vmcnt(0)" ::: "memory");
    }
    __builtin_amdgcn_s_barrier();
    asm volatile("" ::: "memory");
    const bf16x8* L = (const bf16x8*)(lds + (size_t)cur*8192);
    bf16x8 af[4], bfr[4];
    #pragma unroll
    for (int mr = 0; mr < 4; ++mr) af[mr] = L[(wm*4+mr)*64 + lane];
    #pragma unroll
    for (int nr = 0; nr < 4; ++nr) bfr[nr] = L[(8 + wn*4+nr)*64 + lane];
    #pragma unroll
    for (int mr = 0; mr < 4; ++mr)
      #pragma unroll
      for (int nr = 0; nr < 4; ++nr)
        acc[mr][nr] = MFMA16(af[mr], bfr[nr], acc[mr][nr], 0, 0, 0);
    asm volatile("" ::: "memory");
    __builtin_amdgcn_s_barrier();
    cur ^= 1;
  }
  #pragma unroll
  for (int mr = 0; mr < 4; ++mr)
    #pragma unroll
    for (int nr = 0; nr < 4; ++nr) {
      int col = bn + wn*64 + nr*16 + lrow;
      float bs = bias[wtc0 + col];
      #pragma unroll
      for (int i = 0; i < 4; ++i) {
        int row = bm + wm*64 + mr*16 + kcL*4 + i;
        C[(size_t)row*ldc + col] = f2bf(siluf(acc[mr][nr][i] + bs));
      }
    }
}

// standalone GEMM: XCD-colocated 1D grid
__global__ __launch_bounds__(256) void gemm_mfma_silu(
    const u16* __restrict__ A, int lda,
    const u16* __restrict__ BT, int ldbt, int wtc0,
    u16* __restrict__ C, int ldc,
    const float* __restrict__ bias, int K, int nbn)
{
  __shared__ u16 lds[2*16*512];
  int nwg = gridDim.x;
  int bid = blockIdx.x;
  int gidx = (bid & 7) * (nwg >> 3) + (bid >> 3);
  int bm = (gidx / nbn) * 128;
  int bn = (gidx % nbn) * 128;
  gemm_body(lds, A, lda, BT, ldbt, wtc0, C, ldc, bias, K, bm, bn);
}

// merged: th super-chunk 1 (1024 blocks) + qk GEMM (128 blocks). grid 1152.
__global__ __launch_bounds__(256) void gemm_th_qk(
    const u16* __restrict__ nx,
    const u16* __restrict__ WthT, u16* __restrict__ Hpre, const float* __restrict__ Bth,
    const u16* __restrict__ WqkT, u16* __restrict__ Dqk,  const float* __restrict__ Bqk)
{
  __shared__ u16 lds[2*16*512];
  int bid = blockIdx.x;
  if (bid < 1024) {
    int gidx = (bid & 7) * 128 + (bid >> 3);
    int bm = (gidx >> 3) * 128;
    int bn = (gidx & 7) * 128;
    gemm_body(lds, nx, 512, WthT, 512, 1024, Hpre, 1024, Bth, 512, bm, bn);
  } else {
    int lb = bid - 1024;
    int gidx = (lb & 7) * 16 + (lb >> 3);
    gemm_body(lds, nx, 512, WqkT, 512, 0, Dqk, 128, Bqk, 512, gidx * 128, 0);
  }
}

// score body: attn = relu(Eq0 @ Ek2^T / GS)^2 for one 128x128 tile of group g.
__device__ __forceinline__ void score_body(u16* lds,
    const u16* __restrict__ Eq0, const u16* __restrict__ Ek2,
    u16* __restrict__ attn, int g, int bm, int bn)
{
  int t = threadIdx.x;
  int lane = t & 63, wid = t >> 6;
  int wm = wid >> 1, wn = wid & 1;
  int lrow = lane & 15, kcL = lane >> 4;
  size_t rowbase = (size_t)g * GSZ;
  const u16* gA0 = Eq0 + (rowbase + bm + wid*16 + lrow)*128 + kcL*8;
  const u16* gA1 = Eq0 + (rowbase + bm + (wid+4)*16 + lrow)*128 + kcL*8;
  const u16* gB0 = Ek2 + (rowbase + bn + wid*16 + lrow)*128 + kcL*8;
  const u16* gB1 = Ek2 + (rowbase + bn + (wid+4)*16 + lrow)*128 + kcL*8;
  f32x4 acc[4][4] = {};
  auto issue = [&](int ti, u16* b){
    int k1 = ti << 5;
    gload16(gA0 + k1, b + (size_t)wid*512);
    gload16(gA1 + k1, b + (size_t)(wid+4)*512);
    gload16(gB0 + k1, b + (size_t)(8+wid)*512);
    gload16(gB1 + k1, b + (size_t)(12+wid)*512);
  };
  issue(0, lds);
  int cur = 0;
  for (int ti = 0; ti < 4; ++ti) {
    if (ti + 1 < 4) {
      issue(ti + 1, lds + (size_t)(cur^1)*8192);
      asm volatile("s_waitcnt vmcnt(4)" ::: "memory");
    } else {
      asm volatile("s_waitcnt vmcnt(0)" ::: "memory");
    }
    __builtin_amdgcn_s_barrier();
    asm volatile("" ::: "memory");
    const bf16x8* L = (const bf16x8*)(lds + (size_t)cur*8192);
    bf16x8 af[4], bfr[4];
    #pragma unroll
    for (int mr = 0; mr < 4; ++mr) af[mr] = L[(wm*4+mr)*64 + lane];
    #pragma unroll
    for (int nr = 0; nr < 4; ++nr) bfr[nr] = L[(8 + wn*4+nr)*64 + lane];
    #pragma unroll
    for (int mr = 0; mr < 4; ++mr)
      #pragma unroll
      for (int nr = 0; nr < 4; ++nr)
        acc[mr][nr] = MFMA16(af[mr], bfr[nr], acc[mr][nr], 0, 0, 0);
    asm volatile("" ::: "memory");
    __builtin_amdgcn_s_barrier();
    cur ^= 1;
  }
  #pragma unroll
  for (int mr = 0; mr < 4; ++mr)
    #pragma unroll
    for (int nr = 0; nr < 4; ++nr) {
      int col = bn + wn*64 + nr*16 + lrow;
      #pragma unroll
      for (int i = 0; i < 4; ++i) {
        int row = bm + wm*64 + mr*16 + kcL*4 + i;
        float s = fmaxf(acc[mr][nr][i] * (1.0f/GSZ), 0.0f);
        attn[(rowbase + row)*GSZ + col] = f2bf(s*s);
      }
    }
}

__device__ __forceinline__ void fconv_body(float* shf,
    const float* __restrict__ Fraw, const float* __restrict__ osg, const float* __restrict__ osb,
    const float* __restrict__ hsum, float inv_n,
    u16* __restrict__ FTg, float* __restrict__ cvec, int blk)
{
  float* g1s = shf; float* b1s = shf + 128; float* g3s = shf + 256; float* b3s = shf + 384;
  int t = threadIdx.x;
  if (t < 128) { g1s[t] = osg[128+t]; b1s[t] = osb[128+t];
                 g3s[t] = osg[3*128+t]; b3s[t] = osb[3*128+t]; }
  __syncthreads();
  int e = blk*256 + t;
  float hs = hsum[e];
  float c = 0.f;
  for (int d = 0; d < 128; ++d) {
    float f = inv_n * fmaf(g3s[d], Fraw[(size_t)d*2048 + e], b3s[d]*hs);
    c = fmaf(b1s[d], f, c);
    FTg[(size_t)e*128 + d] = f2bf(g1s[d] * f);
  }
  cvec[e] = c;
}

// merged: score (256 blocks) + fconv (8 blocks). grid 264.
__global__ __launch_bounds__(256) void fconv_score(
    const u16* __restrict__ Eq0, const u16* __restrict__ Ek2, u16* __restrict__ attn,
    const float* __restrict__ Fraw, const float* __restrict__ osg, const float* __restrict__ osb,
    const float* __restrict__ hsum, float inv_n,
    u16* __restrict__ FTg, float* __restrict__ cvec)
{
  __shared__ u16 lds[2*16*512];
  int b = blockIdx.x;
  if (b < 256) {
    score_body(lds, Eq0, Ek2, attn, b >> 2, ((b >> 1) & 1)*128, (b & 1)*128);
  } else {
    fconv_body((float*)lds, Fraw, osg, osb, hsum, inv_n, FTg, cvec, b - 256);
  }
}

// Fraw[d][e] += sum_n EqkF(n,d) * hF(n,e) — pure gload dbuf GEMM. grid (32, 16)
__global__ __launch_bounds__(256) void linkv_mfma(
    const u16* __restrict__ EqkF, const u16* __restrict__ hF,
    float* __restrict__ Fraw, int N)
{
  __shared__ u16 lds[2*12*512];
  int t = threadIdx.x;
  int lane = t & 63, wid = t >> 6;
  int wm = wid >> 1, wn = wid & 1;
  int lrow = lane & 15, kcL = lane >> 4;
  int e0 = blockIdx.x * 64;
  int nkt = (N / gridDim.y) >> 5;
  size_t kt0 = (size_t)blockIdx.y * nkt;
  f32x4 acc[4][2] = {};
  auto issue = [&](int kt, u16* b) {
    size_t ktile = kt0 + kt;
    gload16(EqkF + ((ktile*8 + wid)*64 + lane)*8,           b + (size_t)wid*512);
    gload16(EqkF + ((ktile*8 + wid+4)*64 + lane)*8,         b + (size_t)(wid+4)*512);
    gload16(hF + ((ktile*128 + (e0>>4) + wid)*64 + lane)*8, b + (size_t)(8+wid)*512);
  };
  issue(0, lds);
  int cur = 0;
  for (int ti = 0; ti < nkt; ++ti) {
    if (ti + 1 < nkt) {
      issue(ti + 1, lds + (size_t)(cur^1)*6144);
      asm volatile("s_waitcnt vmcnt(3)" ::: "memory");
    } else {
      asm volatile("s_waitcnt vmcnt(0)" ::: "memory");
    }
    __builtin_amdgcn_s_barrier();
    asm volatile("" ::: "memory");
    const bf16x8* L = (const bf16x8*)(lds + (size_t)cur*6144);
    bf16x8 af[4], bfr[2];
    #pragma unroll
    for (int mr = 0; mr < 4; ++mr) af[mr] = L[(wm*4+mr)*64 + lane];
    #pragma unroll
    for (int nr = 0; nr < 2; ++nr) bfr[nr] = L[(8 + wn*2+nr)*64 + lane];
    #pragma unroll
    for (int mr = 0; mr < 4; ++mr)
      #pragma unroll
      for (int nr = 0; nr < 2; ++nr)
        acc[mr][nr] = MFMA16(af[mr], bfr[nr], acc[mr][nr], 0, 0, 0);
    asm volatile("" ::: "memory");
    __builtin_amdgcn_s_barrier();
    cur ^= 1;
  }
  #pragma unroll
  for (int mr = 0; mr < 4; ++mr)
    #pragma unroll
    for (int nr = 0; nr < 2; ++nr) {
      int e = e0 + wn*32 + nr*16 + lrow;
      #pragma unroll
      for (int i = 0; i < 4; ++i) {
        int d = wm*64 + mr*16 + kcL*4 + i;
        atomicAdd(&Fraw[(size_t)d*2048 + e], acc[mr][nr][i]);
      }
    }
}

// fused quad+lin attention + gate. 2-buffer depth-1 (measured best). grid 2048.
__global__ __launch_bounds__(256) void quadlin_mfma(
    const u16* __restrict__ attn, const u16* __restrict__ hF,
    const u16* __restrict__ eqk, const u16* __restrict__ FTg,
    const float* __restrict__ cvec, u16* __restrict__ T2)
{
  __shared__ u16 lds[2*16*512];
  int bid = blockIdx.x;
  int wgid = (bid & 7)*256 + (bid >> 3);
  int g = wgid >> 5;
  int rem = wgid & 31;
  int bm = (rem >> 4) * 128;
  int cb = (rem & 15) * 64;
  int t = threadIdx.x;
  int lane = t & 63, wid = t >> 6;
  int wm = wid >> 1, wn = wid & 1;
  int lrow = lane & 15, kcL = lane >> 4;
  size_t rowbase = (size_t)g * GSZ;
  f32x4 accV[4][2] = {}, accU[4][2] = {};
  const u16* gA0q = attn + (rowbase + bm + wid*16 + lrow)*GSZ + kcL*8;
  const u16* gA1q = attn + (rowbase + bm + (wid+4)*16 + lrow)*GSZ + kcL*8;
  const u16* gA0l = eqk + (rowbase + bm + wid*16 + lrow)*128 + kcL*8;
  const u16* gA1l = eqk + (rowbase + bm + (wid+4)*16 + lrow)*128 + kcL*8;
  const u16* gBVl = FTg + (size_t)(cb + wid*16 + lrow)*128 + kcL*8;
  const u16* gBUl = FTg + (size_t)(1024 + cb + wid*16 + lrow)*128 + kcL*8;
  auto issue = [&](int ti, u16* b) {
    if (ti < 8) {
      int k0 = ti << 5;
      size_t ktile = (size_t)g*8 + ti;
      gload16(gA0q + k0, b + (size_t)wid*512);
      gload16(gA1q + k0, b + (size_t)(wid+4)*512);
      gload16(hF + ((ktile*128 + (cb>>4) + wid)*64 + lane)*8,      b + (size_t)(8+wid)*512);
      gload16(hF + ((ktile*128 + 64 + (cb>>4) + wid)*64 + lane)*8, b + (size_t)(12+wid)*512);
    } else {
      int k0 = (ti - 8) << 5;
      gload16(gA0l + k0, b + (size_t)wid*512);
      gload16(gA1l + k0, b + (size_t)(wid+4)*512);
      gload16(gBVl + k0, b + (size_t)(8+wid)*512);
      gload16(gBUl + k0, b + (size_t)(12+wid)*512);
    }
  };
  issue(0, lds);
  int cur = 0;
  for (int ti = 0; ti < 12; ++ti) {
    if (ti + 1 < 12) {
      issue(ti + 1, lds + (size_t)(cur^1)*8192);
      asm volatile("s_waitcnt vmcnt(4)" ::: "memory");
    } else {
      asm volatile("s_waitcnt vmcnt(0)" ::: "memory");
    }
    __builtin_amdgcn_s_barrier();
    asm volatile("" ::: "memory");
    const bf16x8* L = (const bf16x8*)(lds + (size_t)cur*8192);
    bf16x8 af[4], bv[2], bu[2];
    #pragma unroll
    for (int mr = 0; mr < 4; ++mr) af[mr] = L[(wm*4+mr)*64 + lane];
    #pragma unroll
    for (int nr = 0; nr < 2; ++nr) { bv[nr] = L[(8 + wn*2+nr)*64 + lane];
                                     bu[nr] = L[(12 + wn*2+nr)*64 + lane]; }
    #pragma unroll
    for (int mr = 0; mr < 4; ++mr)
      #pragma unroll
      for (int nr = 0; nr < 2; ++nr) {
        accV[mr][nr] = MFMA16(af[mr], bv[nr], accV[mr][nr], 0, 0, 0);
        accU[mr][nr] = MFMA16(af[mr], bu[nr], accU[mr][nr], 0, 0, 0);
      }
    asm volatile("" ::: "memory");
    __builtin_amdgcn_s_barrier();
    cur ^= 1;
  }
  #pragma unroll
  for (int mr = 0; mr < 4; ++mr)
    #pragma unroll
    for (int nr = 0; nr < 2; ++nr) {
      int c = cb + wn*32 + nr*16 + lrow;
      float cV = cvec[c], cU = cvec[1024 + c];
      int np = bm + wm*64 + mr*16 + kcL*4;
      size_t ktile = (size_t)g*8 + (np>>5);
      int lofs = ((np>>3)&3)*16 + (c&15);
      int eo = np & 7;
      ushort4 vq = *(const ushort4*)(hF + ((ktile*128 + (c>>4))*64 + lofs)*8 + eo);
      ushort4 uq = *(const ushort4*)(hF + ((ktile*128 + 64 + (c>>4))*64 + lofs)*8 + eo);
      float vv[4] = {bf2f(vq.x), bf2f(vq.y), bf2f(vq.z), bf2f(vq.w)};
      float uu[4] = {bf2f(uq.x), bf2f(uq.y), bf2f(uq.z), bf2f(uq.w)};
      #pragma unroll
      for (int i = 0; i < 4; ++i) {
        float av = accV[mr][nr][i] + cV;
        float au = accU[mr][nr][i] + cU;
        T2[(rowbase + np + i)*1024 + c] = f2bf(au * vv[i] * sigm(av * uu[i]));
      }
    }
}

// ---------------- conv / norm kernels ----------------

__global__ __launch_bounds__(256) void dwconv_hf64(
    const u16* __restrict__ xin, int ldin, const float* __restrict__ kern,
    u16* __restrict__ hF, int colbase, float* __restrict__ hsum, int N)
{
  __shared__ float tile[80][64];
  __shared__ float psum[4][64];
  int c0 = blockIdx.x * 64;
  int n0 = blockIdx.y * 64;
  int t = threadIdx.x;
  int tx = t & 63, ty = t >> 6;
  #pragma unroll
  for (int it = 0; it < 5; ++it) {
    int idx = t + it*256;
    int r = idx >> 4, cq = (idx & 15)*4;
    int gn = n0 - 8 + r;
    float4 f;
    if (gn >= 0 && gn < N) {
      ushort4 q = *(const ushort4*)(xin + (size_t)gn*ldin + c0 + cq);
      f.x = bf2f(q.x); f.y = bf2f(q.y); f.z = bf2f(q.z); f.w = bf2f(q.w);
    } else { f.x = 0.f; f.y = 0.f; f.z = 0.f; f.w = 0.f; }
    *(float4*)&tile[r][cq] = f;
  }
  __syncthreads();
  int chl = c0 + tx;
  float kr[17];
  #pragma unroll
  for (int k = 0; k < 17; ++k) kr[k] = kern[chl*17 + k];
  int c = colbase + chl;
  float loc = 0.f;
  #pragma unroll
  for (int u = 0; u < 2; ++u) {
    u16x8 o;
    #pragma unroll
    for (int rr = 0; rr < 8; ++rr) {
      int r = ty*16 + u*8 + rr;
      float s = 0.0f;
      #pragma unroll
      for (int k = 0; k < 17; ++k) s = fmaf(kr[k], tile[r+k][tx], s);
      float val = tile[r+8][tx] + s;
      loc += val;
      o[rr] = f2bf(val);
    }
    int nn = n0 + ty*16 + u*8;
    *(u16x8*)(hF + ((((size_t)(nn>>5))*128 + (c>>4))*64 + ((nn>>3)&3)*16 + (c&15))*8) = o;
  }
  psum[ty][tx] = loc;
  __syncthreads();
  if (t < 64)
    atomicAdd(&hsum[colbase + c0 + t], psum[0][t]+psum[1][t]+psum[2][t]+psum[3][t]);
}

__global__ __launch_bounds__(256) void dwconv_qk(
    const u16* __restrict__ xin, const float* __restrict__ kern,
    const float* __restrict__ osg, const float* __restrict__ osb,
    u16* __restrict__ Eqk, u16* __restrict__ Eq0, u16* __restrict__ Ek2,
    u16* __restrict__ EqkF, int N)
{
  __shared__ float tile[48][64];
  int c0 = blockIdx.x * 64;
  int n0 = blockIdx.y * 32;
  int t = threadIdx.x;
  int tx = t & 63, ty = t >> 6;
  #pragma unroll
  for (int it = 0; it < 3; ++it) {
    int idx = t + it*256;
    int r = idx >> 4, cq = (idx & 15)*4;
    int gn = n0 - 8 + r;
    float4 f;
    if (gn >= 0 && gn < N) {
      ushort4 q = *(const ushort4*)(xin + (size_t)gn*128 + c0 + cq);
      f.x = bf2f(q.x); f.y = bf2f(q.y); f.z = bf2f(q.z); f.w = bf2f(q.w);
    } else { f.x = 0.f; f.y = 0.f; f.z = 0.f; f.w = 0.f; }
    *(float4*)&tile[r][cq] = f;
  }
  __syncthreads();
  int ch = c0 + tx;
  float kr[17];
  #pragma unroll
  for (int k = 0; k < 17; ++k) kr[k] = kern[ch*17 + k];
  float g0 = osg[ch], b0 = osb[ch];
  float g2 = osg[2*128+ch], b2 = osb[2*128+ch];
  float vals[8];
  #pragma unroll
  for (int rr = 0; rr < 8; ++rr) {
    int r = ty*8 + rr;
    float s = 0.0f;
    #pragma unroll
    for (int k = 0; k < 17; ++k) s = fmaf(kr[k], tile[r+k][tx], s);
    vals[rr] = tile[r+8][tx] + s;
    size_t gi = (size_t)(n0 + r)*128 + ch;
    Eqk[gi] = f2bf(vals[rr]);
    Eq0[gi] = f2bf(fmaf(vals[rr], g0, b0));
    Ek2[gi] = f2bf(fmaf(vals[rr], g2, b2));
  }
  u16x8 o;
  #pragma unroll
  for (int rr = 0; rr < 8; ++rr) o[rr] = f2bf(vals[rr]);
  *(u16x8*)(EqkF + ((((size_t)(n0>>5))*8 + (ch>>4))*64 + ty*16 + (ch&15))*8) = o;
}

__global__ __launch_bounds__(256) void dwconv_final64(
    const u16* __restrict__ xin, const float* __restrict__ kern,
    const float* __restrict__ resid, float* __restrict__ y, int N)
{
  __shared__ float tile[80][64];
  int c0 = blockIdx.x * 64;
  int n0 = blockIdx.y * 64;
  int t = threadIdx.x;
  int tx = t & 63, ty = t >> 6;
  #pragma unroll
  for (int it = 0; it < 5; ++it) {
    int idx = t + it*256;
    int r = idx >> 4, cq = (idx & 15)*4;
    int gn = n0 - 8 + r;
    float4 f;
    if (gn >= 0 && gn < N) {
      ushort4 q = *(const ushort4*)(xin + (size_t)gn*512 + c0 + cq);
      f.x = bf2f(q.x); f.y = bf2f(q.y); f.z = bf2f(q.z); f.w = bf2f(q.w);
    } else { f.x = 0.f; f.y = 0.f; f.z = 0.f; f.w = 0.f; }
    *(float4*)&tile[r][cq] = f;
  }
  __syncthreads();
  int ch = c0 + tx;
  float kr[17];
  #pragma unroll
  for (int k = 0; k < 17; ++k) kr[k] = kern[ch*17 + k];
  #pragma unroll
  for (int rr = 0; rr < 16; ++rr) {
    int r = ty*16 + rr;
    float s = 0.0f;
    #pragma unroll
    for (int k = 0; k < 17; ++k) s = fmaf(kr[k], tile[r+k][tx], s);
    size_t gi = (size_t)(n0 + r)*512 + ch;
    y[gi] = resid[gi] + tile[r+8][tx] + s;
  }
}

__global__ __launch_bounds__(256) void ln1024_kernel(u16* __restrict__ buf)
{
  long long n = blockIdx.x;
  ushort4* p = (ushort4*)(buf + n*1024) + threadIdx.x;
  ushort4 q = *p;
  float a = bf2f(q.x), b = bf2f(q.y), c = bf2f(q.z), d = bf2f(q.w);
  float s = a+b+c+d;
  float ss = fmaf(a,a, fmaf(b,b, fmaf(c,c, d*d)));
  float2 r = blockReduce2(s, ss);
  float mu = r.x * (1.0f/1024.0f);
  float var = r.y * (1.0f/1024.0f) - mu*mu;
  float rs = rsqrtf(var + 1e-5f);
  q.x = f2bf((a-mu)*rs); q.y = f2bf((b-mu)*rs);
  q.z = f2bf((c-mu)*rs); q.w = f2bf((d-mu)*rs);
  *p = q;
}

// ---------------- host launcher ----------------

extern "C" void kernel_launch(void* const* d_in, const int* in_sizes, int n_in,
                              void* d_out, int out_size, void* d_ws, size_t ws_size,
                              hipStream_t stream)
{
  const float* x        = (const float*)d_in[0];
  const float* th_ln_g  = (const float*)d_in[2];
  const float* th_ln_b  = (const float*)d_in[3];
  const float* th_w     = (const float*)d_in[4];
  const float* th_b     = (const float*)d_in[5];
  const float* th_conv  = (const float*)d_in[6];
  const float* qk_ln_g  = (const float*)d_in[7];
  const float* qk_ln_b  = (const float*)d_in[8];
  const float* qk_w     = (const float*)d_in[9];
  const float* qk_b     = (const float*)d_in[10];
  const float* qk_conv  = (const float*)d_in[11];
  const float* osg      = (const float*)d_in[12];
  const float* osb      = (const float*)d_in[13];
  const float* out_ln_g = (const float*)d_in[14];
  const float* out_ln_b = (const float*)d_in[15];
  const float* out_w    = (const float*)d_in[16];
  const float* out_b    = (const float*)d_in[17];
  const float* out_conv = (const float*)d_in[18];

  const int N = in_sizes[0] / 512;          // 16384
  const float inv_n = 1.0f / (float)N;
  const int G = N / GSZ;                    // 64
  char* wsb = (char*)d_ws;

  // ---- workspace layout (bytes), lifetime-aliased ----
  size_t o_hF   = 0;
  size_t o_T2   = o_hF  + (size_t)N*2048*2;
  size_t o_C    = o_T2  + (size_t)N*1024*2;
  size_t o_eqk  = o_C   + (size_t)N*512*2;
  size_t o_fr   = o_eqk + (size_t)N*128*2;            // Dqk (4MB); FTg/cvec after Dqk dead
  size_t o_wth  = o_fr  + (size_t)N*128*2;
  size_t o_wqk  = o_wth + (size_t)2048*512*2;
  size_t o_wout = o_wqk + (size_t)128*512*2;
  size_t o_bth  = o_wout+ (size_t)1024*512*2;
  size_t o_bqk  = o_bth + 2048*4;
  size_t o_bout = o_bqk + 128*4;
  size_t o_hsum = o_bout + 512*4;
  size_t o_fraw = o_hsum + 2048*4;                    // dedicated Fraw: 1MB
  size_t required = o_fraw + (size_t)128*2048*4;
  if (ws_size < required) return;

  u16*   hF   = (u16*)(wsb + o_hF);
  u16*   T2   = (u16*)(wsb + o_T2);
  u16*   Hpre = T2;
  u16*   Cu   = (u16*)(wsb + o_C);
  u16*   nx   = Cu;
  u16*   EqkF = Cu;
  u16*   Eq0  = Cu + (size_t)N*256;
  u16*   Ek2  = Cu + (size_t)N*384;
  u16*   attn = Cu;
  u16*   outtmp = Cu;
  u16*   Eqk  = (u16*)(wsb + o_eqk);
  u16*   Dqk  = (u16*)(wsb + o_fr);
  u16*   FTg  = (u16*)(wsb + o_fr);                        // after Dqk dead
  float* cvec = (float*)(wsb + o_fr + (size_t)2048*128*2);
  float* Fraw = (float*)(wsb + o_fraw);
  u16*   WthT = (u16*)(wsb + o_wth);
  u16*   WqkT = (u16*)(wsb + o_wqk);
  u16*   WoutT= (u16*)(wsb + o_wout);
  float* Bth  = (float*)(wsb + o_bth);
  float* Bqk  = (float*)(wsb + o_bqk);
  float* Bout = (float*)(wsb + o_bout);
  float* hsum = (float*)(wsb + o_hsum);

  // ---- single prep launch: shift_ln + transposes + zeros + biases ----
  hipLaunchKernelGGL(prep_all, dim3(N + 2674), dim3(256), 0, stream,
                     x, nx, N,
                     th_ln_g, th_w, WthT, qk_ln_g, qk_w, WqkT, out_ln_g, out_w, WoutT,
                     hsum, Fraw,
                     th_ln_b, th_b, Bth, qk_ln_b, qk_b, Bqk, out_ln_b, out_b, Bout);

  // ---- th branch super-chunk 0 ----
  hipLaunchKernelGGL(gemm_mfma_silu, dim3(8 * (N/128)), dim3(256), 0, stream,
                     nx, 512, WthT, 512, 0, Hpre, 1024, Bth, 512, 8);
  hipLaunchKernelGGL(dwconv_hf64, dim3(16, N/64), dim3(256), 0, stream,
                     Hpre, 1024, th_conv, hF, 0, hsum, N);

  // ---- th super-chunk 1 + qk GEMM (merged launch) ----
  hipLaunchKernelGGL(gemm_th_qk, dim3(1152), dim3(256), 0, stream,
                     nx, WthT, Hpre, Bth, WqkT, Dqk, Bqk);
  hipLaunchKernelGGL(dwconv_hf64, dim3(16, N/64), dim3(256), 0, stream,
                     Hpre, 1024, th_conv + (size_t)1024*17, hF, 1024, hsum, N);
  hipLaunchKernelGGL(dwconv_qk, dim3(2, N/32), dim3(256), 0, stream,
                     Dqk, qk_conv, osg, osb, Eqk, Eq0, Ek2, EqkF, N);

  // ---- linear attention kv summary (Fraw pre-zeroed in prep) ----
  hipLaunchKernelGGL(linkv_mfma, dim3(32, 16), dim3(256), 0, stream, EqkF, hF, Fraw, N);

  // ---- fconv + quadratic attention scores (merged, independent) ----
  hipLaunchKernelGGL(fconv_score, dim3(264), dim3(256), 0, stream,
                     Eq0, Ek2, attn, Fraw, osg, osb, hsum, inv_n, FTg, cvec);

  // ---- fused quad + lin + gate -> T2 ----
  hipLaunchKernelGGL(quadlin_mfma, dim3(2*G*16), dim3(256), 0, stream,
                     attn, hF, Eqk, FTg, cvec, T2);

  // ---- out branch ----
  hipLaunchKernelGGL(ln1024_kernel, dim3(N), dim3(256), 0, stream, T2);
  hipLaunchKernelGGL(gemm_mfma_silu, dim3(4 * (N/128)), dim3(256), 0, stream,
                     T2, 1024, WoutT, 1024, 0, outtmp, 512, Bout, 1024, 4);
  hipLaunchKernelGGL(dwconv_final64, dim3(8, N/64), dim3(256), 0, stream,
                     outtmp, out_conv, x, (float*)d_out, N);
}